// Round 2
// baseline (2571.111 us; speedup 1.0000x reference)
//
#include <hip/hip_runtime.h>

// ---------------- problem constants ----------------
#define BB     16
#define LLEN   1024
#define CINN   14
#define TSZ    256
#define HSZ    512
#define NST    32
#define ESZ    128
#define NDEPTH 6
#define NCHUNK 16
#define LCHUNK 64
#define QHN    (HSZ*NST)   // per-(d,j) const stride = 16384

#define RS2 0.70710678118654752f   // 1/sqrt(2)
#define IS6 0.40824829046386302f   // 1/sqrt(6)

typedef unsigned short u16;
typedef unsigned int   u32;

// workspace layout (float offsets)
#define OFF_LAM  0u
#define OFF_C    393216u
#define OFF_LAMP 786432u
#define OFF_EMB  1179648u
#define OFF_DPE  1181696u
#define OFF_H    1206272u
#define OFF_SKIP 5400576u
#define OFF_Y1   9594880u
#define OFF_Y2   17983488u
#define OFF_SLOC 26372096u
#define WS_FLOATS 26896384u

// ---------------- S4D constants: lambda = exp(dt*A), C' = 2*C*(lambda-1)/A, lambda^Lc ----
__global__ void consts_kernel(const float* __restrict__ log_dt, const float* __restrict__ logA,
                              const float* __restrict__ Aim,   const float* __restrict__ Cre,
                              const float* __restrict__ Cim,
                              float2* __restrict__ lam2, float2* __restrict__ C2,
                              float2* __restrict__ lamP2){
  int gid = blockIdx.x*256 + threadIdx.x;            // q*16384 + h*32 + n
  int h = (gid>>5) & 511;
  int q = gid >> 14;
  float dt  = expf(log_dt[q*HSZ + h]);
  float are = -expf(logA[gid]);
  float aim = Aim[gid];
  float dre = are*dt, dim = aim*dt;
  float e   = expf(dre);
  float lre = e*cosf(dim), lim = e*sinf(dim);
  // (lambda-1)/A
  float nre = lre - 1.f, nim = lim;
  float invden = 1.f/(are*are + aim*aim);
  float tre = (nre*are + nim*aim)*invden;
  float tim = (nim*are - nre*aim)*invden;
  float cr = Cre[gid], ci = Cim[gid];
  float Cr = 2.f*(cr*tre - ci*tim);
  float Ci = 2.f*(cr*tim + ci*tre);
  lam2[gid] = make_float2(lre, lim);
  C2[gid]   = make_float2(Cr, Ci);
  // lambda^64 via 6 squarings
  float pr = lre, pi = lim;
#pragma unroll
  for (int i=0;i<6;i++){ float nr = pr*pr - pi*pi; pi = 2.f*pr*pi; pr = nr; }
  lamP2[gid] = make_float2(pr, pi);
}

// ---------------- diffusion embedding MLP ----------------
__global__ void emb_kernel(const float* __restrict__ t, const float* __restrict__ gw,
                           const float* __restrict__ w1, const float* __restrict__ b1,
                           const float* __restrict__ w2, const float* __restrict__ b2,
                           float* __restrict__ emb){
  __shared__ float e0[128], e1[128];
  int b = blockIdx.x, tid = threadIdx.x;
  float tb = t[b];
  if (tid < 64){
    float xp = tb * gw[tid] * 6.283185307179586f;
    e0[tid]    = sinf(xp);
    e0[tid+64] = cosf(xp);
  }
  __syncthreads();
  float a = b1[tid];
  for (int i=0;i<128;i++) a = fmaf(e0[i], w1[tid*128+i], a);
  a = a / (1.f + __expf(-a));            // silu
  e1[tid] = a;
  __syncthreads();
  float a2 = b2[tid];
  for (int i=0;i<128;i++) a2 = fmaf(e1[i], w2[tid*128+i], a2);
  a2 = a2 / (1.f + __expf(-a2));
  emb[b*ESZ + tid] = a2;
}

// ---------------- per-depth diffusion projection (emb @ dp_w^T + dp_b) ----------------
__global__ void dpe_kernel(const float* __restrict__ emb, const float* __restrict__ dw,
                           const float* __restrict__ db, float* __restrict__ dpe){
  int blk = blockIdx.x; int d = blk >> 4; int b = blk & 15; int o = threadIdx.x;
  const float* wp = dw + (size_t)(d*TSZ + o)*ESZ;
  const float* ep = emb + b*ESZ;
  float a = db[d*TSZ + o];
  for (int e=0;e<128;e++) a = fmaf(ep[e], wp[e], a);
  dpe[(size_t)(d*BB + b)*TSZ + o] = a;
}

// ---------------- input projection [B,L,14] -> h [B,256,L] ----------------
__global__ __launch_bounds__(256) void inproj_kernel(const float* __restrict__ x, const float* __restrict__ w,
                                                     const float* __restrict__ bias, float* __restrict__ hb){
  __shared__ float ws[256*14];
  __shared__ float bs[256];
  int tid = threadIdx.x;
#pragma unroll
  for (int c=0;c<14;c++) ws[tid*14+c] = w[tid*14+c];
  bs[tid] = bias[tid];
  __syncthreads();
  int b = blockIdx.x >> 2;
  int l = ((blockIdx.x & 3) << 8) + tid;
  float xv[14];
  const float* xp = x + (size_t)(b*LLEN + l)*CINN;
#pragma unroll
  for (int c=0;c<14;c++) xv[c] = xp[c];
  for (int o=0;o<256;o++){
    float a = bs[o];
#pragma unroll
    for (int c=0;c<14;c++) a = fmaf(ws[o*14+c], xv[c], a);
    hb[(size_t)(b*TSZ + o)*LLEN + l] = a;
  }
}

// ---------------- fp32 tiled GEMM: Y[b] = W[M,256] @ X[b][256,1024]  ----------------
// MODE 0: ip  (X = hbuf + dpe broadcast, Y = y1, M=512)
// MODE 1: op  (X = gated, epilogue: res->hbuf, skip->skipb, M=512)
// MODE 2: out1 (X = skipb*1/sqrt6, relu, Y = zbuf, M=256)
template<int MODE>
__global__ __launch_bounds__(256) void gemm_k(const float* __restrict__ W, const float* __restrict__ bias,
                                              const float* __restrict__ X, float* __restrict__ Y,
                                              const float* __restrict__ dpev, float* __restrict__ hbuf,
                                              float* __restrict__ skipb, int first){
  __shared__ float Ws[16][64];
  __shared__ float Xs[16][128];
  int tid = threadIdx.x;
  int tx = tid & 15, ty = tid >> 4;
  int n0 = blockIdx.x * 128;
  int m0 = blockIdx.y * 64;
  int bz = blockIdx.z;
  const float* Xb = X + (size_t)bz * (TSZ*LLEN);
  float acc[4][8];
#pragma unroll
  for (int i=0;i<4;i++)
#pragma unroll
    for (int j=0;j<8;j++) acc[i][j]=0.f;

  int wm = tid >> 2;            // 0..63
  int wk = (tid & 3) * 4;       // 0,4,8,12
  int xr = tid >> 5;            // 0..7
  int xc = (tid & 31) * 4;      // 0..124

  for (int kt=0; kt<16; kt++){
    int k0 = kt*16;
    { // W tile (stored transposed [k][m])
      const float* wp = W + (size_t)(m0+wm)*256 + k0 + wk;
      float4 uv = *(const float4*)wp;
      Ws[wk+0][wm] = uv.x;
      Ws[wk+1][wm] = uv.y;
      Ws[wk+2][wm] = uv.z;
      Ws[wk+3][wm] = uv.w;
    }
    { // X tile
#pragma unroll
      for (int rr=0; rr<2; rr++){
        int r = xr + rr*8;
        float4 v = *(const float4*)(Xb + (size_t)(k0+r)*LLEN + n0 + xc);
        if (MODE==0){
          float dval = dpev[bz*TSZ + k0 + r];
          v.x += dval; v.y += dval; v.z += dval; v.w += dval;
        }
        if (MODE==2){ v.x *= IS6; v.y *= IS6; v.z *= IS6; v.w *= IS6; }
        *(float4*)&Xs[r][xc] = v;
      }
    }
    __syncthreads();
#pragma unroll
    for (int k=0;k<16;k++){
      float4 av = *(const float4*)&Ws[k][ty*4];
      float4 b0 = *(const float4*)&Xs[k][tx*8];
      float4 b1 = *(const float4*)&Xs[k][tx*8+4];
      float a[4]  = {av.x,av.y,av.z,av.w};
      float bv[8] = {b0.x,b0.y,b0.z,b0.w,b1.x,b1.y,b1.z,b1.w};
#pragma unroll
      for (int i=0;i<4;i++)
#pragma unroll
        for (int j=0;j<8;j++)
          acc[i][j] = fmaf(a[i], bv[j], acc[i][j]);
    }
    __syncthreads();
  }
#pragma unroll
  for (int i=0;i<4;i++){
    int m = m0 + ty*4 + i;
    float bvv = bias[m];
    int n = n0 + tx*8;
    float4 v0 = make_float4(acc[i][0]+bvv, acc[i][1]+bvv, acc[i][2]+bvv, acc[i][3]+bvv);
    float4 v1 = make_float4(acc[i][4]+bvv, acc[i][5]+bvv, acc[i][6]+bvv, acc[i][7]+bvv);
    if (MODE==0){
      float* yp = Y + ((size_t)bz*HSZ + m)*LLEN + n;
      *(float4*)yp = v0; *(float4*)(yp+4) = v1;
    } else if (MODE==2){
      v0.x=fmaxf(v0.x,0.f); v0.y=fmaxf(v0.y,0.f); v0.z=fmaxf(v0.z,0.f); v0.w=fmaxf(v0.w,0.f);
      v1.x=fmaxf(v1.x,0.f); v1.y=fmaxf(v1.y,0.f); v1.z=fmaxf(v1.z,0.f); v1.w=fmaxf(v1.w,0.f);
      float* yp = Y + ((size_t)bz*TSZ + m)*LLEN + n;
      *(float4*)yp = v0; *(float4*)(yp+4) = v1;
    } else {
      if (m < TSZ){
        float* hp = hbuf + ((size_t)bz*TSZ + m)*LLEN + n;
        float4 h0 = *(float4*)hp; float4 h1 = *(float4*)(hp+4);
        h0.x=(h0.x+v0.x)*RS2; h0.y=(h0.y+v0.y)*RS2; h0.z=(h0.z+v0.z)*RS2; h0.w=(h0.w+v0.w)*RS2;
        h1.x=(h1.x+v1.x)*RS2; h1.y=(h1.y+v1.y)*RS2; h1.z=(h1.z+v1.z)*RS2; h1.w=(h1.w+v1.w)*RS2;
        *(float4*)hp = h0; *(float4*)(hp+4) = h1;
      } else {
        float* sp = skipb + ((size_t)bz*TSZ + (m-TSZ))*LLEN + n;
        if (first){
          *(float4*)sp = v0; *(float4*)(sp+4) = v1;
        } else {
          float4 s0 = *(float4*)sp; float4 s1 = *(float4*)(sp+4);
          s0.x+=v0.x; s0.y+=v0.y; s0.z+=v0.z; s0.w+=v0.w;
          s1.x+=v1.x; s1.y+=v1.y; s1.z+=v1.z; s1.w+=v1.w;
          *(float4*)sp = s0; *(float4*)(sp+4) = s1;
        }
      }
    }
  }
}

// ---------------- S4D chunked scan ----------------
// phase1: per (b,h,chunk) local final state with zero init
__global__ __launch_bounds__(256,1) void s4_phase1(const float2* __restrict__ lamq,
                                                   const float* __restrict__ u,
                                                   float2* __restrict__ sloc){
  int gid = blockIdx.x*256 + threadIdx.x;     // ((b*512)+h)*16 + c
  int c = gid & (NCHUNK-1);
  int h = (gid >> 4) & (HSZ-1);
  int b = gid >> 13;
  const float2* lp = lamq + h*NST;
  float lre[NST], lim[NST], sre[NST], sim[NST];
#pragma unroll
  for (int n=0;n<NST;n++){ float2 t=lp[n]; lre[n]=t.x; lim[n]=t.y; sre[n]=0.f; sim[n]=0.f; }
  const float4* up = (const float4*)(u + (size_t)(b*HSZ+h)*LLEN + c*LCHUNK);
#pragma unroll 1
  for (int i=0;i<LCHUNK/4;i++){
    float4 uv = up[i];
    float us[4] = {uv.x, uv.y, uv.z, uv.w};
#pragma unroll
    for (int e=0;e<4;e++){
      float uu = us[e];
#pragma unroll
      for (int n=0;n<NST;n++){
        float nr = fmaf(lre[n], sre[n], fmaf(-lim[n], sim[n], uu));
        float ni = fmaf(lre[n], sim[n], lim[n]*sre[n]);
        sre[n]=nr; sim[n]=ni;
      }
    }
  }
  float2* sp = sloc + (size_t)((b*HSZ+h)*NCHUNK + c)*NST;
#pragma unroll
  for (int n=0;n<NST;n++) sp[n] = make_float2(sre[n], sim[n]);
}

// combine: sequential prefix over 16 chunks; sloc[c] overwritten with chunk INITIAL state
__global__ void s4_combine(const float2* __restrict__ lamPq, float2* __restrict__ sloc){
  int gid = blockIdx.x*256 + threadIdx.x;     // ((b*512)+h)*32 + n
  int n = gid & 31;
  int h = (gid>>5) & 511;
  int b = gid >> 14;
  float2 lp = lamPq[h*NST + n];
  float2* sp = sloc + (size_t)((b*HSZ + h)*NCHUNK)*NST + n;
  float Sre = 0.f, Sim = 0.f;
#pragma unroll
  for (int cc=0; cc<NCHUNK; cc++){
    float2 cur = sp[cc*NST];
    sp[cc*NST] = make_float2(Sre, Sim);
    float nr = fmaf(lp.x, Sre, fmaf(-lp.y, Sim, cur.x));
    float ni = fmaf(lp.x, Sim, fmaf(lp.y, Sre, cur.y));
    Sre = nr; Sim = ni;
  }
}

// phase2: re-run scan from the chunk's initial state, emit y = Re(sum C'*s) + D*u
__global__ __launch_bounds__(256,1) void s4_phase2(const float2* __restrict__ lamq,
                                                   const float2* __restrict__ Cq,
                                                   const float* __restrict__ Dq,
                                                   const float* __restrict__ u,
                                                   const float2* __restrict__ sloc,
                                                   float* __restrict__ y){
  int gid = blockIdx.x*256 + threadIdx.x;
  int c = gid & (NCHUNK-1);
  int h = (gid >> 4) & (HSZ-1);
  int b = gid >> 13;
  const float2* lp = lamq + h*NST;
  const float2* cp = Cq + h*NST;
  const float2* ip = sloc + (size_t)((b*HSZ+h)*NCHUNK + c)*NST;
  float lre[NST], lim[NST], cre[NST], cim[NST], sre[NST], sim[NST];
#pragma unroll
  for (int n=0;n<NST;n++){
    float2 t  = lp[n]; lre[n]=t.x;  lim[n]=t.y;
    float2 t2 = cp[n]; cre[n]=t2.x; cim[n]=t2.y;
    float2 t3 = ip[n]; sre[n]=t3.x; sim[n]=t3.y;
  }
  float dv = Dq[h];
  size_t base = (size_t)(b*HSZ+h)*LLEN + c*LCHUNK;
  const float4* up = (const float4*)(u + base);
  float4* yp = (float4*)(y + base);
#pragma unroll 1
  for (int i=0;i<LCHUNK/4;i++){
    float4 uv = up[i];
    float us[4] = {uv.x,uv.y,uv.z,uv.w};
    float os[4];
#pragma unroll
    for (int e=0;e<4;e++){
      float uu = us[e];
      float acc = dv*uu;
#pragma unroll
      for (int n=0;n<NST;n++){
        float nr = fmaf(lre[n], sre[n], fmaf(-lim[n], sim[n], uu));
        float ni = fmaf(lre[n], sim[n], lim[n]*sre[n]);
        sre[n]=nr; sim[n]=ni;
        acc = fmaf(cre[n], nr, acc);
        acc = fmaf(-cim[n], ni, acc);
      }
      os[e]=acc;
    }
    yp[i] = make_float4(os[0],os[1],os[2],os[3]);
  }
}

// ---------------- channel LayerNorm over 512 channels ----------------
__global__ __launch_bounds__(256) void ln_kernel(const float* __restrict__ in, float* __restrict__ out,
                                                 const float* __restrict__ g, const float* __restrict__ bt){
  __shared__ float rs[4][64];
  __shared__ float rq[4][64];
  __shared__ float mbuf[64], rbuf[64];
  int tid = threadIdx.x;
  int hg = tid >> 6;
  int lo = tid & 63;
  int b = blockIdx.x >> 4;
  int l = ((blockIdx.x & 15) << 6) + lo;
  size_t base = (size_t)(b*HSZ)*LLEN + l;
  float s=0.f, ss=0.f;
  for (int hh=0; hh<128; hh++){
    float v = in[base + (size_t)(hg*128+hh)*LLEN];
    s += v; ss = fmaf(v,v,ss);
  }
  rs[hg][lo]=s; rq[hg][lo]=ss;
  __syncthreads();
  if (tid < 64){
    float S = rs[0][tid]+rs[1][tid]+rs[2][tid]+rs[3][tid];
    float Q = rq[0][tid]+rq[1][tid]+rq[2][tid]+rq[3][tid];
    float mean = S * (1.f/HSZ);
    float var  = Q * (1.f/HSZ) - mean*mean;
    mbuf[tid]=mean;
    rbuf[tid]=rsqrtf(var + 1e-5f);
  }
  __syncthreads();
  float mean = mbuf[lo], rstd = rbuf[lo];
  for (int hh=0; hh<128; hh++){
    int h = hg*128+hh;
    float v = in[base + (size_t)h*LLEN];
    out[base + (size_t)h*LLEN] = (v-mean)*rstd*g[h] + bt[h];
  }
}

// ---------------- gate: sigmoid(y[:256]) * tanh(y[256:]) ----------------
__global__ void gate_kernel(const float* __restrict__ in, float* __restrict__ outp){
  int gid = blockIdx.x*256 + threadIdx.x;
  int l4 = gid & 255;
  int tt = (gid>>8) & 255;
  int b = gid >> 16;
  float4 gv = *(const float4*)(in + (size_t)(b*HSZ+tt)*LLEN + l4*4);
  float4 fv = *(const float4*)(in + (size_t)(b*HSZ+256+tt)*LLEN + l4*4);
  float4 o;
  o.x = (1.f/(1.f+__expf(-gv.x))) * (1.f - 2.f/(__expf(2.f*fv.x)+1.f));
  o.y = (1.f/(1.f+__expf(-gv.y))) * (1.f - 2.f/(__expf(2.f*fv.y)+1.f));
  o.z = (1.f/(1.f+__expf(-gv.z))) * (1.f - 2.f/(__expf(2.f*fv.z)+1.f));
  o.w = (1.f/(1.f+__expf(-gv.w))) * (1.f - 2.f/(__expf(2.f*fv.w)+1.f));
  *(float4*)(outp + (size_t)(b*TSZ+tt)*LLEN + l4*4) = o;
}

// ---------------- out2 projection + 1/sqrt(beta) + transpose to [B,L,14] --------
__global__ __launch_bounds__(256) void out2_kernel(const float* __restrict__ w2, const float* __restrict__ b2,
                                                   const float* __restrict__ t, const float* __restrict__ z,
                                                   float* __restrict__ outp){
  __shared__ float ws[14*256];
  __shared__ float bs[14];
  int tid = threadIdx.x;
#pragma unroll
  for (int c=0;c<14;c++) ws[c*256+tid] = w2[c*256+tid];
  if (tid < 14) bs[tid] = b2[tid];
  __syncthreads();
  int b = blockIdx.x >> 2;
  int l = ((blockIdx.x & 3) << 8) + tid;
  float tb = t[b];
  float scale = rsqrtf(1e-4f + tb*(2e-2f - 1e-4f));
  float acc[14];
#pragma unroll
  for (int c=0;c<14;c++) acc[c]=0.f;
  const float* zp = z + (size_t)b*TSZ*LLEN + l;
  for (int tt2=0; tt2<256; tt2++){
    float xv = zp[(size_t)tt2*LLEN];
#pragma unroll
    for (int c=0;c<14;c++) acc[c] = fmaf(ws[c*256+tt2], xv, acc[c]);
  }
  float* op = outp + (size_t)(b*LLEN + l)*CINN;
#pragma unroll
  for (int c=0;c<14;c++) op[c] = (acc[c]+bs[c])*scale;
}

// ---------------- host launcher ----------------
extern "C" void kernel_launch(void* const* d_in, const int* in_sizes, int n_in,
                              void* d_out, int out_size, void* d_ws, size_t ws_size,
                              hipStream_t stream) {
  (void)in_sizes; (void)n_in; (void)out_size;
  if (ws_size < (size_t)WS_FLOATS * 4) return;   // fail visibly rather than corrupt

  const float* x      = (const float*)d_in[0];
  const float* t      = (const float*)d_in[1];
  const float* gfpW   = (const float*)d_in[2];
  const float* ew1    = (const float*)d_in[3];
  const float* eb1    = (const float*)d_in[4];
  const float* ew2    = (const float*)d_in[5];
  const float* eb2    = (const float*)d_in[6];
  const float* in_w   = (const float*)d_in[7];
  const float* in_b   = (const float*)d_in[8];
  const float* out1_w = (const float*)d_in[9];
  const float* out1_b = (const float*)d_in[10];
  const float* out2_w = (const float*)d_in[11];
  const float* out2_b = (const float*)d_in[12];
  const float* dp_w   = (const float*)d_in[13];
  const float* dp_b   = (const float*)d_in[14];
  const float* ip_w   = (const float*)d_in[15];
  const float* ip_b   = (const float*)d_in[16];
  const float* op_w   = (const float*)d_in[17];
  const float* op_b   = (const float*)d_in[18];
  const float* log_dt = (const float*)d_in[19];
  const float* logA   = (const float*)d_in[20];
  const float* Aim    = (const float*)d_in[21];
  const float* Cre    = (const float*)d_in[22];
  const float* Cim    = (const float*)d_in[23];
  const float* s4D    = (const float*)d_in[24];
  const float* ln_g   = (const float*)d_in[25];
  const float* ln_b   = (const float*)d_in[26];
  float* out = (float*)d_out;
  float* ws = (float*)d_ws;

  float2* lam2  = (float2*)(ws + OFF_LAM);
  float2* C2v   = (float2*)(ws + OFF_C);
  float2* lamP2 = (float2*)(ws + OFF_LAMP);
  float* embb  = ws + OFF_EMB;
  float* dpeb  = ws + OFF_DPE;
  float* hbuf  = ws + OFF_H;
  float* skipb = ws + OFF_SKIP;
  float* y1    = ws + OFF_Y1;
  float* y2    = ws + OFF_Y2;
  float2* sloc = (float2*)(ws + OFF_SLOC);

  consts_kernel<<<768,256,0,stream>>>(log_dt, logA, Aim, Cre, Cim, lam2, C2v, lamP2);
  emb_kernel<<<BB,128,0,stream>>>(t, gfpW, ew1, eb1, ew2, eb2, embb);
  dpe_kernel<<<NDEPTH*BB,256,0,stream>>>(embb, dp_w, dp_b, dpeb);
  inproj_kernel<<<64,256,0,stream>>>(x, in_w, in_b, hbuf);

  for (int d=0; d<NDEPTH; d++){
    int q0 = d*2, q1 = d*2+1;
    // ip projection (with dpe broadcast add)
    gemm_k<0><<<dim3(8,8,16),256,0,stream>>>(ip_w + (size_t)d*HSZ*TSZ, ip_b + d*HSZ,
                                             hbuf, y1, dpeb + (size_t)d*BB*TSZ,
                                             nullptr, nullptr, 0);
    // S4 layer j=0: y1 -> y2
    s4_phase1<<<512,256,0,stream>>>(lam2 + (size_t)q0*QHN, y1, sloc);
    s4_combine<<<1024,256,0,stream>>>(lamP2 + (size_t)q0*QHN, sloc);
    s4_phase2<<<512,256,0,stream>>>(lam2 + (size_t)q0*QHN, C2v + (size_t)q0*QHN,
                                    s4D + q0*HSZ, y1, sloc, y2);
    ln_kernel<<<256,256,0,stream>>>(y2, y1, ln_g + q0*HSZ, ln_b + q0*HSZ);
    // S4 layer j=1: y1 -> y2
    s4_phase1<<<512,256,0,stream>>>(lam2 + (size_t)q1*QHN, y1, sloc);
    s4_combine<<<1024,256,0,stream>>>(lamP2 + (size_t)q1*QHN, sloc);
    s4_phase2<<<512,256,0,stream>>>(lam2 + (size_t)q1*QHN, C2v + (size_t)q1*QHN,
                                    s4D + q1*HSZ, y1, sloc, y2);
    ln_kernel<<<256,256,0,stream>>>(y2, y1, ln_g + q1*HSZ, ln_b + q1*HSZ);
    // gate: y1 -> y2 (first 16MB used as [B,256,L])
    gate_kernel<<<4096,256,0,stream>>>(y1, y2);
    // op projection + residual/skip epilogue
    gemm_k<1><<<dim3(8,8,16),256,0,stream>>>(op_w + (size_t)d*HSZ*TSZ, op_b + d*HSZ,
                                             y2, y1, nullptr, hbuf, skipb, (d==0)?1:0);
  }
  // out1 (relu, input scaled by 1/sqrt(6)): skipb -> y1
  gemm_k<2><<<dim3(8,4,16),256,0,stream>>>(out1_w, out1_b, skipb, y1,
                                           nullptr, nullptr, nullptr, 0);
  // out2 + 1/sqrt(beta) + transpose
  out2_kernel<<<64,256,0,stream>>>(out2_w, out2_b, t, y1, out);
}

// Round 3
// 2254.239 us; speedup vs baseline: 1.1406x; 1.1406x over previous
//
#include <hip/hip_runtime.h>

// ---------------- problem constants ----------------
#define BB     16
#define LLEN   1024
#define CINN   14
#define TSZ    256
#define HSZ    512
#define NST    32
#define ESZ    128
#define NDEPTH 6
#define NCHUNK 16
#define LCHUNK 64
#define QHN    (HSZ*NST)   // per-(d,j) const stride = 16384

#define RS2 0.70710678118654752f   // 1/sqrt(2)
#define IS6 0.40824829046386302f   // 1/sqrt(6)

// LDS swizzle for s4 staging: chunk stride 65, row stride 1040 (floats)
#define CSTR 65
#define RSTR 1040

typedef unsigned short u16;
typedef unsigned int   u32;

// workspace layout (float offsets)
#define OFF_LAM  0u
#define OFF_C    393216u
#define OFF_EMB  1179648u
#define OFF_DPE  1181696u
#define OFF_H    1206272u
#define OFF_SKIP 5400576u
#define OFF_Y1   9594880u
#define OFF_Y2   17983488u
#define WS_FLOATS 26372096u

// ---------------- S4D constants: lambda = exp(dt*A), C' = 2*C*(lambda-1)/A ----
__global__ void consts_kernel(const float* __restrict__ log_dt, const float* __restrict__ logA,
                              const float* __restrict__ Aim,   const float* __restrict__ Cre,
                              const float* __restrict__ Cim,
                              float2* __restrict__ lam2, float2* __restrict__ C2){
  int gid = blockIdx.x*256 + threadIdx.x;            // q*16384 + h*32 + n
  int h = (gid>>5) & 511;
  int q = gid >> 14;
  float dt  = expf(log_dt[q*HSZ + h]);
  float are = -expf(logA[gid]);
  float aim = Aim[gid];
  float dre = are*dt, dim = aim*dt;
  float e   = expf(dre);
  float lre = e*cosf(dim), lim = e*sinf(dim);
  float nre = lre - 1.f, nim = lim;
  float invden = 1.f/(are*are + aim*aim);
  float tre = (nre*are + nim*aim)*invden;
  float tim = (nim*are - nre*aim)*invden;
  float cr = Cre[gid], ci = Cim[gid];
  float Cr = 2.f*(cr*tre - ci*tim);
  float Ci = 2.f*(cr*tim + ci*tre);
  lam2[gid] = make_float2(lre, lim);
  C2[gid]   = make_float2(Cr, Ci);
}

// ---------------- diffusion embedding MLP ----------------
__global__ void emb_kernel(const float* __restrict__ t, const float* __restrict__ gw,
                           const float* __restrict__ w1, const float* __restrict__ b1,
                           const float* __restrict__ w2, const float* __restrict__ b2,
                           float* __restrict__ emb){
  __shared__ float e0[128], e1[128];
  int b = blockIdx.x, tid = threadIdx.x;
  float tb = t[b];
  if (tid < 64){
    float xp = tb * gw[tid] * 6.283185307179586f;
    e0[tid]    = sinf(xp);
    e0[tid+64] = cosf(xp);
  }
  __syncthreads();
  float a = b1[tid];
  for (int i=0;i<128;i++) a = fmaf(e0[i], w1[tid*128+i], a);
  a = a / (1.f + __expf(-a));            // silu
  e1[tid] = a;
  __syncthreads();
  float a2 = b2[tid];
  for (int i=0;i<128;i++) a2 = fmaf(e1[i], w2[tid*128+i], a2);
  a2 = a2 / (1.f + __expf(-a2));
  emb[b*ESZ + tid] = a2;
}

// ---------------- per-depth diffusion projection (emb @ dp_w^T + dp_b) ----------------
__global__ void dpe_kernel(const float* __restrict__ emb, const float* __restrict__ dw,
                           const float* __restrict__ db, float* __restrict__ dpe){
  int blk = blockIdx.x; int d = blk >> 4; int b = blk & 15; int o = threadIdx.x;
  const float* wp = dw + (size_t)(d*TSZ + o)*ESZ;
  const float* ep = emb + b*ESZ;
  float a = db[d*TSZ + o];
  for (int e=0;e<128;e++) a = fmaf(ep[e], wp[e], a);
  dpe[(size_t)(d*BB + b)*TSZ + o] = a;
}

// ---------------- input projection [B,L,14] -> h [B,256,L] ----------------
__global__ __launch_bounds__(256) void inproj_kernel(const float* __restrict__ x, const float* __restrict__ w,
                                                     const float* __restrict__ bias, float* __restrict__ hb){
  __shared__ float ws[256*14];
  __shared__ float bs[256];
  int tid = threadIdx.x;
#pragma unroll
  for (int c=0;c<14;c++) ws[tid*14+c] = w[tid*14+c];
  bs[tid] = bias[tid];
  __syncthreads();
  int b = blockIdx.x >> 2;
  int l = ((blockIdx.x & 3) << 8) + tid;
  float xv[14];
  const float* xp = x + (size_t)(b*LLEN + l)*CINN;
#pragma unroll
  for (int c=0;c<14;c++) xv[c] = xp[c];
  for (int o=0;o<256;o++){
    float a = bs[o];
#pragma unroll
    for (int c=0;c<14;c++) a = fmaf(ws[o*14+c], xv[c], a);
    hb[(size_t)(b*TSZ + o)*LLEN + l] = a;
  }
}

// ---------------- fp32 tiled GEMM: Y[b] = W[M,256] @ X[b][256,1024]  ----------------
// MODE 0: ip  (X = hbuf + dpe broadcast, Y = y1, M=512)
// MODE 1: op  (X = gated, epilogue: res->hbuf, skip->skipb, M=512)
// MODE 2: out1 (X = skipb*1/sqrt6, relu, Y = zbuf, M=256)
template<int MODE>
__global__ __launch_bounds__(256) void gemm_k(const float* __restrict__ W, const float* __restrict__ bias,
                                              const float* __restrict__ X, float* __restrict__ Y,
                                              const float* __restrict__ dpev, float* __restrict__ hbuf,
                                              float* __restrict__ skipb, int first){
  __shared__ float Ws[16][64];
  __shared__ float Xs[16][128];
  int tid = threadIdx.x;
  int tx = tid & 15, ty = tid >> 4;
  int n0 = blockIdx.x * 128;
  int m0 = blockIdx.y * 64;
  int bz = blockIdx.z;
  const float* Xb = X + (size_t)bz * (TSZ*LLEN);
  float acc[4][8];
#pragma unroll
  for (int i=0;i<4;i++)
#pragma unroll
    for (int j=0;j<8;j++) acc[i][j]=0.f;

  int wm = tid >> 2;            // 0..63
  int wk = (tid & 3) * 4;       // 0,4,8,12
  int xr = tid >> 5;            // 0..7
  int xc = (tid & 31) * 4;      // 0..124

  for (int kt=0; kt<16; kt++){
    int k0 = kt*16;
    { // W tile (stored transposed [k][m])
      const float* wp = W + (size_t)(m0+wm)*256 + k0 + wk;
      float4 uv = *(const float4*)wp;
      Ws[wk+0][wm] = uv.x;
      Ws[wk+1][wm] = uv.y;
      Ws[wk+2][wm] = uv.z;
      Ws[wk+3][wm] = uv.w;
    }
    { // X tile
#pragma unroll
      for (int rr=0; rr<2; rr++){
        int r = xr + rr*8;
        float4 v = *(const float4*)(Xb + (size_t)(k0+r)*LLEN + n0 + xc);
        if (MODE==0){
          float dval = dpev[bz*TSZ + k0 + r];
          v.x += dval; v.y += dval; v.z += dval; v.w += dval;
        }
        if (MODE==2){ v.x *= IS6; v.y *= IS6; v.z *= IS6; v.w *= IS6; }
        *(float4*)&Xs[r][xc] = v;
      }
    }
    __syncthreads();
#pragma unroll
    for (int k=0;k<16;k++){
      float4 av = *(const float4*)&Ws[k][ty*4];
      float4 b0 = *(const float4*)&Xs[k][tx*8];
      float4 b1 = *(const float4*)&Xs[k][tx*8+4];
      float a[4]  = {av.x,av.y,av.z,av.w};
      float bv[8] = {b0.x,b0.y,b0.z,b0.w,b1.x,b1.y,b1.z,b1.w};
#pragma unroll
      for (int i=0;i<4;i++)
#pragma unroll
        for (int j=0;j<8;j++)
          acc[i][j] = fmaf(a[i], bv[j], acc[i][j]);
    }
    __syncthreads();
  }
#pragma unroll
  for (int i=0;i<4;i++){
    int m = m0 + ty*4 + i;
    float bvv = bias[m];
    int n = n0 + tx*8;
    float4 v0 = make_float4(acc[i][0]+bvv, acc[i][1]+bvv, acc[i][2]+bvv, acc[i][3]+bvv);
    float4 v1 = make_float4(acc[i][4]+bvv, acc[i][5]+bvv, acc[i][6]+bvv, acc[i][7]+bvv);
    if (MODE==0){
      float* yp = Y + ((size_t)bz*HSZ + m)*LLEN + n;
      *(float4*)yp = v0; *(float4*)(yp+4) = v1;
    } else if (MODE==2){
      v0.x=fmaxf(v0.x,0.f); v0.y=fmaxf(v0.y,0.f); v0.z=fmaxf(v0.z,0.f); v0.w=fmaxf(v0.w,0.f);
      v1.x=fmaxf(v1.x,0.f); v1.y=fmaxf(v1.y,0.f); v1.z=fmaxf(v1.z,0.f); v1.w=fmaxf(v1.w,0.f);
      float* yp = Y + ((size_t)bz*TSZ + m)*LLEN + n;
      *(float4*)yp = v0; *(float4*)(yp+4) = v1;
    } else {
      if (m < TSZ){
        float* hp = hbuf + ((size_t)bz*TSZ + m)*LLEN + n;
        float4 h0 = *(float4*)hp; float4 h1 = *(float4*)(hp+4);
        h0.x=(h0.x+v0.x)*RS2; h0.y=(h0.y+v0.y)*RS2; h0.z=(h0.z+v0.z)*RS2; h0.w=(h0.w+v0.w)*RS2;
        h1.x=(h1.x+v1.x)*RS2; h1.y=(h1.y+v1.y)*RS2; h1.z=(h1.z+v1.z)*RS2; h1.w=(h1.w+v1.w)*RS2;
        *(float4*)hp = h0; *(float4*)(hp+4) = h1;
      } else {
        float* sp = skipb + ((size_t)bz*TSZ + (m-TSZ))*LLEN + n;
        if (first){
          *(float4*)sp = v0; *(float4*)(sp+4) = v1;
        } else {
          float4 s0 = *(float4*)sp; float4 s1 = *(float4*)(sp+4);
          s0.x+=v0.x; s0.y+=v0.y; s0.z+=v0.z; s0.w+=v0.w;
          s1.x+=v1.x; s1.y+=v1.y; s1.z+=v1.z; s1.w+=v1.w;
          *(float4*)sp = s0; *(float4*)(sp+4) = s1;
        }
      }
    }
  }
}

// ---------------- fused S4D: stage->phase1->shfl combine->phase2->write ----------------
// block: 256 threads = 16 rows (one b, 16 consecutive h) x 16 chunks of 64.
// LDS: swizzled u/y buffer, chunk stride 65 floats, row stride 1040 floats (66.56 KB).
// in-place safe (u may equal y).
__global__ __launch_bounds__(256,2) void s4_fused(const float2* __restrict__ lamq,
                                                  const float2* __restrict__ Cq,
                                                  const float* __restrict__ Dq,
                                                  const float* u, float* y){
  __shared__ float uly[16*RSTR];
  int tid = threadIdx.x;
  int b = blockIdx.x >> 5;
  int hbase = (blockIdx.x & 31) * 16;
  int rowBase = b*HSZ + hbase;

  // ---- stage u -> LDS (coalesced float4 reads, swizzled scalar LDS writes)
#pragma unroll
  for (int i=0;i<16;i++){
    int fidx = i*256 + tid;          // float4 index, 0..4095
    int row = fidx >> 8;             // 0..15
    int l   = (fidx & 255) * 4;      // 0..1020
    float4 v = *(const float4*)(u + (size_t)(rowBase + row)*LLEN + l);
    int a = row*RSTR + (l>>6)*CSTR + (l & 63);
    uly[a+0]=v.x; uly[a+1]=v.y; uly[a+2]=v.z; uly[a+3]=v.w;
  }
  __syncthreads();

  int c    = tid & 15;               // chunk index = lane-in-16-segment
  int hrow = tid >> 4;               // 0..15
  int h    = hbase + hrow;
  int ubase = hrow*RSTR + c*CSTR;

  // ---- load lambda, init states
  float lre[NST], lim[NST], sre[NST], sim[NST];
  const float2* lp = lamq + h*NST;
#pragma unroll
  for (int n=0;n<NST;n++){ float2 t=lp[n]; lre[n]=t.x; lim[n]=t.y; sre[n]=0.f; sim[n]=0.f; }

  // ---- phase 1: local scan (zero init) over own chunk
#pragma unroll 2
  for (int j=0;j<LCHUNK;j++){
    float uu = uly[ubase + j];
#pragma unroll
    for (int n=0;n<NST;n++){
      float nr = fmaf(lre[n], sre[n], fmaf(-lim[n], sim[n], uu));
      float ni = fmaf(lre[n], sim[n], lim[n]*sre[n]);
      sre[n]=nr; sim[n]=ni;
    }
  }

  // ---- combine: exclusive prefix of chunk transforms across 16 lanes (per n)
  // chunk transform: x -> M x + s_c, M = lambda^64. Hillis-Steele with shuffles.
#pragma unroll 4
  for (int n=0;n<NST;n++){
    // M = lambda^64 via 6 squarings
    float mr = lre[n], mi = lim[n];
#pragma unroll
    for (int k=0;k<6;k++){ float t2 = mr*mr - mi*mi; mi = 2.f*mr*mi; mr = t2; }
    float Sr = sre[n], Si = sim[n];
#pragma unroll
    for (int d=1; d<16; d<<=1){
      float tr = __shfl_up(Sr, (unsigned)d, 16);
      float ti = __shfl_up(Si, (unsigned)d, 16);
      float nr2 = fmaf(mr, tr, fmaf(-mi, ti, Sr));
      float ni2 = fmaf(mr, ti, fmaf(mi, tr, Si));
      bool ok = (c >= d);
      Sr = ok ? nr2 : Sr;  Si = ok ? ni2 : Si;
      float t2 = mr*mr - mi*mi; mi = 2.f*mr*mi; mr = t2;
    }
    // exclusive: take inclusive result of lane c-1; chunk 0 starts at zero
    float er = __shfl_up(Sr, 1u, 16);
    float ei = __shfl_up(Si, 1u, 16);
    sre[n] = (c==0) ? 0.f : er;
    sim[n] = (c==0) ? 0.f : ei;
  }

  // ---- phase 2: rescan from carried-in state, emit y in-place into LDS
  float cre[NST], cim[NST];
  const float2* cp = Cq + h*NST;
#pragma unroll
  for (int n=0;n<NST;n++){ float2 t=cp[n]; cre[n]=t.x; cim[n]=t.y; }
  float dv = Dq[h];
#pragma unroll 2
  for (int j=0;j<LCHUNK;j++){
    float uu = uly[ubase + j];
    float acc = dv*uu;
#pragma unroll
    for (int n=0;n<NST;n++){
      float nr = fmaf(lre[n], sre[n], fmaf(-lim[n], sim[n], uu));
      float ni = fmaf(lre[n], sim[n], lim[n]*sre[n]);
      sre[n]=nr; sim[n]=ni;
      acc = fmaf(cre[n], nr, acc);
      acc = fmaf(-cim[n], ni, acc);
    }
    uly[ubase + j] = acc;
  }
  __syncthreads();

  // ---- write out (coalesced float4)
#pragma unroll
  for (int i=0;i<16;i++){
    int fidx = i*256 + tid;
    int row = fidx >> 8;
    int l   = (fidx & 255) * 4;
    int a = row*RSTR + (l>>6)*CSTR + (l & 63);
    float4 v = make_float4(uly[a], uly[a+1], uly[a+2], uly[a+3]);
    *(float4*)(y + (size_t)(rowBase + row)*LLEN + l) = v;
  }
}

// ---------------- channel LayerNorm over 512 channels; GATED variant fuses
// sigmoid(gate)*tanh(filt) and writes packed [B,256,L] ----------------
template<int GATED>
__global__ __launch_bounds__(256) void ln_kernel(const float* in, float* out,
                                                 const float* __restrict__ g, const float* __restrict__ bt){
  __shared__ float rs[4][64];
  __shared__ float rq[4][64];
  __shared__ float mbuf[64], rbuf[64];
  int tid = threadIdx.x;
  int hg = tid >> 6;
  int lo = tid & 63;
  int b = blockIdx.x >> 4;
  int l = ((blockIdx.x & 15) << 6) + lo;
  size_t base = (size_t)(b*HSZ)*LLEN + l;
  float s=0.f, ss=0.f;
  for (int hh=0; hh<128; hh++){
    float v = in[base + (size_t)(hg*128+hh)*LLEN];
    s += v; ss = fmaf(v,v,ss);
  }
  rs[hg][lo]=s; rq[hg][lo]=ss;
  __syncthreads();
  if (tid < 64){
    float S = rs[0][tid]+rs[1][tid]+rs[2][tid]+rs[3][tid];
    float Q = rq[0][tid]+rq[1][tid]+rq[2][tid]+rq[3][tid];
    float mean = S * (1.f/HSZ);
    float var  = Q * (1.f/HSZ) - mean*mean;
    mbuf[tid]=mean;
    rbuf[tid]=rsqrtf(var + 1e-5f);
  }
  __syncthreads();
  float mean = mbuf[lo], rstd = rbuf[lo];
  if (!GATED){
    for (int hh=0; hh<128; hh++){
      int h = hg*128+hh;
      float v = in[base + (size_t)h*LLEN];
      out[base + (size_t)h*LLEN] = (v-mean)*rstd*g[h] + bt[h];
    }
  } else {
    size_t gbase = (size_t)(b*TSZ)*LLEN + l;
    for (int tt=0; tt<64; tt++){
      int t = hg*64 + tt;
      float a = (in[base + (size_t)t*LLEN]       - mean)*rstd*g[t]     + bt[t];
      float f = (in[base + (size_t)(t+256)*LLEN] - mean)*rstd*g[t+256] + bt[t+256];
      float sg = 1.f/(1.f+__expf(-a));
      float th = 1.f - 2.f/(__expf(2.f*f)+1.f);
      out[gbase + (size_t)t*LLEN] = sg*th;
    }
  }
}

// ---------------- out2 projection + 1/sqrt(beta) + transpose to [B,L,14] --------
__global__ __launch_bounds__(256) void out2_kernel(const float* __restrict__ w2, const float* __restrict__ b2,
                                                   const float* __restrict__ t, const float* __restrict__ z,
                                                   float* __restrict__ outp){
  __shared__ float ws[14*256];
  __shared__ float bs[14];
  int tid = threadIdx.x;
#pragma unroll
  for (int c=0;c<14;c++) ws[c*256+tid] = w2[c*256+tid];
  if (tid < 14) bs[tid] = b2[tid];
  __syncthreads();
  int b = blockIdx.x >> 2;
  int l = ((blockIdx.x & 3) << 8) + tid;
  float tb = t[b];
  float scale = rsqrtf(1e-4f + tb*(2e-2f - 1e-4f));
  float acc[14];
#pragma unroll
  for (int c=0;c<14;c++) acc[c]=0.f;
  const float* zp = z + (size_t)b*TSZ*LLEN + l;
  for (int tt2=0; tt2<256; tt2++){
    float xv = zp[(size_t)tt2*LLEN];
#pragma unroll
    for (int c=0;c<14;c++) acc[c] = fmaf(ws[c*256+tt2], xv, acc[c]);
  }
  float* op = outp + (size_t)(b*LLEN + l)*CINN;
#pragma unroll
  for (int c=0;c<14;c++) op[c] = (acc[c]+bs[c])*scale;
}

// ---------------- host launcher ----------------
extern "C" void kernel_launch(void* const* d_in, const int* in_sizes, int n_in,
                              void* d_out, int out_size, void* d_ws, size_t ws_size,
                              hipStream_t stream) {
  (void)in_sizes; (void)n_in; (void)out_size;
  if (ws_size < (size_t)WS_FLOATS * 4) return;   // fail visibly rather than corrupt

  const float* x      = (const float*)d_in[0];
  const float* t      = (const float*)d_in[1];
  const float* gfpW   = (const float*)d_in[2];
  const float* ew1    = (const float*)d_in[3];
  const float* eb1    = (const float*)d_in[4];
  const float* ew2    = (const float*)d_in[5];
  const float* eb2    = (const float*)d_in[6];
  const float* in_w   = (const float*)d_in[7];
  const float* in_b   = (const float*)d_in[8];
  const float* out1_w = (const float*)d_in[9];
  const float* out1_b = (const float*)d_in[10];
  const float* out2_w = (const float*)d_in[11];
  const float* out2_b = (const float*)d_in[12];
  const float* dp_w   = (const float*)d_in[13];
  const float* dp_b   = (const float*)d_in[14];
  const float* ip_w   = (const float*)d_in[15];
  const float* ip_b   = (const float*)d_in[16];
  const float* op_w   = (const float*)d_in[17];
  const float* op_b   = (const float*)d_in[18];
  const float* log_dt = (const float*)d_in[19];
  const float* logA   = (const float*)d_in[20];
  const float* Aim    = (const float*)d_in[21];
  const float* Cre    = (const float*)d_in[22];
  const float* Cim    = (const float*)d_in[23];
  const float* s4D    = (const float*)d_in[24];
  const float* ln_g   = (const float*)d_in[25];
  const float* ln_b   = (const float*)d_in[26];
  float* out = (float*)d_out;
  float* ws = (float*)d_ws;

  float2* lam2  = (float2*)(ws + OFF_LAM);
  float2* C2v   = (float2*)(ws + OFF_C);
  float* embb  = ws + OFF_EMB;
  float* dpeb  = ws + OFF_DPE;
  float* hbuf  = ws + OFF_H;
  float* skipb = ws + OFF_SKIP;
  float* y1    = ws + OFF_Y1;
  float* y2    = ws + OFF_Y2;

  consts_kernel<<<768,256,0,stream>>>(log_dt, logA, Aim, Cre, Cim, lam2, C2v);
  emb_kernel<<<BB,128,0,stream>>>(t, gfpW, ew1, eb1, ew2, eb2, embb);
  dpe_kernel<<<NDEPTH*BB,256,0,stream>>>(embb, dp_w, dp_b, dpeb);
  inproj_kernel<<<64,256,0,stream>>>(x, in_w, in_b, hbuf);

  for (int d=0; d<NDEPTH; d++){
    int q0 = d*2, q1 = d*2+1;
    // ip projection (with dpe broadcast add): hbuf -> y1
    gemm_k<0><<<dim3(8,8,16),256,0,stream>>>(ip_w + (size_t)d*HSZ*TSZ, ip_b + d*HSZ,
                                             hbuf, y1, dpeb + (size_t)d*BB*TSZ,
                                             nullptr, nullptr, 0);
    // S4 layer 0 (in place on y1)
    s4_fused<<<512,256,0,stream>>>(lam2 + (size_t)q0*QHN, C2v + (size_t)q0*QHN,
                                   s4D + q0*HSZ, y1, y1);
    // LN 0 (in place on y1)
    ln_kernel<0><<<256,256,0,stream>>>(y1, y1, ln_g + q0*HSZ, ln_b + q0*HSZ);
    // S4 layer 1 (in place on y1)
    s4_fused<<<512,256,0,stream>>>(lam2 + (size_t)q1*QHN, C2v + (size_t)q1*QHN,
                                   s4D + q1*HSZ, y1, y1);
    // LN 1 + gate fused: y1 -> y2 packed [B,256,L]
    ln_kernel<1><<<256,256,0,stream>>>(y1, y2, ln_g + q1*HSZ, ln_b + q1*HSZ);
    // op projection + residual/skip epilogue
    gemm_k<1><<<dim3(8,8,16),256,0,stream>>>(op_w + (size_t)d*HSZ*TSZ, op_b + d*HSZ,
                                             y2, y1, nullptr, hbuf, skipb, (d==0)?1:0);
  }
  // out1 (relu, input scaled by 1/sqrt(6)): skipb -> y1
  gemm_k<2><<<dim3(8,4,16),256,0,stream>>>(out1_w, out1_b, skipb, y1,
                                           nullptr, nullptr, nullptr, 0);
  // out2 + 1/sqrt(beta) + transpose
  out2_kernel<<<64,256,0,stream>>>(out2_w, out2_b, t, y1, out);
}

// Round 4
// 2016.155 us; speedup vs baseline: 1.2753x; 1.1181x over previous
//
#include <hip/hip_runtime.h>

// ---------------- problem constants ----------------
#define BB     16
#define LLEN   1024
#define CINN   14
#define TSZ    256
#define HSZ    512
#define NST    32
#define ESZ    128
#define NDEPTH 6
#define NCHUNK 16
#define LCHUNK 64
#define QHN    (HSZ*NST)   // per-(d,j) const stride = 16384

#define RS2 0.70710678118654752f   // 1/sqrt(2)
#define IS6 0.40824829046386302f   // 1/sqrt(6)

// LDS swizzle for s4 staging: chunk stride 65, row stride 1040 (floats)
#define CSTR 65
#define RSTR 1040

typedef unsigned short u16;
typedef unsigned int   u32;

// workspace layout (float offsets)
#define OFF_A    0u          // float2 (a1,a2) x 12*16384
#define OFF_B    393216u     // float2 (b0,b1) x 12*16384
#define OFF_M    786432u     // float4 M^64    x 12*16384
#define OFF_EMB  1572864u
#define OFF_DPE  1574912u
#define OFF_H    1599488u
#define OFF_SKIP 5793792u
#define OFF_Y1   9988096u
#define OFF_Y2   18376704u
#define WS_FLOATS 26765312u

// ---------------- S4D constants -> DF2 sections + chunk transition matrix ----------------
// lambda = exp(dt*A); C' = 2*C*(lambda-1)/A
// DF2: w[j] = u[j] + a1 w[j-1] + a2 w[j-2]; y += b0 w[j] + b1 w[j-1]
//   a1=2 Re(l), a2=-|l|^2, b0=Re(C'), b1=-(Re(C')Re(l)+Im(C')Im(l))
// n==0: lambda real -> 1st-order exact section (a2=b1=0).
// M = [[a1,a2],[1,0]]^64 per section (for chunk-prefix combine).
__global__ void consts_kernel(const float* __restrict__ log_dt, const float* __restrict__ logA,
                              const float* __restrict__ Aim,   const float* __restrict__ Cre,
                              const float* __restrict__ Cim,
                              float2* __restrict__ cA, float2* __restrict__ cB,
                              float4* __restrict__ cM){
  int gid = blockIdx.x*256 + threadIdx.x;            // q*16384 + h*32 + n
  int n = gid & 31;
  int h = (gid>>5) & 511;
  int q = gid >> 14;
  float dt  = expf(log_dt[q*HSZ + h]);
  float are = -expf(logA[gid]);
  float aim = Aim[gid];
  float dre = are*dt, dim = aim*dt;
  float e   = expf(dre);
  float lre = e*cosf(dim), lim = e*sinf(dim);
  float nre = lre - 1.f, nim = lim;
  float invden = 1.f/(are*are + aim*aim);
  float tre = (nre*are + nim*aim)*invden;
  float tim = (nim*are - nre*aim)*invden;
  float cr = Cre[gid], ci = Cim[gid];
  float Cr = 2.f*(cr*tre - ci*tim);
  float Ci = 2.f*(cr*tim + ci*tre);
  float a1, a2, b0, b1;
  if (n == 0){
    a1 = lre; a2 = 0.f; b0 = Cr; b1 = 0.f;
  } else {
    a1 = 2.f*lre;
    a2 = -(lre*lre + lim*lim);
    b0 = Cr;
    b1 = -(Cr*lre + Ci*lim);
  }
  cA[gid] = make_float2(a1, a2);
  cB[gid] = make_float2(b0, b1);
  // M^64 via 6 squarings of companion matrix [[a1,a2],[1,0]]
  float p = a1, qq = a2, r = 1.f, s = 0.f;
#pragma unroll
  for (int k=0;k<6;k++){
    float np_ = fmaf(p,p, qq*r);
    float nq  = qq*(p+s);
    float nr  = r*(p+s);
    float ns  = fmaf(s,s, qq*r);
    p=np_; qq=nq; r=nr; s=ns;
  }
  cM[gid] = make_float4(p, qq, r, s);
}

// ---------------- diffusion embedding MLP ----------------
__global__ void emb_kernel(const float* __restrict__ t, const float* __restrict__ gw,
                           const float* __restrict__ w1, const float* __restrict__ b1,
                           const float* __restrict__ w2, const float* __restrict__ b2,
                           float* __restrict__ emb){
  __shared__ float e0[128], e1[128];
  int b = blockIdx.x, tid = threadIdx.x;
  float tb = t[b];
  if (tid < 64){
    float xp = tb * gw[tid] * 6.283185307179586f;
    e0[tid]    = sinf(xp);
    e0[tid+64] = cosf(xp);
  }
  __syncthreads();
  float a = b1[tid];
  for (int i=0;i<128;i++) a = fmaf(e0[i], w1[tid*128+i], a);
  a = a / (1.f + __expf(-a));            // silu
  e1[tid] = a;
  __syncthreads();
  float a2 = b2[tid];
  for (int i=0;i<128;i++) a2 = fmaf(e1[i], w2[tid*128+i], a2);
  a2 = a2 / (1.f + __expf(-a2));
  emb[b*ESZ + tid] = a2;
}

// ---------------- per-depth diffusion projection (emb @ dp_w^T + dp_b) ----------------
__global__ void dpe_kernel(const float* __restrict__ emb, const float* __restrict__ dw,
                           const float* __restrict__ db, float* __restrict__ dpe){
  int blk = blockIdx.x; int d = blk >> 4; int b = blk & 15; int o = threadIdx.x;
  const float* wp = dw + (size_t)(d*TSZ + o)*ESZ;
  const float* ep = emb + b*ESZ;
  float a = db[d*TSZ + o];
  for (int e=0;e<128;e++) a = fmaf(ep[e], wp[e], a);
  dpe[(size_t)(d*BB + b)*TSZ + o] = a;
}

// ---------------- input projection [B,L,14] -> h [B,256,L] ----------------
__global__ __launch_bounds__(256) void inproj_kernel(const float* __restrict__ x, const float* __restrict__ w,
                                                     const float* __restrict__ bias, float* __restrict__ hb){
  __shared__ float ws[256*14];
  __shared__ float bs[256];
  int tid = threadIdx.x;
#pragma unroll
  for (int c=0;c<14;c++) ws[tid*14+c] = w[tid*14+c];
  bs[tid] = bias[tid];
  __syncthreads();
  int b = blockIdx.x >> 2;
  int l = ((blockIdx.x & 3) << 8) + tid;
  float xv[14];
  const float* xp = x + (size_t)(b*LLEN + l)*CINN;
#pragma unroll
  for (int c=0;c<14;c++) xv[c] = xp[c];
  for (int o=0;o<256;o++){
    float a = bs[o];
#pragma unroll
    for (int c=0;c<14;c++) a = fmaf(ws[o*14+c], xv[c], a);
    hb[(size_t)(b*TSZ + o)*LLEN + l] = a;
  }
}

// ---------------- fp32 tiled GEMM: Y[b] = W[M,256] @ X[b][256,1024]  ----------------
template<int MODE>
__global__ __launch_bounds__(256) void gemm_k(const float* __restrict__ W, const float* __restrict__ bias,
                                              const float* __restrict__ X, float* __restrict__ Y,
                                              const float* __restrict__ dpev, float* __restrict__ hbuf,
                                              float* __restrict__ skipb, int first){
  __shared__ float Ws[16][64];
  __shared__ float Xs[16][128];
  int tid = threadIdx.x;
  int tx = tid & 15, ty = tid >> 4;
  int n0 = blockIdx.x * 128;
  int m0 = blockIdx.y * 64;
  int bz = blockIdx.z;
  const float* Xb = X + (size_t)bz * (TSZ*LLEN);
  float acc[4][8];
#pragma unroll
  for (int i=0;i<4;i++)
#pragma unroll
    for (int j=0;j<8;j++) acc[i][j]=0.f;

  int wm = tid >> 2;            // 0..63
  int wk = (tid & 3) * 4;       // 0,4,8,12
  int xr = tid >> 5;            // 0..7
  int xc = (tid & 31) * 4;      // 0..124

  for (int kt=0; kt<16; kt++){
    int k0 = kt*16;
    {
      const float* wp = W + (size_t)(m0+wm)*256 + k0 + wk;
      float4 uv = *(const float4*)wp;
      Ws[wk+0][wm] = uv.x;
      Ws[wk+1][wm] = uv.y;
      Ws[wk+2][wm] = uv.z;
      Ws[wk+3][wm] = uv.w;
    }
    {
#pragma unroll
      for (int rr=0; rr<2; rr++){
        int r = xr + rr*8;
        float4 v = *(const float4*)(Xb + (size_t)(k0+r)*LLEN + n0 + xc);
        if (MODE==0){
          float dval = dpev[bz*TSZ + k0 + r];
          v.x += dval; v.y += dval; v.z += dval; v.w += dval;
        }
        if (MODE==2){ v.x *= IS6; v.y *= IS6; v.z *= IS6; v.w *= IS6; }
        *(float4*)&Xs[r][xc] = v;
      }
    }
    __syncthreads();
#pragma unroll
    for (int k=0;k<16;k++){
      float4 av = *(const float4*)&Ws[k][ty*4];
      float4 b0 = *(const float4*)&Xs[k][tx*8];
      float4 b1 = *(const float4*)&Xs[k][tx*8+4];
      float a[4]  = {av.x,av.y,av.z,av.w};
      float bv[8] = {b0.x,b0.y,b0.z,b0.w,b1.x,b1.y,b1.z,b1.w};
#pragma unroll
      for (int i=0;i<4;i++)
#pragma unroll
        for (int j=0;j<8;j++)
          acc[i][j] = fmaf(a[i], bv[j], acc[i][j]);
    }
    __syncthreads();
  }
#pragma unroll
  for (int i=0;i<4;i++){
    int m = m0 + ty*4 + i;
    float bvv = bias[m];
    int n = n0 + tx*8;
    float4 v0 = make_float4(acc[i][0]+bvv, acc[i][1]+bvv, acc[i][2]+bvv, acc[i][3]+bvv);
    float4 v1 = make_float4(acc[i][4]+bvv, acc[i][5]+bvv, acc[i][6]+bvv, acc[i][7]+bvv);
    if (MODE==0){
      float* yp = Y + ((size_t)bz*HSZ + m)*LLEN + n;
      *(float4*)yp = v0; *(float4*)(yp+4) = v1;
    } else if (MODE==2){
      v0.x=fmaxf(v0.x,0.f); v0.y=fmaxf(v0.y,0.f); v0.z=fmaxf(v0.z,0.f); v0.w=fmaxf(v0.w,0.f);
      v1.x=fmaxf(v1.x,0.f); v1.y=fmaxf(v1.y,0.f); v1.z=fmaxf(v1.z,0.f); v1.w=fmaxf(v1.w,0.f);
      float* yp = Y + ((size_t)bz*TSZ + m)*LLEN + n;
      *(float4*)yp = v0; *(float4*)(yp+4) = v1;
    } else {
      if (m < TSZ){
        float* hp = hbuf + ((size_t)bz*TSZ + m)*LLEN + n;
        float4 h0 = *(float4*)hp; float4 h1 = *(float4*)(hp+4);
        h0.x=(h0.x+v0.x)*RS2; h0.y=(h0.y+v0.y)*RS2; h0.z=(h0.z+v0.z)*RS2; h0.w=(h0.w+v0.w)*RS2;
        h1.x=(h1.x+v1.x)*RS2; h1.y=(h1.y+v1.y)*RS2; h1.z=(h1.z+v1.z)*RS2; h1.w=(h1.w+v1.w)*RS2;
        *(float4*)hp = h0; *(float4*)(hp+4) = h1;
      } else {
        float* sp = skipb + ((size_t)bz*TSZ + (m-TSZ))*LLEN + n;
        if (first){
          *(float4*)sp = v0; *(float4*)(sp+4) = v1;
        } else {
          float4 s0 = *(float4*)sp; float4 s1 = *(float4*)(sp+4);
          s0.x+=v0.x; s0.y+=v0.y; s0.z+=v0.z; s0.w+=v0.w;
          s1.x+=v1.x; s1.y+=v1.y; s1.z+=v1.z; s1.w+=v1.w;
          *(float4*)sp = s0; *(float4*)(sp+4) = s1;
        }
      }
    }
  }
}

// ---------------- fused S4D (DF2 form), wave-local, no __syncthreads ----------------
// block: 256 threads = 4 waves; wave w owns rows 4w..4w+3 (16 chunks x 64 per row).
// LDS: swizzled u/y, chunk stride 65, row stride 1040 (66.56 KB). in-place safe.
__global__ __launch_bounds__(256,2) void s4_fused(const float2* __restrict__ cA,
                                                  const float2* __restrict__ cB,
                                                  const float4* __restrict__ cM,
                                                  const float* __restrict__ Dq,
                                                  const float* u, float* y){
  __shared__ float uly[16*RSTR];
  int tid  = threadIdx.x;
  int wave = tid >> 6;
  int lane = tid & 63;
  int b = blockIdx.x >> 5;
  int hbase = (blockIdx.x & 31) * 16;
  int rowBase = b*HSZ + hbase;

  // ---- wave-local staging: wave w loads rows 4w..4w+3 (coalesced float4)
#pragma unroll
  for (int i=0;i<16;i++){
    int fidx = i*64 + lane;          // 0..1023 within wave's 4 rows
    int rl = fidx >> 8;              // 0..3
    int row = wave*4 + rl;
    int l   = (fidx & 255) * 4;
    float4 v = *(const float4*)(u + (size_t)(rowBase + row)*LLEN + l);
    int a = row*RSTR + (l>>6)*CSTR + (l & 63);
    uly[a+0]=v.x; uly[a+1]=v.y; uly[a+2]=v.z; uly[a+3]=v.w;
  }
  __builtin_amdgcn_wave_barrier();
  __builtin_amdgcn_s_waitcnt(0);
  __builtin_amdgcn_wave_barrier();

  int c    = tid & 15;               // chunk index within row
  int hrow = tid >> 4;               // 0..15 (== wave*4 + lane>>4)
  int h    = hbase + hrow;
  int ubase = hrow*RSTR + c*CSTR;

  // ---- DF2 section coefficients (a1,a2) and states
  float a1[NST], a2[NST], w1[NST], w2[NST];
  const float2* ap = cA + h*NST;
#pragma unroll
  for (int n=0;n<NST;n++){ float2 t=ap[n]; a1[n]=t.x; a2[n]=t.y; w1[n]=0.f; w2[n]=0.f; }

  // ---- phase 1: local scan (zero init), states only
#pragma unroll 2
  for (int j=0;j<LCHUNK;j++){
    float uu = uly[ubase + j];
#pragma unroll
    for (int n=0;n<NST;n++){
      float wn = fmaf(a1[n], w1[n], fmaf(a2[n], w2[n], uu));
      w2[n]=w1[n]; w1[n]=wn;
    }
  }

  // ---- combine: affine prefix over 16 chunks, 2x2 matrix form, via shuffles
  const float4* mp = cM + h*NST;
#pragma unroll 4
  for (int n=0;n<NST;n++){
    float4 M = mp[n];                 // M^64
    float p=M.x, q=M.y, r=M.z, s=M.w;
    float Vr = w1[n], Vs = w2[n];
#pragma unroll
    for (int d=1; d<16; d<<=1){
      float tr = __shfl_up(Vr, (unsigned)d, 16);
      float ts = __shfl_up(Vs, (unsigned)d, 16);
      float nr = fmaf(p, tr, fmaf(q, ts, Vr));
      float ns = fmaf(r, tr, fmaf(s, ts, Vs));
      bool ok = (c >= d);
      Vr = ok ? nr : Vr;  Vs = ok ? ns : Vs;
      if (d < 8){
        float np_ = fmaf(p,p, q*r);
        float nq  = q*(p+s);
        float nr2 = r*(p+s);
        float ns2 = fmaf(s,s, q*r);
        p=np_; q=nq; r=nr2; s=ns2;
      }
    }
    // exclusive carry: inclusive of lane c-1; chunk 0 starts from zero state
    float er = __shfl_up(Vr, 1u, 16);
    float es = __shfl_up(Vs, 1u, 16);
    w1[n] = (c==0) ? 0.f : er;
    w2[n] = (c==0) ? 0.f : es;
  }

  // ---- phase 2: rescan from carry-in, project output, write back to LDS
  float b0a[NST], b1a[NST];
  const float2* bp = cB + h*NST;
#pragma unroll
  for (int n=0;n<NST;n++){ float2 t=bp[n]; b0a[n]=t.x; b1a[n]=t.y; }
  float dv = Dq[h];
#pragma unroll 2
  for (int j=0;j<LCHUNK;j++){
    float uu = uly[ubase + j];
    float acc = dv*uu;
#pragma unroll
    for (int n=0;n<NST;n++){
      float wn = fmaf(a1[n], w1[n], fmaf(a2[n], w2[n], uu));
      acc = fmaf(b0a[n], wn, fmaf(b1a[n], w1[n], acc));
      w2[n]=w1[n]; w1[n]=wn;
    }
    uly[ubase + j] = acc;
  }
  __builtin_amdgcn_wave_barrier();
  __builtin_amdgcn_s_waitcnt(0);
  __builtin_amdgcn_wave_barrier();

  // ---- wave-local writeback (coalesced float4)
#pragma unroll
  for (int i=0;i<16;i++){
    int fidx = i*64 + lane;
    int rl = fidx >> 8;
    int row = wave*4 + rl;
    int l   = (fidx & 255) * 4;
    int a = row*RSTR + (l>>6)*CSTR + (l & 63);
    float4 v = make_float4(uly[a], uly[a+1], uly[a+2], uly[a+3]);
    *(float4*)(y + (size_t)(rowBase + row)*LLEN + l) = v;
  }
}

// ---------------- channel LayerNorm over 512 channels; GATED fuses gate ----------------
template<int GATED>
__global__ __launch_bounds__(256) void ln_kernel(const float* in, float* out,
                                                 const float* __restrict__ g, const float* __restrict__ bt){
  __shared__ float rs[4][64];
  __shared__ float rq[4][64];
  __shared__ float mbuf[64], rbuf[64];
  int tid = threadIdx.x;
  int hg = tid >> 6;
  int lo = tid & 63;
  int b = blockIdx.x >> 4;
  int l = ((blockIdx.x & 15) << 6) + lo;
  size_t base = (size_t)(b*HSZ)*LLEN + l;
  float s=0.f, ss=0.f;
  for (int hh=0; hh<128; hh++){
    float v = in[base + (size_t)(hg*128+hh)*LLEN];
    s += v; ss = fmaf(v,v,ss);
  }
  rs[hg][lo]=s; rq[hg][lo]=ss;
  __syncthreads();
  if (tid < 64){
    float S = rs[0][tid]+rs[1][tid]+rs[2][tid]+rs[3][tid];
    float Q = rq[0][tid]+rq[1][tid]+rq[2][tid]+rq[3][tid];
    float mean = S * (1.f/HSZ);
    float var  = Q * (1.f/HSZ) - mean*mean;
    mbuf[tid]=mean;
    rbuf[tid]=rsqrtf(var + 1e-5f);
  }
  __syncthreads();
  float mean = mbuf[lo], rstd = rbuf[lo];
  if (!GATED){
    for (int hh=0; hh<128; hh++){
      int h = hg*128+hh;
      float v = in[base + (size_t)h*LLEN];
      out[base + (size_t)h*LLEN] = (v-mean)*rstd*g[h] + bt[h];
    }
  } else {
    size_t gbase = (size_t)(b*TSZ)*LLEN + l;
    for (int tt=0; tt<64; tt++){
      int t = hg*64 + tt;
      float a = (in[base + (size_t)t*LLEN]       - mean)*rstd*g[t]     + bt[t];
      float f = (in[base + (size_t)(t+256)*LLEN] - mean)*rstd*g[t+256] + bt[t+256];
      float sg = 1.f/(1.f+__expf(-a));
      float th = 1.f - 2.f/(__expf(2.f*f)+1.f);
      out[gbase + (size_t)t*LLEN] = sg*th;
    }
  }
}

// ---------------- out2 projection + 1/sqrt(beta) + transpose to [B,L,14] --------
__global__ __launch_bounds__(256) void out2_kernel(const float* __restrict__ w2, const float* __restrict__ b2,
                                                   const float* __restrict__ t, const float* __restrict__ z,
                                                   float* __restrict__ outp){
  __shared__ float ws[14*256];
  __shared__ float bs[14];
  int tid = threadIdx.x;
#pragma unroll
  for (int c=0;c<14;c++) ws[c*256+tid] = w2[c*256+tid];
  if (tid < 14) bs[tid] = b2[tid];
  __syncthreads();
  int b = blockIdx.x >> 2;
  int l = ((blockIdx.x & 3) << 8) + tid;
  float tb = t[b];
  float scale = rsqrtf(1e-4f + tb*(2e-2f - 1e-4f));
  float acc[14];
#pragma unroll
  for (int c=0;c<14;c++) acc[c]=0.f;
  const float* zp = z + (size_t)b*TSZ*LLEN + l;
  for (int tt2=0; tt2<256; tt2++){
    float xv = zp[(size_t)tt2*LLEN];
#pragma unroll
    for (int c=0;c<14;c++) acc[c] = fmaf(ws[c*256+tt2], xv, acc[c]);
  }
  float* op = outp + (size_t)(b*LLEN + l)*CINN;
#pragma unroll
  for (int c=0;c<14;c++) op[c] = (acc[c]+bs[c])*scale;
}

// ---------------- host launcher ----------------
extern "C" void kernel_launch(void* const* d_in, const int* in_sizes, int n_in,
                              void* d_out, int out_size, void* d_ws, size_t ws_size,
                              hipStream_t stream) {
  (void)in_sizes; (void)n_in; (void)out_size;
  if (ws_size < (size_t)WS_FLOATS * 4) return;

  const float* x      = (const float*)d_in[0];
  const float* t      = (const float*)d_in[1];
  const float* gfpW   = (const float*)d_in[2];
  const float* ew1    = (const float*)d_in[3];
  const float* eb1    = (const float*)d_in[4];
  const float* ew2    = (const float*)d_in[5];
  const float* eb2    = (const float*)d_in[6];
  const float* in_w   = (const float*)d_in[7];
  const float* in_b   = (const float*)d_in[8];
  const float* out1_w = (const float*)d_in[9];
  const float* out1_b = (const float*)d_in[10];
  const float* out2_w = (const float*)d_in[11];
  const float* out2_b = (const float*)d_in[12];
  const float* dp_w   = (const float*)d_in[13];
  const float* dp_b   = (const float*)d_in[14];
  const float* ip_w   = (const float*)d_in[15];
  const float* ip_b   = (const float*)d_in[16];
  const float* op_w   = (const float*)d_in[17];
  const float* op_b   = (const float*)d_in[18];
  const float* log_dt = (const float*)d_in[19];
  const float* logA   = (const float*)d_in[20];
  const float* Aim    = (const float*)d_in[21];
  const float* Cre    = (const float*)d_in[22];
  const float* Cim    = (const float*)d_in[23];
  const float* s4D    = (const float*)d_in[24];
  const float* ln_g   = (const float*)d_in[25];
  const float* ln_b   = (const float*)d_in[26];
  float* out = (float*)d_out;
  float* ws = (float*)d_ws;

  float2* cA   = (float2*)(ws + OFF_A);
  float2* cB   = (float2*)(ws + OFF_B);
  float4* cM   = (float4*)(ws + OFF_M);
  float* embb  = ws + OFF_EMB;
  float* dpeb  = ws + OFF_DPE;
  float* hbuf  = ws + OFF_H;
  float* skipb = ws + OFF_SKIP;
  float* y1    = ws + OFF_Y1;
  float* y2    = ws + OFF_Y2;

  consts_kernel<<<768,256,0,stream>>>(log_dt, logA, Aim, Cre, Cim, cA, cB, cM);
  emb_kernel<<<BB,128,0,stream>>>(t, gfpW, ew1, eb1, ew2, eb2, embb);
  dpe_kernel<<<NDEPTH*BB,256,0,stream>>>(embb, dp_w, dp_b, dpeb);
  inproj_kernel<<<64,256,0,stream>>>(x, in_w, in_b, hbuf);

  for (int d=0; d<NDEPTH; d++){
    int q0 = d*2, q1 = d*2+1;
    gemm_k<0><<<dim3(8,8,16),256,0,stream>>>(ip_w + (size_t)d*HSZ*TSZ, ip_b + d*HSZ,
                                             hbuf, y1, dpeb + (size_t)d*BB*TSZ,
                                             nullptr, nullptr, 0);
    s4_fused<<<512,256,0,stream>>>(cA + (size_t)q0*QHN, cB + (size_t)q0*QHN,
                                   cM + (size_t)q0*QHN, s4D + q0*HSZ, y1, y1);
    ln_kernel<0><<<256,256,0,stream>>>(y1, y1, ln_g + q0*HSZ, ln_b + q0*HSZ);
    s4_fused<<<512,256,0,stream>>>(cA + (size_t)q1*QHN, cB + (size_t)q1*QHN,
                                   cM + (size_t)q1*QHN, s4D + q1*HSZ, y1, y1);
    ln_kernel<1><<<256,256,0,stream>>>(y1, y2, ln_g + q1*HSZ, ln_b + q1*HSZ);
    gemm_k<1><<<dim3(8,8,16),256,0,stream>>>(op_w + (size_t)d*HSZ*TSZ, op_b + d*HSZ,
                                             y2, y1, nullptr, hbuf, skipb, (d==0)?1:0);
  }
  gemm_k<2><<<dim3(8,4,16),256,0,stream>>>(out1_w, out1_b, skipb, y1,
                                           nullptr, nullptr, nullptr, 0);
  out2_kernel<<<64,256,0,stream>>>(out2_w, out2_b, t, y1, out);
}

// Round 5
// 1366.970 us; speedup vs baseline: 1.8809x; 1.4749x over previous
//
#include <hip/hip_runtime.h>

// ---------------- problem constants ----------------
#define BB     16
#define LLEN   1024
#define CINN   14
#define TSZ    256
#define HSZ    512
#define NST    32
#define ESZ    128
#define NDEPTH 6
#define NCHUNK 16
#define LCHUNK 64
#define QHN    (HSZ*NST)

#define RS2 0.70710678118654752f   // 1/sqrt(2)
#define IS6 0.40824829046386302f   // 1/sqrt(6)

// s4 LDS swizzle
#define CSTR 65
#define RSTR 1040

typedef unsigned short u16;
typedef unsigned int   u32;
typedef _Float16 f16;
typedef __attribute__((ext_vector_type(8)))  _Float16 f16x8;
typedef __attribute__((ext_vector_type(16))) float    f32x16;

// workspace layout (float offsets)
#define OFF_A    0u          // float2 (a1,a2) x 12*16384
#define OFF_B    393216u     // float2 (b0,b1) x 12*16384
#define OFF_M    786432u     // float4 M^64    x 12*16384
#define OFF_EMB  1572864u
#define OFF_DPE16 1574912u   // f16 [6][16][256] = 24576 f16 = 12288 floats
#define OFF_H    1587200u    // fp32 [16][256][1024]
#define OFF_SKIP 5781504u    // fp32 [16][256][1024]
#define OFF_Y1   9975808u    // fp32 [16][512][1024]
#define OFF_HT   18364416u   // f16 [16][1024][256] = 2097152 floats
#define OFF_GT   20461568u   // f16 [16][1024][256]
#define OFF_ST   22558720u   // f16 [16][1024][256]
#define WS_FLOATS 24655872u

// ---------------- S4D constants -> DF2 sections + chunk transition matrix ----------------
__global__ void consts_kernel(const float* __restrict__ log_dt, const float* __restrict__ logA,
                              const float* __restrict__ Aim,   const float* __restrict__ Cre,
                              const float* __restrict__ Cim,
                              float2* __restrict__ cA, float2* __restrict__ cB,
                              float4* __restrict__ cM){
  int gid = blockIdx.x*256 + threadIdx.x;            // q*16384 + h*32 + n
  int n = gid & 31;
  int h = (gid>>5) & 511;
  int q = gid >> 14;
  float dt  = expf(log_dt[q*HSZ + h]);
  float are = -expf(logA[gid]);
  float aim = Aim[gid];
  float dre = are*dt, dim = aim*dt;
  float e   = expf(dre);
  float lre = e*cosf(dim), lim = e*sinf(dim);
  float nre = lre - 1.f, nim = lim;
  float invden = 1.f/(are*are + aim*aim);
  float tre = (nre*are + nim*aim)*invden;
  float tim = (nim*are - nre*aim)*invden;
  float cr = Cre[gid], ci = Cim[gid];
  float Cr = 2.f*(cr*tre - ci*tim);
  float Ci = 2.f*(cr*tim + ci*tre);
  float a1, a2, b0, b1;
  if (n == 0){
    a1 = lre; a2 = 0.f; b0 = Cr; b1 = 0.f;
  } else {
    a1 = 2.f*lre;
    a2 = -(lre*lre + lim*lim);
    b0 = Cr;
    b1 = -(Cr*lre + Ci*lim);
  }
  cA[gid] = make_float2(a1, a2);
  cB[gid] = make_float2(b0, b1);
  float p = a1, qq = a2, r = 1.f, s = 0.f;
#pragma unroll
  for (int k=0;k<6;k++){
    float np_ = fmaf(p,p, qq*r);
    float nq  = qq*(p+s);
    float nr  = r*(p+s);
    float ns  = fmaf(s,s, qq*r);
    p=np_; qq=nq; r=nr; s=ns;
  }
  cM[gid] = make_float4(p, qq, r, s);
}

// ---------------- diffusion embedding MLP ----------------
__global__ void emb_kernel(const float* __restrict__ t, const float* __restrict__ gw,
                           const float* __restrict__ w1, const float* __restrict__ b1,
                           const float* __restrict__ w2, const float* __restrict__ b2,
                           float* __restrict__ emb){
  __shared__ float e0[128], e1[128];
  int b = blockIdx.x, tid = threadIdx.x;
  float tb = t[b];
  if (tid < 64){
    float xp = tb * gw[tid] * 6.283185307179586f;
    e0[tid]    = sinf(xp);
    e0[tid+64] = cosf(xp);
  }
  __syncthreads();
  float a = b1[tid];
  for (int i=0;i<128;i++) a = fmaf(e0[i], w1[tid*128+i], a);
  a = a / (1.f + __expf(-a));
  e1[tid] = a;
  __syncthreads();
  float a2 = b2[tid];
  for (int i=0;i<128;i++) a2 = fmaf(e1[i], w2[tid*128+i], a2);
  a2 = a2 / (1.f + __expf(-a2));
  emb[b*ESZ + tid] = a2;
}

// ---------------- per-depth diffusion projection -> f16 ----------------
__global__ void dpe_kernel(const float* __restrict__ emb, const float* __restrict__ dw,
                           const float* __restrict__ db, f16* __restrict__ dpe16){
  int blk = blockIdx.x; int d = blk >> 4; int b = blk & 15; int o = threadIdx.x;
  const float* wp = dw + (size_t)(d*TSZ + o)*ESZ;
  const float* ep = emb + b*ESZ;
  float a = db[d*TSZ + o];
  for (int e=0;e<128;e++) a = fmaf(ep[e], wp[e], a);
  dpe16[(size_t)(d*BB + b)*TSZ + o] = (f16)a;
}

// ---------------- input projection [B,L,14] -> h [B,256,L] fp32 ----------------
__global__ __launch_bounds__(256) void inproj_kernel(const float* __restrict__ x, const float* __restrict__ w,
                                                     const float* __restrict__ bias, float* __restrict__ hb){
  __shared__ float ws[256*14];
  __shared__ float bs[256];
  int tid = threadIdx.x;
#pragma unroll
  for (int c=0;c<14;c++) ws[tid*14+c] = w[tid*14+c];
  bs[tid] = bias[tid];
  __syncthreads();
  int b = blockIdx.x >> 2;
  int l = ((blockIdx.x & 3) << 8) + tid;
  float xv[14];
  const float* xp = x + (size_t)(b*LLEN + l)*CINN;
#pragma unroll
  for (int c=0;c<14;c++) xv[c] = xp[c];
  for (int o=0;o<256;o++){
    float a = bs[o];
#pragma unroll
    for (int c=0;c<14;c++) a = fmaf(ws[o*14+c], xv[c], a);
    hb[(size_t)(b*TSZ + o)*LLEN + l] = a;
  }
}

// ---------------- transpose fp32 [b][256][1024] -> f16 [b][1024][256] ----------------
__global__ __launch_bounds__(256) void h2t_kernel(const float* __restrict__ src, f16* __restrict__ dst){
  __shared__ f16 TT[64*72];
  int tid = threadIdx.x;
  int b = blockIdx.z;
  int l0 = blockIdx.x * 64;
  int t0 = blockIdx.y * 64;
#pragma unroll
  for (int i=0;i<4;i++){
    int job = i*256 + tid;            // 64 t x 16 l4
    int tt = job >> 4, l4 = (job & 15)*4;
    float4 v = *(const float4*)(src + ((size_t)b*TSZ + t0+tt)*LLEN + l0 + l4);
    TT[(l4+0)*72 + tt] = (f16)v.x;
    TT[(l4+1)*72 + tt] = (f16)v.y;
    TT[(l4+2)*72 + tt] = (f16)v.z;
    TT[(l4+3)*72 + tt] = (f16)v.w;
  }
  __syncthreads();
#pragma unroll
  for (int i=0;i<2;i++){
    int job = i*256 + tid;            // 64 l x 8 granules
    int l = job >> 3, g = job & 7;
    f16x8 hv = *(const f16x8*)(TT + l*72 + g*8);
    *(f16x8*)(dst + ((size_t)b*LLEN + l0 + l)*TSZ + t0 + g*8) = hv;
  }
}

// ---------------- MFMA GEMM: Y[b] = W[M,256] @ X[b][256,1024], X given transposed f16 ----
// MODE 0: ip  (B = hT16 + dpe16, Y fp32 [512][1024])
// MODE 1: op  (B = gT16; y<2: res->hbuf RMW + hT16; y>=2: skip->skipb RMW)
// MODE 2: out1 (B = skipT16 * IS6, relu, Y fp32 [256][1024])
template<int MODE>
__global__ __launch_bounds__(256) void gemm_k(const float* __restrict__ W, const float* __restrict__ bias,
                                              const f16* __restrict__ XT, const f16* __restrict__ dpeD,
                                              float* __restrict__ Y, float* __restrict__ hbuf,
                                              f16* __restrict__ hT16, float* __restrict__ skipb, int first){
  __shared__ f16 sm[17408];          // As[0..8191], Bs[8192..16383]; TR reuses all
  f16* As = sm;
  f16* Bs = sm + 8192;
  int tid = threadIdx.x;
  int lane = tid & 63;
  int wv = tid >> 6;
  int n_blk = blockIdx.x * 128;
  int m_blk = blockIdx.y * 128;
  int bz = blockIdx.z;
  const f16* Xb = XT + (size_t)bz * (LLEN*TSZ);
  int wm = (wv & 1) * 64;
  int wn = (wv >> 1) * 64;

  f32x16 acc[2][2];
#pragma unroll
  for (int mi=0;mi<2;mi++)
#pragma unroll
    for (int ni=0;ni<2;ni++)
#pragma unroll
      for (int r=0;r<16;r++) acc[mi][ni][r] = 0.f;

  for (int kt=0; kt<4; kt++){
    int k0 = kt*64;
    // stage A (fp32 W -> f16 frag-granules, XOR swizzle)
#pragma unroll
    for (int i=0;i<4;i++){
      int job = i*256 + tid;
      int m = job >> 3, gk = job & 7;
      const float* wp = W + (size_t)(m_blk + m)*TSZ + k0 + gk*8;
      float4 u0 = *(const float4*)wp;
      float4 u1 = *(const float4*)(wp+4);
      f16x8 hv;
      hv[0]=(f16)u0.x; hv[1]=(f16)u0.y; hv[2]=(f16)u0.z; hv[3]=(f16)u0.w;
      hv[4]=(f16)u1.x; hv[5]=(f16)u1.y; hv[6]=(f16)u1.z; hv[7]=(f16)u1.w;
      int P = m*8 + (gk ^ (m & 7));
      *(f16x8*)(As + P*8) = hv;
    }
    // stage B (f16 XT granules, XOR swizzle)
#pragma unroll
    for (int i=0;i<4;i++){
      int job = i*256 + tid;
      int n = job >> 3, gk = job & 7;
      f16x8 hv = *(const f16x8*)(Xb + (size_t)(n_blk + n)*TSZ + k0 + gk*8);
      if (MODE==0){
        f16x8 dv = *(const f16x8*)(dpeD + bz*TSZ + k0 + gk*8);
#pragma unroll
        for (int e=0;e<8;e++) hv[e] = hv[e] + dv[e];
      }
      if (MODE==2){
#pragma unroll
        for (int e=0;e<8;e++) hv[e] = hv[e] * (f16)IS6;
      }
      int P = n*8 + (gk ^ (n & 7));
      *(f16x8*)(Bs + P*8) = hv;
    }
    __syncthreads();
#pragma unroll
    for (int ks=0; ks<4; ks++){
      int q = lane >> 5;
      int gk = ks*2 + q;
      f16x8 af[2], bf[2];
#pragma unroll
      for (int mi=0; mi<2; mi++){
        int m = wm + mi*32 + (lane & 31);
        af[mi] = *(const f16x8*)(As + (m*8 + (gk ^ (m&7)))*8);
      }
#pragma unroll
      for (int ni=0; ni<2; ni++){
        int n = wn + ni*32 + (lane & 31);
        bf[ni] = *(const f16x8*)(Bs + (n*8 + (gk ^ (n&7)))*8);
      }
#pragma unroll
      for (int mi=0; mi<2; mi++)
#pragma unroll
        for (int ni=0; ni<2; ni++)
          acc[mi][ni] = __builtin_amdgcn_mfma_f32_32x32x16_f16(af[mi], bf[ni], acc[mi][ni], 0, 0, 0);
    }
    __syncthreads();
  }

  // ---- epilogue ----
  int q = lane >> 5;
  if (MODE == 0 || MODE == 2){
    const int MD = (MODE==0) ? HSZ : TSZ;
#pragma unroll
    for (int mi=0;mi<2;mi++)
#pragma unroll
      for (int ni=0;ni<2;ni++){
        int col = n_blk + wn + ni*32 + (lane & 31);
#pragma unroll
        for (int r=0;r<16;r++){
          int row = m_blk + wm + mi*32 + (r&3) + 8*(r>>2) + 4*q;
          float v = acc[mi][ni][r] + bias[row];
          if (MODE==2) v = fmaxf(v, 0.f);
          Y[((size_t)bz*MD + row)*LLEN + col] = v;
        }
      }
  } else {
    if (blockIdx.y < 2){
      // residual: hbuf RMW + f16 transpose into hT16
#pragma unroll
      for (int mi=0;mi<2;mi++)
#pragma unroll
        for (int ni=0;ni<2;ni++){
          int col_l = wn + ni*32 + (lane & 31);
#pragma unroll
          for (int r=0;r<16;r++){
            int row_l = wm + mi*32 + (r&3) + 8*(r>>2) + 4*q;
            int row = m_blk + row_l;
            float v = acc[mi][ni][r] + bias[row];
            float* hp = hbuf + ((size_t)bz*TSZ + row)*LLEN + n_blk + col_l;
            float hn = (*hp + v)*RS2;
            *hp = hn;
            sm[col_l*136 + row_l] = (f16)hn;
          }
        }
      __syncthreads();
#pragma unroll
      for (int i=0;i<8;i++){
        int job = i*256 + tid;         // 128 n x 16 m-granules
        int n = job >> 4, m8 = job & 15;
        f16x8 hv = *(const f16x8*)(sm + n*136 + m8*8);
        *(f16x8*)(hT16 + ((size_t)bz*LLEN + n_blk + n)*TSZ + m_blk + m8*8) = hv;
      }
    } else {
      // skip accumulate
#pragma unroll
      for (int mi=0;mi<2;mi++)
#pragma unroll
        for (int ni=0;ni<2;ni++){
          int col = n_blk + wn + ni*32 + (lane & 31);
#pragma unroll
          for (int r=0;r<16;r++){
            int row = m_blk + wm + mi*32 + (r&3) + 8*(r>>2) + 4*q;
            float v = acc[mi][ni][r] + bias[row];
            float* sp = skipb + ((size_t)bz*TSZ + (row - TSZ))*LLEN + col;
            if (first) *sp = v; else *sp = *sp + v;
          }
        }
    }
  }
}

// ---------------- fused S4D (DF2), wave-local ----------------
__global__ __launch_bounds__(256,2) void s4_fused(const float2* __restrict__ cA,
                                                  const float2* __restrict__ cB,
                                                  const float4* __restrict__ cM,
                                                  const float* __restrict__ Dq,
                                                  const float* u, float* y){
  __shared__ float uly[16*RSTR];
  int tid  = threadIdx.x;
  int wave = tid >> 6;
  int lane = tid & 63;
  int b = blockIdx.x >> 5;
  int hbase = (blockIdx.x & 31) * 16;
  int rowBase = b*HSZ + hbase;

#pragma unroll
  for (int i=0;i<16;i++){
    int fidx = i*64 + lane;
    int rl = fidx >> 8;
    int row = wave*4 + rl;
    int l   = (fidx & 255) * 4;
    float4 v = *(const float4*)(u + (size_t)(rowBase + row)*LLEN + l);
    int a = row*RSTR + (l>>6)*CSTR + (l & 63);
    uly[a+0]=v.x; uly[a+1]=v.y; uly[a+2]=v.z; uly[a+3]=v.w;
  }
  __builtin_amdgcn_wave_barrier();
  __builtin_amdgcn_s_waitcnt(0);
  __builtin_amdgcn_wave_barrier();

  int c    = tid & 15;
  int hrow = tid >> 4;
  int h    = hbase + hrow;
  int ubase = hrow*RSTR + c*CSTR;

  float a1[NST], a2[NST], w1[NST], w2[NST];
  const float2* ap = cA + h*NST;
#pragma unroll
  for (int n=0;n<NST;n++){ float2 t=ap[n]; a1[n]=t.x; a2[n]=t.y; w1[n]=0.f; w2[n]=0.f; }

#pragma unroll 2
  for (int j=0;j<LCHUNK;j++){
    float uu = uly[ubase + j];
#pragma unroll
    for (int n=0;n<NST;n++){
      float wn = fmaf(a1[n], w1[n], fmaf(a2[n], w2[n], uu));
      w2[n]=w1[n]; w1[n]=wn;
    }
  }

  const float4* mp = cM + h*NST;
#pragma unroll 4
  for (int n=0;n<NST;n++){
    float4 M = mp[n];
    float p=M.x, q=M.y, r=M.z, s=M.w;
    float Vr = w1[n], Vs = w2[n];
#pragma unroll
    for (int d=1; d<16; d<<=1){
      float tr = __shfl_up(Vr, (unsigned)d, 16);
      float ts = __shfl_up(Vs, (unsigned)d, 16);
      float nr = fmaf(p, tr, fmaf(q, ts, Vr));
      float ns = fmaf(r, tr, fmaf(s, ts, Vs));
      bool ok = (c >= d);
      Vr = ok ? nr : Vr;  Vs = ok ? ns : Vs;
      if (d < 8){
        float np_ = fmaf(p,p, q*r);
        float nq  = q*(p+s);
        float nr2 = r*(p+s);
        float ns2 = fmaf(s,s, q*r);
        p=np_; q=nq; r=nr2; s=ns2;
      }
    }
    float er = __shfl_up(Vr, 1u, 16);
    float es = __shfl_up(Vs, 1u, 16);
    w1[n] = (c==0) ? 0.f : er;
    w2[n] = (c==0) ? 0.f : es;
  }

  float b0a[NST], b1a[NST];
  const float2* bp = cB + h*NST;
#pragma unroll
  for (int n=0;n<NST;n++){ float2 t=bp[n]; b0a[n]=t.x; b1a[n]=t.y; }
  float dv = Dq[h];
#pragma unroll 2
  for (int j=0;j<LCHUNK;j++){
    float uu = uly[ubase + j];
    float acc = dv*uu;
#pragma unroll
    for (int n=0;n<NST;n++){
      float wn = fmaf(a1[n], w1[n], fmaf(a2[n], w2[n], uu));
      acc = fmaf(b0a[n], wn, fmaf(b1a[n], w1[n], acc));
      w2[n]=w1[n]; w1[n]=wn;
    }
    uly[ubase + j] = acc;
  }
  __builtin_amdgcn_wave_barrier();
  __builtin_amdgcn_s_waitcnt(0);
  __builtin_amdgcn_wave_barrier();

#pragma unroll
  for (int i=0;i<16;i++){
    int fidx = i*64 + lane;
    int rl = fidx >> 8;
    int row = wave*4 + rl;
    int l   = (fidx & 255) * 4;
    int a = row*RSTR + (l>>6)*CSTR + (l & 63);
    float4 v = make_float4(uly[a], uly[a+1], uly[a+2], uly[a+3]);
    *(float4*)(y + (size_t)(rowBase + row)*LLEN + l) = v;
  }
}

// ---------------- channel LayerNorm (plain, in-place capable) ----------------
__global__ __launch_bounds__(256) void ln_kernel(const float* in, float* out,
                                                 const float* __restrict__ g, const float* __restrict__ bt){
  __shared__ float rs[4][64];
  __shared__ float rq[4][64];
  __shared__ float mbuf[64], rbuf[64];
  int tid = threadIdx.x;
  int hg = tid >> 6;
  int lo = tid & 63;
  int b = blockIdx.x >> 4;
  int l = ((blockIdx.x & 15) << 6) + lo;
  size_t base = (size_t)(b*HSZ)*LLEN + l;
  float s=0.f, ss=0.f;
  for (int hh=0; hh<128; hh++){
    float v = in[base + (size_t)(hg*128+hh)*LLEN];
    s += v; ss = fmaf(v,v,ss);
  }
  rs[hg][lo]=s; rq[hg][lo]=ss;
  __syncthreads();
  if (tid < 64){
    float S = rs[0][tid]+rs[1][tid]+rs[2][tid]+rs[3][tid];
    float Q = rq[0][tid]+rq[1][tid]+rq[2][tid]+rq[3][tid];
    float mean = S * (1.f/HSZ);
    float var  = Q * (1.f/HSZ) - mean*mean;
    mbuf[tid]=mean;
    rbuf[tid]=rsqrtf(var + 1e-5f);
  }
  __syncthreads();
  float mean = mbuf[lo], rstd = rbuf[lo];
  for (int hh=0; hh<128; hh++){
    int h = hg*128+hh;
    float v = in[base + (size_t)h*LLEN];
    out[base + (size_t)h*LLEN] = (v-mean)*rstd*g[h] + bt[h];
  }
}

// ---------------- LN + gate fused, output transposed f16 [b][l][t] ----------------
__global__ __launch_bounds__(256) void ln_gate_kernel(const float* in, f16* __restrict__ gT,
                                                      const float* __restrict__ g, const float* __restrict__ bt){
  __shared__ float rs[4][64];
  __shared__ float rq[4][64];
  __shared__ float mbuf[64], rbuf[64];
  __shared__ f16 gbuf[64*272];
  int tid = threadIdx.x;
  int hg = tid >> 6;
  int lo = tid & 63;
  int b = blockIdx.x >> 4;
  int l0 = (blockIdx.x & 15) << 6;
  int l = l0 + lo;
  size_t base = (size_t)(b*HSZ)*LLEN + l;
  float s=0.f, ss=0.f;
  for (int hh=0; hh<128; hh++){
    float v = in[base + (size_t)(hg*128+hh)*LLEN];
    s += v; ss = fmaf(v,v,ss);
  }
  rs[hg][lo]=s; rq[hg][lo]=ss;
  __syncthreads();
  if (tid < 64){
    float S = rs[0][tid]+rs[1][tid]+rs[2][tid]+rs[3][tid];
    float Q = rq[0][tid]+rq[1][tid]+rq[2][tid]+rq[3][tid];
    float mean = S * (1.f/HSZ);
    float var  = Q * (1.f/HSZ) - mean*mean;
    mbuf[tid]=mean;
    rbuf[tid]=rsqrtf(var + 1e-5f);
  }
  __syncthreads();
  float mean = mbuf[lo], rstd = rbuf[lo];
  for (int tt=0; tt<64; tt++){
    int t = hg*64 + tt;
    float a = (in[base + (size_t)t*LLEN]       - mean)*rstd*g[t]     + bt[t];
    float f = (in[base + (size_t)(t+256)*LLEN] - mean)*rstd*g[t+256] + bt[t+256];
    float sg = 1.f/(1.f+__expf(-a));
    float th = 1.f - 2.f/(__expf(2.f*f)+1.f);
    gbuf[lo*272 + t] = (f16)(sg*th);
  }
  __syncthreads();
#pragma unroll
  for (int i=0;i<8;i++){
    int job = i*256 + tid;            // 64 l x 32 granules
    int ll = job >> 5, g8 = (job & 31)*8;
    f16x8 hv = *(const f16x8*)(gbuf + ll*272 + g8);
    *(f16x8*)(gT + ((size_t)b*LLEN + l0 + ll)*TSZ + g8) = hv;
  }
}

// ---------------- out2 projection + 1/sqrt(beta) + transpose to [B,L,14] --------
__global__ __launch_bounds__(256) void out2_kernel(const float* __restrict__ w2, const float* __restrict__ b2,
                                                   const float* __restrict__ t, const float* __restrict__ z,
                                                   float* __restrict__ outp){
  __shared__ float ws[14*256];
  __shared__ float bs[14];
  int tid = threadIdx.x;
#pragma unroll
  for (int c=0;c<14;c++) ws[c*256+tid] = w2[c*256+tid];
  if (tid < 14) bs[tid] = b2[tid];
  __syncthreads();
  int b = blockIdx.x >> 2;
  int l = ((blockIdx.x & 3) << 8) + tid;
  float tb = t[b];
  float scale = rsqrtf(1e-4f + tb*(2e-2f - 1e-4f));
  float acc[14];
#pragma unroll
  for (int c=0;c<14;c++) acc[c]=0.f;
  const float* zp = z + (size_t)b*TSZ*LLEN + l;
  for (int tt2=0; tt2<256; tt2++){
    float xv = zp[(size_t)tt2*LLEN];
#pragma unroll
    for (int c=0;c<14;c++) acc[c] = fmaf(ws[c*256+tt2], xv, acc[c]);
  }
  float* op = outp + (size_t)(b*LLEN + l)*CINN;
#pragma unroll
  for (int c=0;c<14;c++) op[c] = (acc[c]+bs[c])*scale;
}

// ---------------- host launcher ----------------
extern "C" void kernel_launch(void* const* d_in, const int* in_sizes, int n_in,
                              void* d_out, int out_size, void* d_ws, size_t ws_size,
                              hipStream_t stream) {
  (void)in_sizes; (void)n_in; (void)out_size;
  if (ws_size < (size_t)WS_FLOATS * 4) return;

  const float* x      = (const float*)d_in[0];
  const float* t      = (const float*)d_in[1];
  const float* gfpW   = (const float*)d_in[2];
  const float* ew1    = (const float*)d_in[3];
  const float* eb1    = (const float*)d_in[4];
  const float* ew2    = (const float*)d_in[5];
  const float* eb2    = (const float*)d_in[6];
  const float* in_w   = (const float*)d_in[7];
  const float* in_b   = (const float*)d_in[8];
  const float* out1_w = (const float*)d_in[9];
  const float* out1_b = (const float*)d_in[10];
  const float* out2_w = (const float*)d_in[11];
  const float* out2_b = (const float*)d_in[12];
  const float* dp_w   = (const float*)d_in[13];
  const float* dp_b   = (const float*)d_in[14];
  const float* ip_w   = (const float*)d_in[15];
  const float* ip_b   = (const float*)d_in[16];
  const float* op_w   = (const float*)d_in[17];
  const float* op_b   = (const float*)d_in[18];
  const float* log_dt = (const float*)d_in[19];
  const float* logA   = (const float*)d_in[20];
  const float* Aim    = (const float*)d_in[21];
  const float* Cre    = (const float*)d_in[22];
  const float* Cim    = (const float*)d_in[23];
  const float* s4D    = (const float*)d_in[24];
  const float* ln_g   = (const float*)d_in[25];
  const float* ln_b   = (const float*)d_in[26];
  float* out = (float*)d_out;
  float* ws = (float*)d_ws;

  float2* cA   = (float2*)(ws + OFF_A);
  float2* cB   = (float2*)(ws + OFF_B);
  float4* cM   = (float4*)(ws + OFF_M);
  float* embb  = ws + OFF_EMB;
  f16*   dpe16 = (f16*)(ws + OFF_DPE16);
  float* hbuf  = ws + OFF_H;
  float* skipb = ws + OFF_SKIP;
  float* y1    = ws + OFF_Y1;
  f16*   hT16  = (f16*)(ws + OFF_HT);
  f16*   gT16  = (f16*)(ws + OFF_GT);
  f16*   sT16  = (f16*)(ws + OFF_ST);

  consts_kernel<<<768,256,0,stream>>>(log_dt, logA, Aim, Cre, Cim, cA, cB, cM);
  emb_kernel<<<BB,128,0,stream>>>(t, gfpW, ew1, eb1, ew2, eb2, embb);
  dpe_kernel<<<NDEPTH*BB,256,0,stream>>>(embb, dp_w, dp_b, dpe16);
  inproj_kernel<<<64,256,0,stream>>>(x, in_w, in_b, hbuf);
  h2t_kernel<<<dim3(16,4,16),256,0,stream>>>(hbuf, hT16);

  for (int d=0; d<NDEPTH; d++){
    int q0 = d*2, q1 = d*2+1;
    // ip: hT16 (+dpe) -> y1 fp32
    gemm_k<0><<<dim3(8,4,16),256,0,stream>>>(ip_w + (size_t)d*HSZ*TSZ, ip_b + d*HSZ,
                                             hT16, dpe16 + (size_t)d*BB*TSZ,
                                             y1, nullptr, nullptr, nullptr, 0);
    s4_fused<<<512,256,0,stream>>>(cA + (size_t)q0*QHN, cB + (size_t)q0*QHN,
                                   cM + (size_t)q0*QHN, s4D + q0*HSZ, y1, y1);
    ln_kernel<<<256,256,0,stream>>>(y1, y1, ln_g + q0*HSZ, ln_b + q0*HSZ);
    s4_fused<<<512,256,0,stream>>>(cA + (size_t)q1*QHN, cB + (size_t)q1*QHN,
                                   cM + (size_t)q1*QHN, s4D + q1*HSZ, y1, y1);
    ln_gate_kernel<<<256,256,0,stream>>>(y1, gT16, ln_g + q1*HSZ, ln_b + q1*HSZ);
    // op: gT16 -> res(hbuf,hT16) / skip(skipb)
    gemm_k<1><<<dim3(8,4,16),256,0,stream>>>(op_w + (size_t)d*HSZ*TSZ, op_b + d*HSZ,
                                             gT16, nullptr, nullptr, hbuf, hT16, skipb, (d==0)?1:0);
  }
  h2t_kernel<<<dim3(16,4,16),256,0,stream>>>(skipb, sT16);
  gemm_k<2><<<dim3(8,2,16),256,0,stream>>>(out1_w, out1_b, sT16, nullptr,
                                           y1, nullptr, nullptr, nullptr, 0);
  out2_kernel<<<64,256,0,stream>>>(out2_w, out2_b, t, y1, out);
}

// Round 6
// 1366.395 us; speedup vs baseline: 1.8817x; 1.0004x over previous
//
#include <hip/hip_runtime.h>

// ---------------- problem constants ----------------
#define BB     16
#define LLEN   1024
#define CINN   14
#define TSZ    256
#define HSZ    512
#define NST    32
#define ESZ    128
#define NDEPTH 6
#define QHN    (HSZ*NST)

#define RS2 0.70710678118654752f   // 1/sqrt(2)
#define IS6 0.40824829046386302f   // 1/sqrt(6)

// s4 LDS swizzle: 32 chunks of 32, chunk stride 33, row stride 1056
#define CSTR2 33
#define RSTR2 1056

typedef unsigned short u16;
typedef unsigned int   u32;
typedef _Float16 f16;
typedef __attribute__((ext_vector_type(8)))  _Float16 f16x8;
typedef __attribute__((ext_vector_type(16))) float    f32x16;

// workspace layout (float offsets)
#define OFF_A    0u          // float2 (a1,a2) x 12*16384
#define OFF_B    393216u     // float2 (b0,b1) x 12*16384
#define OFF_M    786432u     // float4 M^32    x 12*16384
#define OFF_EMB  1572864u
#define OFF_DPE16 1574912u
#define OFF_H    1587200u    // fp32 [16][256][1024]
#define OFF_SKIP 5781504u    // fp32 [16][256][1024]
#define OFF_Y1   9975808u    // fp32 [16][512][1024]
#define OFF_HT   18364416u   // f16 [16][1024][256]
#define OFF_GT   20461568u
#define OFF_ST   22558720u
#define OFF_MEAN 24655872u   // [16][1024]
#define OFF_RSTD 24672256u   // [16][1024]
#define WS_FLOATS 24688640u

// ---------------- S4D constants -> DF2 sections + chunk transition matrix ----------------
__global__ void consts_kernel(const float* __restrict__ log_dt, const float* __restrict__ logA,
                              const float* __restrict__ Aim,   const float* __restrict__ Cre,
                              const float* __restrict__ Cim,
                              float2* __restrict__ cA, float2* __restrict__ cB,
                              float4* __restrict__ cM){
  int gid = blockIdx.x*256 + threadIdx.x;            // q*16384 + h*32 + n
  int n = gid & 31;
  int h = (gid>>5) & 511;
  int q = gid >> 14;
  float dt  = expf(log_dt[q*HSZ + h]);
  float are = -expf(logA[gid]);
  float aim = Aim[gid];
  float dre = are*dt, dim = aim*dt;
  float e   = expf(dre);
  float lre = e*cosf(dim), lim = e*sinf(dim);
  float nre = lre - 1.f, nim = lim;
  float invden = 1.f/(are*are + aim*aim);
  float tre = (nre*are + nim*aim)*invden;
  float tim = (nim*are - nre*aim)*invden;
  float cr = Cre[gid], ci = Cim[gid];
  float Cr = 2.f*(cr*tre - ci*tim);
  float Ci = 2.f*(cr*tim + ci*tre);
  float a1, a2, b0, b1;
  if (n == 0){
    a1 = lre; a2 = 0.f; b0 = Cr; b1 = 0.f;
  } else {
    a1 = 2.f*lre;
    a2 = -(lre*lre + lim*lim);
    b0 = Cr;
    b1 = -(Cr*lre + Ci*lim);
  }
  cA[gid] = make_float2(a1, a2);
  cB[gid] = make_float2(b0, b1);
  // M^32 via 5 squarings of companion matrix [[a1,a2],[1,0]] (chunk length 32)
  float p = a1, qq = a2, r = 1.f, s = 0.f;
#pragma unroll
  for (int k=0;k<5;k++){
    float np_ = fmaf(p,p, qq*r);
    float nq  = qq*(p+s);
    float nr  = r*(p+s);
    float ns  = fmaf(s,s, qq*r);
    p=np_; qq=nq; r=nr; s=ns;
  }
  cM[gid] = make_float4(p, qq, r, s);
}

// ---------------- diffusion embedding MLP ----------------
__global__ void emb_kernel(const float* __restrict__ t, const float* __restrict__ gw,
                           const float* __restrict__ w1, const float* __restrict__ b1,
                           const float* __restrict__ w2, const float* __restrict__ b2,
                           float* __restrict__ emb){
  __shared__ float e0[128], e1[128];
  int b = blockIdx.x, tid = threadIdx.x;
  float tb = t[b];
  if (tid < 64){
    float xp = tb * gw[tid] * 6.283185307179586f;
    e0[tid]    = sinf(xp);
    e0[tid+64] = cosf(xp);
  }
  __syncthreads();
  float a = b1[tid];
  for (int i=0;i<128;i++) a = fmaf(e0[i], w1[tid*128+i], a);
  a = a / (1.f + __expf(-a));
  e1[tid] = a;
  __syncthreads();
  float a2 = b2[tid];
  for (int i=0;i<128;i++) a2 = fmaf(e1[i], w2[tid*128+i], a2);
  a2 = a2 / (1.f + __expf(-a2));
  emb[b*ESZ + tid] = a2;
}

// ---------------- per-depth diffusion projection -> f16 ----------------
__global__ void dpe_kernel(const float* __restrict__ emb, const float* __restrict__ dw,
                           const float* __restrict__ db, f16* __restrict__ dpe16){
  int blk = blockIdx.x; int d = blk >> 4; int b = blk & 15; int o = threadIdx.x;
  const float* wp = dw + (size_t)(d*TSZ + o)*ESZ;
  const float* ep = emb + b*ESZ;
  float a = db[d*TSZ + o];
  for (int e=0;e<128;e++) a = fmaf(ep[e], wp[e], a);
  dpe16[(size_t)(d*BB + b)*TSZ + o] = (f16)a;
}

// ---------------- input projection [B,L,14] -> h [B,256,L] fp32 ----------------
__global__ __launch_bounds__(256) void inproj_kernel(const float* __restrict__ x, const float* __restrict__ w,
                                                     const float* __restrict__ bias, float* __restrict__ hb){
  __shared__ float ws[256*14];
  __shared__ float bs[256];
  int tid = threadIdx.x;
#pragma unroll
  for (int c=0;c<14;c++) ws[tid*14+c] = w[tid*14+c];
  bs[tid] = bias[tid];
  __syncthreads();
  int b = blockIdx.x >> 2;
  int l = ((blockIdx.x & 3) << 8) + tid;
  float xv[14];
  const float* xp = x + (size_t)(b*LLEN + l)*CINN;
#pragma unroll
  for (int c=0;c<14;c++) xv[c] = xp[c];
  for (int o=0;o<256;o++){
    float a = bs[o];
#pragma unroll
    for (int c=0;c<14;c++) a = fmaf(ws[o*14+c], xv[c], a);
    hb[(size_t)(b*TSZ + o)*LLEN + l] = a;
  }
}

// ---------------- transpose fp32 [b][256][1024] -> f16 [b][1024][256] ----------------
__global__ __launch_bounds__(256) void h2t_kernel(const float* __restrict__ src, f16* __restrict__ dst){
  __shared__ f16 TT[64*72];
  int tid = threadIdx.x;
  int b = blockIdx.z;
  int l0 = blockIdx.x * 64;
  int t0 = blockIdx.y * 64;
#pragma unroll
  for (int i=0;i<4;i++){
    int job = i*256 + tid;
    int tt = job >> 4, l4 = (job & 15)*4;
    float4 v = *(const float4*)(src + ((size_t)b*TSZ + t0+tt)*LLEN + l0 + l4);
    TT[(l4+0)*72 + tt] = (f16)v.x;
    TT[(l4+1)*72 + tt] = (f16)v.y;
    TT[(l4+2)*72 + tt] = (f16)v.z;
    TT[(l4+3)*72 + tt] = (f16)v.w;
  }
  __syncthreads();
#pragma unroll
  for (int i=0;i<2;i++){
    int job = i*256 + tid;
    int l = job >> 3, g = job & 7;
    f16x8 hv = *(const f16x8*)(TT + l*72 + g*8);
    *(f16x8*)(dst + ((size_t)b*LLEN + l0 + l)*TSZ + t0 + g*8) = hv;
  }
}

// ---------------- MFMA GEMM (unchanged from R5) ----------------
template<int MODE>
__global__ __launch_bounds__(256) void gemm_k(const float* __restrict__ W, const float* __restrict__ bias,
                                              const f16* __restrict__ XT, const f16* __restrict__ dpeD,
                                              float* __restrict__ Y, float* __restrict__ hbuf,
                                              f16* __restrict__ hT16, float* __restrict__ skipb, int first){
  __shared__ f16 sm[17408];
  f16* As = sm;
  f16* Bs = sm + 8192;
  int tid = threadIdx.x;
  int lane = tid & 63;
  int wv = tid >> 6;
  int n_blk = blockIdx.x * 128;
  int m_blk = blockIdx.y * 128;
  int bz = blockIdx.z;
  const f16* Xb = XT + (size_t)bz * (LLEN*TSZ);
  int wm = (wv & 1) * 64;
  int wn = (wv >> 1) * 64;

  f32x16 acc[2][2];
#pragma unroll
  for (int mi=0;mi<2;mi++)
#pragma unroll
    for (int ni=0;ni<2;ni++)
#pragma unroll
      for (int r=0;r<16;r++) acc[mi][ni][r] = 0.f;

  for (int kt=0; kt<4; kt++){
    int k0 = kt*64;
#pragma unroll
    for (int i=0;i<4;i++){
      int job = i*256 + tid;
      int m = job >> 3, gk = job & 7;
      const float* wp = W + (size_t)(m_blk + m)*TSZ + k0 + gk*8;
      float4 u0 = *(const float4*)wp;
      float4 u1 = *(const float4*)(wp+4);
      f16x8 hv;
      hv[0]=(f16)u0.x; hv[1]=(f16)u0.y; hv[2]=(f16)u0.z; hv[3]=(f16)u0.w;
      hv[4]=(f16)u1.x; hv[5]=(f16)u1.y; hv[6]=(f16)u1.z; hv[7]=(f16)u1.w;
      int P = m*8 + (gk ^ (m & 7));
      *(f16x8*)(As + P*8) = hv;
    }
#pragma unroll
    for (int i=0;i<4;i++){
      int job = i*256 + tid;
      int n = job >> 3, gk = job & 7;
      f16x8 hv = *(const f16x8*)(Xb + (size_t)(n_blk + n)*TSZ + k0 + gk*8);
      if (MODE==0){
        f16x8 dv = *(const f16x8*)(dpeD + bz*TSZ + k0 + gk*8);
#pragma unroll
        for (int e=0;e<8;e++) hv[e] = hv[e] + dv[e];
      }
      if (MODE==2){
#pragma unroll
        for (int e=0;e<8;e++) hv[e] = hv[e] * (f16)IS6;
      }
      int P = n*8 + (gk ^ (n & 7));
      *(f16x8*)(Bs + P*8) = hv;
    }
    __syncthreads();
#pragma unroll
    for (int ks=0; ks<4; ks++){
      int q = lane >> 5;
      int gk = ks*2 + q;
      f16x8 af[2], bf[2];
#pragma unroll
      for (int mi=0; mi<2; mi++){
        int m = wm + mi*32 + (lane & 31);
        af[mi] = *(const f16x8*)(As + (m*8 + (gk ^ (m&7)))*8);
      }
#pragma unroll
      for (int ni=0; ni<2; ni++){
        int n = wn + ni*32 + (lane & 31);
        bf[ni] = *(const f16x8*)(Bs + (n*8 + (gk ^ (n&7)))*8);
      }
#pragma unroll
      for (int mi=0; mi<2; mi++)
#pragma unroll
        for (int ni=0; ni<2; ni++)
          acc[mi][ni] = __builtin_amdgcn_mfma_f32_32x32x16_f16(af[mi], bf[ni], acc[mi][ni], 0, 0, 0);
    }
    __syncthreads();
  }

  int q = lane >> 5;
  if (MODE == 0 || MODE == 2){
    const int MD = (MODE==0) ? HSZ : TSZ;
#pragma unroll
    for (int mi=0;mi<2;mi++)
#pragma unroll
      for (int ni=0;ni<2;ni++){
        int col = n_blk + wn + ni*32 + (lane & 31);
#pragma unroll
        for (int r=0;r<16;r++){
          int row = m_blk + wm + mi*32 + (r&3) + 8*(r>>2) + 4*q;
          float v = acc[mi][ni][r] + bias[row];
          if (MODE==2) v = fmaxf(v, 0.f);
          Y[((size_t)bz*MD + row)*LLEN + col] = v;
        }
      }
  } else {
    if (blockIdx.y < 2){
#pragma unroll
      for (int mi=0;mi<2;mi++)
#pragma unroll
        for (int ni=0;ni<2;ni++){
          int col_l = wn + ni*32 + (lane & 31);
#pragma unroll
          for (int r=0;r<16;r++){
            int row_l = wm + mi*32 + (r&3) + 8*(r>>2) + 4*q;
            int row = m_blk + row_l;
            float v = acc[mi][ni][r] + bias[row];
            float* hp = hbuf + ((size_t)bz*TSZ + row)*LLEN + n_blk + col_l;
            float hn = (*hp + v)*RS2;
            *hp = hn;
            sm[col_l*136 + row_l] = (f16)hn;
          }
        }
      __syncthreads();
#pragma unroll
      for (int i=0;i<8;i++){
        int job = i*256 + tid;
        int n = job >> 4, m8 = job & 15;
        f16x8 hv = *(const f16x8*)(sm + n*136 + m8*8);
        *(f16x8*)(hT16 + ((size_t)bz*LLEN + n_blk + n)*TSZ + m_blk + m8*8) = hv;
      }
    } else {
#pragma unroll
      for (int mi=0;mi<2;mi++)
#pragma unroll
        for (int ni=0;ni<2;ni++){
          int col = n_blk + wn + ni*32 + (lane & 31);
#pragma unroll
          for (int r=0;r<16;r++){
            int row = m_blk + wm + mi*32 + (r&3) + 8*(r>>2) + 4*q;
            float v = acc[mi][ni][r] + bias[row];
            float* sp = skipb + ((size_t)bz*TSZ + (row - TSZ))*LLEN + col;
            if (first) *sp = v; else *sp = *sp + v;
          }
        }
    }
  }
}

// ---------------- LN stats: mean/rstd per (b,l) over 512 channels ----------------
__global__ __launch_bounds__(256) void ln_stats(const float* __restrict__ in,
                                                float* __restrict__ mean, float* __restrict__ rstd){
  __shared__ float rs[4][64];
  __shared__ float rq[4][64];
  int tid = threadIdx.x;
  int hg = tid >> 6;
  int lo = tid & 63;
  int b = blockIdx.x >> 4;
  int l = ((blockIdx.x & 15) << 6) + lo;
  size_t base = (size_t)(b*HSZ)*LLEN + l;
  float s=0.f, ss=0.f;
  for (int hh=0; hh<128; hh++){
    float v = in[base + (size_t)(hg*128+hh)*LLEN];
    s += v; ss = fmaf(v,v,ss);
  }
  rs[hg][lo]=s; rq[hg][lo]=ss;
  __syncthreads();
  if (tid < 64){
    float S = rs[0][tid]+rs[1][tid]+rs[2][tid]+rs[3][tid];
    float Q = rq[0][tid]+rq[1][tid]+rq[2][tid]+rq[3][tid];
    float mn = S * (1.f/HSZ);
    float var  = Q * (1.f/HSZ) - mn*mn;
    int lw = ((blockIdx.x & 15) << 6) + tid;
    mean[b*LLEN + lw] = mn;
    rstd[b*LLEN + lw] = rsqrtf(var + 1e-5f);
  }
}

// ---------------- fused S4D v2: 4 rows x 32 chunks x 2 section-halves ----------------
// LN!=0: apply (v-mean)*rstd*g+b during staging (mid-layer LN fusion).
template<int LN>
__global__ __launch_bounds__(256,4) void s4_fused(const float2* __restrict__ cA,
                                                  const float2* __restrict__ cB,
                                                  const float4* __restrict__ cM,
                                                  const float* __restrict__ Dq,
                                                  const float* u, float* y,
                                                  const float* __restrict__ meanp,
                                                  const float* __restrict__ rstdp,
                                                  const float* __restrict__ gp,
                                                  const float* __restrict__ btp){
  __shared__ float uly[4*RSTR2];
  int tid  = threadIdx.x;
  int wave = tid >> 6;                 // row within block
  int lane = tid & 63;
  int s    = lane >> 5;                // section half
  int c    = lane & 31;                // chunk
  int b = blockIdx.x >> 7;
  int hbase = (blockIdx.x & 127) * 4;
  int r = wave;
  int h = hbase + r;
  int rowBase = b*HSZ + hbase;

  float gv = 0.f, bv = 0.f;
  if (LN){ gv = gp[h]; bv = btp[h]; }

  // ---- wave-local staging: wave r loads row r (coalesced float4)
#pragma unroll
  for (int i=0;i<4;i++){
    int fidx = i*64 + lane;            // 0..255
    int l = fidx*4;
    float4 v = *(const float4*)(u + (size_t)(rowBase + r)*LLEN + l);
    if (LN){
      float4 mn = *(const float4*)(meanp + b*LLEN + l);
      float4 rsd= *(const float4*)(rstdp + b*LLEN + l);
      v.x = (v.x-mn.x)*rsd.x*gv + bv;
      v.y = (v.y-mn.y)*rsd.y*gv + bv;
      v.z = (v.z-mn.z)*rsd.z*gv + bv;
      v.w = (v.w-mn.w)*rsd.w*gv + bv;
    }
    int a = r*RSTR2 + ((l>>5)*CSTR2) + (l & 31);
    *(float4*)(uly + a) = v;
  }
  __builtin_amdgcn_wave_barrier();
  __builtin_amdgcn_s_waitcnt(0);
  __builtin_amdgcn_wave_barrier();

  int ubase = r*RSTR2 + c*CSTR2;
  int nbase = h*NST + s*16;

  // ---- DF2 coefficients for this thread's 16 sections
  float a1[16], a2[16], w1[16], w2[16];
  const float2* ap = cA + nbase;
#pragma unroll
  for (int n=0;n<16;n++){ float2 t=ap[n]; a1[n]=t.x; a2[n]=t.y; w1[n]=0.f; w2[n]=0.f; }

  // ---- phase 1: local scan (zero init)
#pragma unroll 2
  for (int j=0;j<32;j++){
    float uu = uly[ubase + j];
#pragma unroll
    for (int n=0;n<16;n++){
      float wn = fmaf(a1[n], w1[n], fmaf(a2[n], w2[n], uu));
      w2[n]=w1[n]; w1[n]=wn;
    }
  }

  // ---- combine: affine prefix over 32 chunks (width-32 shuffles)
  const float4* mp = cM + nbase;
#pragma unroll 2
  for (int n=0;n<16;n++){
    float4 M = mp[n];                  // M^32
    float p=M.x, q=M.y, rr=M.z, ss_=M.w;
    float Vr = w1[n], Vs = w2[n];
#pragma unroll
    for (int d=1; d<32; d<<=1){
      float tr = __shfl_up(Vr, (unsigned)d, 32);
      float ts = __shfl_up(Vs, (unsigned)d, 32);
      float nr = fmaf(p, tr, fmaf(q, ts, Vr));
      float ns = fmaf(rr, tr, fmaf(ss_, ts, Vs));
      bool ok = (c >= d);
      Vr = ok ? nr : Vr;  Vs = ok ? ns : Vs;
      if (d < 16){
        float np_ = fmaf(p,p, q*rr);
        float nq  = q*(p+ss_);
        float nr2 = rr*(p+ss_);
        float ns2 = fmaf(ss_,ss_, q*rr);
        p=np_; q=nq; rr=nr2; ss_=ns2;
      }
    }
    float er = __shfl_up(Vr, 1u, 32);
    float es = __shfl_up(Vs, 1u, 32);
    w1[n] = (c==0) ? 0.f : er;
    w2[n] = (c==0) ? 0.f : es;
  }

  // ---- phase 2: rescan from carry-in; halves sum via shfl_xor(32)
  float b0a[16], b1a[16];
  const float2* bp = cB + nbase;
#pragma unroll
  for (int n=0;n<16;n++){ float2 t=bp[n]; b0a[n]=t.x; b1a[n]=t.y; }
  float dv = Dq[h];
#pragma unroll 1
  for (int j=0;j<32;j++){
    float uu = uly[ubase + j];
    float acc = (s==0) ? dv*uu : 0.f;
#pragma unroll
    for (int n=0;n<16;n++){
      float wn = fmaf(a1[n], w1[n], fmaf(a2[n], w2[n], uu));
      acc = fmaf(b0a[n], wn, fmaf(b1a[n], w1[n], acc));
      w2[n]=w1[n]; w1[n]=wn;
    }
    float tot = acc + __shfl_xor(acc, 32);
    if (s == 0) uly[ubase + j] = tot;
  }
  __builtin_amdgcn_wave_barrier();
  __builtin_amdgcn_s_waitcnt(0);
  __builtin_amdgcn_wave_barrier();

  // ---- wave-local writeback (coalesced float4)
#pragma unroll
  for (int i=0;i<4;i++){
    int fidx = i*64 + lane;
    int l = fidx*4;
    int a = r*RSTR2 + ((l>>5)*CSTR2) + (l & 31);
    float4 v = *(const float4*)(uly + a);
    *(float4*)(y + (size_t)(rowBase + r)*LLEN + l) = v;
  }
}

// ---------------- LN + gate fused, output transposed f16 [b][l][t] ----------------
__global__ __launch_bounds__(256) void ln_gate_kernel(const float* in, f16* __restrict__ gT,
                                                      const float* __restrict__ g, const float* __restrict__ bt){
  __shared__ float rs[4][64];
  __shared__ float rq[4][64];
  __shared__ float mbuf[64], rbuf[64];
  __shared__ f16 gbuf[64*272];
  int tid = threadIdx.x;
  int hg = tid >> 6;
  int lo = tid & 63;
  int b = blockIdx.x >> 4;
  int l0 = (blockIdx.x & 15) << 6;
  int l = l0 + lo;
  size_t base = (size_t)(b*HSZ)*LLEN + l;
  float s=0.f, ss=0.f;
  for (int hh=0; hh<128; hh++){
    float v = in[base + (size_t)(hg*128+hh)*LLEN];
    s += v; ss = fmaf(v,v,ss);
  }
  rs[hg][lo]=s; rq[hg][lo]=ss;
  __syncthreads();
  if (tid < 64){
    float S = rs[0][tid]+rs[1][tid]+rs[2][tid]+rs[3][tid];
    float Q = rq[0][tid]+rq[1][tid]+rq[2][tid]+rq[3][tid];
    float mean = S * (1.f/HSZ);
    float var  = Q * (1.f/HSZ) - mean*mean;
    mbuf[tid]=mean;
    rbuf[tid]=rsqrtf(var + 1e-5f);
  }
  __syncthreads();
  float mean = mbuf[lo], rstd = rbuf[lo];
  for (int tt=0; tt<64; tt++){
    int t = hg*64 + tt;
    float a = (in[base + (size_t)t*LLEN]       - mean)*rstd*g[t]     + bt[t];
    float f = (in[base + (size_t)(t+256)*LLEN] - mean)*rstd*g[t+256] + bt[t+256];
    float sg = 1.f/(1.f+__expf(-a));
    float th = 1.f - 2.f/(__expf(2.f*f)+1.f);
    gbuf[lo*272 + t] = (f16)(sg*th);
  }
  __syncthreads();
#pragma unroll
  for (int i=0;i<8;i++){
    int job = i*256 + tid;
    int ll = job >> 5, g8 = (job & 31)*8;
    f16x8 hv = *(const f16x8*)(gbuf + ll*272 + g8);
    *(f16x8*)(gT + ((size_t)b*LLEN + l0 + ll)*TSZ + g8) = hv;
  }
}

// ---------------- out2 projection + 1/sqrt(beta) + transpose to [B,L,14] --------
__global__ __launch_bounds__(256) void out2_kernel(const float* __restrict__ w2, const float* __restrict__ b2,
                                                   const float* __restrict__ t, const float* __restrict__ z,
                                                   float* __restrict__ outp){
  __shared__ float ws[14*256];
  __shared__ float bs[14];
  int tid = threadIdx.x;
#pragma unroll
  for (int c=0;c<14;c++) ws[c*256+tid] = w2[c*256+tid];
  if (tid < 14) bs[tid] = b2[tid];
  __syncthreads();
  int b = blockIdx.x >> 2;
  int l = ((blockIdx.x & 3) << 8) + tid;
  float tb = t[b];
  float scale = rsqrtf(1e-4f + tb*(2e-2f - 1e-4f));
  float acc[14];
#pragma unroll
  for (int c=0;c<14;c++) acc[c]=0.f;
  const float* zp = z + (size_t)b*TSZ*LLEN + l;
  for (int tt2=0; tt2<256; tt2++){
    float xv = zp[(size_t)tt2*LLEN];
#pragma unroll
    for (int c=0;c<14;c++) acc[c] = fmaf(ws[c*256+tt2], xv, acc[c]);
  }
  float* op = outp + (size_t)(b*LLEN + l)*CINN;
#pragma unroll
  for (int c=0;c<14;c++) op[c] = (acc[c]+bs[c])*scale;
}

// ---------------- host launcher ----------------
extern "C" void kernel_launch(void* const* d_in, const int* in_sizes, int n_in,
                              void* d_out, int out_size, void* d_ws, size_t ws_size,
                              hipStream_t stream) {
  (void)in_sizes; (void)n_in; (void)out_size;
  if (ws_size < (size_t)WS_FLOATS * 4) return;

  const float* x      = (const float*)d_in[0];
  const float* t      = (const float*)d_in[1];
  const float* gfpW   = (const float*)d_in[2];
  const float* ew1    = (const float*)d_in[3];
  const float* eb1    = (const float*)d_in[4];
  const float* ew2    = (const float*)d_in[5];
  const float* eb2    = (const float*)d_in[6];
  const float* in_w   = (const float*)d_in[7];
  const float* in_b   = (const float*)d_in[8];
  const float* out1_w = (const float*)d_in[9];
  const float* out1_b = (const float*)d_in[10];
  const float* out2_w = (const float*)d_in[11];
  const float* out2_b = (const float*)d_in[12];
  const float* dp_w   = (const float*)d_in[13];
  const float* dp_b   = (const float*)d_in[14];
  const float* ip_w   = (const float*)d_in[15];
  const float* ip_b   = (const float*)d_in[16];
  const float* op_w   = (const float*)d_in[17];
  const float* op_b   = (const float*)d_in[18];
  const float* log_dt = (const float*)d_in[19];
  const float* logA   = (const float*)d_in[20];
  const float* Aim    = (const float*)d_in[21];
  const float* Cre    = (const float*)d_in[22];
  const float* Cim    = (const float*)d_in[23];
  const float* s4D    = (const float*)d_in[24];
  const float* ln_g   = (const float*)d_in[25];
  const float* ln_b   = (const float*)d_in[26];
  float* out = (float*)d_out;
  float* ws = (float*)d_ws;

  float2* cA   = (float2*)(ws + OFF_A);
  float2* cB   = (float2*)(ws + OFF_B);
  float4* cM   = (float4*)(ws + OFF_M);
  float* embb  = ws + OFF_EMB;
  f16*   dpe16 = (f16*)(ws + OFF_DPE16);
  float* hbuf  = ws + OFF_H;
  float* skipb = ws + OFF_SKIP;
  float* y1    = ws + OFF_Y1;
  f16*   hT16  = (f16*)(ws + OFF_HT);
  f16*   gT16  = (f16*)(ws + OFF_GT);
  f16*   sT16  = (f16*)(ws + OFF_ST);
  float* meanb = ws + OFF_MEAN;
  float* rstdb = ws + OFF_RSTD;

  consts_kernel<<<768,256,0,stream>>>(log_dt, logA, Aim, Cre, Cim, cA, cB, cM);
  emb_kernel<<<BB,128,0,stream>>>(t, gfpW, ew1, eb1, ew2, eb2, embb);
  dpe_kernel<<<NDEPTH*BB,256,0,stream>>>(embb, dp_w, dp_b, dpe16);
  inproj_kernel<<<64,256,0,stream>>>(x, in_w, in_b, hbuf);
  h2t_kernel<<<dim3(16,4,16),256,0,stream>>>(hbuf, hT16);

  for (int d=0; d<NDEPTH; d++){
    int q0 = d*2, q1 = d*2+1;
    // ip: hT16 (+dpe) -> y1 fp32
    gemm_k<0><<<dim3(8,4,16),256,0,stream>>>(ip_w + (size_t)d*HSZ*TSZ, ip_b + d*HSZ,
                                             hT16, dpe16 + (size_t)d*BB*TSZ,
                                             y1, nullptr, nullptr, nullptr, 0);
    // S4 q0 (no LN on input)
    s4_fused<0><<<2048,256,0,stream>>>(cA + (size_t)q0*QHN, cB + (size_t)q0*QHN,
                                       cM + (size_t)q0*QHN, s4D + q0*HSZ, y1, y1,
                                       nullptr, nullptr, nullptr, nullptr);
    // mid-LN stats (params q0 applied inside next s4's staging)
    ln_stats<<<256,256,0,stream>>>(y1, meanb, rstdb);
    // S4 q1 with fused LN(q0) on staging
    s4_fused<1><<<2048,256,0,stream>>>(cA + (size_t)q1*QHN, cB + (size_t)q1*QHN,
                                       cM + (size_t)q1*QHN, s4D + q1*HSZ, y1, y1,
                                       meanb, rstdb, ln_g + q0*HSZ, ln_b + q0*HSZ);
    // LN(q1) + gate -> gT16
    ln_gate_kernel<<<256,256,0,stream>>>(y1, gT16, ln_g + q1*HSZ, ln_b + q1*HSZ);
    // op: gT16 -> res(hbuf,hT16) / skip(skipb)
    gemm_k<1><<<dim3(8,4,16),256,0,stream>>>(op_w + (size_t)d*HSZ*TSZ, op_b + d*HSZ,
                                             gT16, nullptr, nullptr, hbuf, hT16, skipb, (d==0)?1:0);
  }
  h2t_kernel<<<dim3(16,4,16),256,0,stream>>>(skipb, sT16);
  gemm_k<2><<<dim3(8,2,16),256,0,stream>>>(out1_w, out1_b, sT16, nullptr,
                                           y1, nullptr, nullptr, nullptr, 0);
  out2_kernel<<<64,256,0,stream>>>(out2_w, out2_b, t, y1, out);
}

// Round 8
// 906.609 us; speedup vs baseline: 2.8360x; 1.5071x over previous
//
#include <hip/hip_runtime.h>

// ---------------- problem constants ----------------
#define BB     16
#define LLEN   1024
#define CINN   14
#define TSZ    256
#define HSZ    512
#define NST    32
#define ESZ    128
#define NDEPTH 6
#define QHN    (HSZ*NST)

#define RS2 0.70710678118654752f   // 1/sqrt(2)
#define IS6 0.40824829046386302f   // 1/sqrt(6)

typedef unsigned short u16;
typedef unsigned int   u32;
typedef _Float16 f16;
typedef __attribute__((ext_vector_type(2)))  _Float16 f16x2;
typedef __attribute__((ext_vector_type(4)))  _Float16 f16x4;
typedef __attribute__((ext_vector_type(8)))  _Float16 f16x8;
typedef __attribute__((ext_vector_type(16))) float    f32x16;

// workspace layout (float offsets)
#define OFF_LAM   0u          // float2 lambda      x 12*16384
#define OFF_C     393216u     // float2 C'          x 12*16384
#define OFF_LAMP  786432u     // float2 lambda^64   x 12*16384
#define OFF_EMB   1179648u
#define OFF_DPE16 1181696u
#define OFF_H     1193984u    // fp32 [16][256][1024]
#define OFF_SKIP  5388288u
#define OFF_Y1    9582592u    // fp32 [16][512][1024]
#define OFF_HT    17971200u   // f16 [16][1024][256]
#define OFF_GT    20068352u
#define OFF_ST    22165504u
#define OFF_MEAN  24262656u
#define OFF_RSTD  24279040u
#define OFF_MATS  24295424u   // f16 [2][512][3][4096] = 6291456 floats
#define WS_FLOATS 30586880u

// ---------------- S4D constants: lambda, C' = 2C(lambda-1)/A, lambda^64 ----------------
__global__ void consts_kernel(const float* __restrict__ log_dt, const float* __restrict__ logA,
                              const float* __restrict__ Aim,   const float* __restrict__ Cre,
                              const float* __restrict__ Cim,
                              float2* __restrict__ lam2, float2* __restrict__ C2,
                              float2* __restrict__ lamP){
  int gid = blockIdx.x*256 + threadIdx.x;            // q*16384 + h*32 + n
  int h = (gid>>5) & 511;
  int q = gid >> 14;
  float dt  = expf(log_dt[q*HSZ + h]);
  float are = -expf(logA[gid]);
  float aim = Aim[gid];
  float dre = are*dt, dim = aim*dt;
  float e   = expf(dre);
  float lre = e*cosf(dim), lim = e*sinf(dim);
  float nre = lre - 1.f, nim = lim;
  float invden = 1.f/(are*are + aim*aim);
  float tre = (nre*are + nim*aim)*invden;
  float tim = (nim*are - nre*aim)*invden;
  float cr = Cre[gid], ci = Cim[gid];
  float Cr = 2.f*(cr*tre - ci*tim);
  float Ci = 2.f*(cr*tim + ci*tre);
  lam2[gid] = make_float2(lre, lim);
  C2[gid]   = make_float2(Cr, Ci);
  float pr = lre, pi = lim;
#pragma unroll
  for (int i=0;i<6;i++){ float nr2 = pr*pr - pi*pi; pi = 2.f*pr*pi; pr = nr2; }
  lamP[gid] = make_float2(pr, pi);
}

// ---------------- build per-(q,h) f16 matrices T,V,E in MFMA A-frag order ----------------
// frag order: element (m,k) at ((k>>3)*64 + m)*8 + (k&7)
__global__ __launch_bounds__(256) void build_mats(const float2* __restrict__ lam2d,
                                                  const float2* __restrict__ C2d,
                                                  const float* __restrict__ Dd,
                                                  f16* __restrict__ mats){
  __shared__ float Pre[65][33];
  __shared__ float Pim[65][33];
  __shared__ float Kk[64];
  int bid = blockIdx.x;
  int sub = bid >> 9;            // 0/1 (layer within depth)
  int h   = bid & 511;
  const float2* lp = lam2d + sub*QHN + h*NST;
  const float2* cp = C2d  + sub*QHN + h*NST;
  int tid = threadIdx.x;
  int n  = tid & 31;
  int pg = tid >> 5;             // 0..7
  {
    float2 l = lp[n];
    float ar=l.x, ai=l.y;
#pragma unroll
    for (int i=0;i<3;i++){ float t2 = ar*ar - ai*ai; ai = 2.f*ar*ai; ar = t2; }
    float br=1.f, bi=0.f;
    for (int i=0;i<pg;i++){ float t2 = br*ar - bi*ai; bi = br*ai + bi*ar; br = t2; }
    float pr=br, pi=bi;
#pragma unroll
    for (int i=0;i<8;i++){
      Pre[8*pg+i][n] = pr; Pim[8*pg+i][n] = pi;
      float t2 = pr*l.x - pi*l.y; pi = pr*l.y + pi*l.x; pr = t2;
    }
    if (pg == 7){ Pre[64][n] = pr; Pim[64][n] = pi; }
  }
  __syncthreads();
  if (tid < 64){
    float s = 0.f;
    for (int n2=0;n2<32;n2++){
      float2 c_ = cp[n2];
      s += c_.x*Pre[tid][n2] - c_.y*Pim[tid][n2];
    }
    Kk[tid] = s;
  }
  __syncthreads();
  float Kdiag = Kk[0] + Dd[sub*HSZ + h];
  f16* base = mats + (size_t)(sub*512 + h)*12288;
#pragma unroll
  for (int jj=0; jj<6; jj++){
    int job = jj*256 + tid;       // 0..1535
    int mat = job >> 9;           // 0:T 1:V 2:E
    int rem = job & 511;
    int m = rem >> 3;
    int g = rem & 7;
    f16x8 vals;
    if (mat == 0){
#pragma unroll
      for (int j8=0;j8<8;j8++){
        int k = g*8 + j8;
        float v = (m > k) ? Kk[m-k] : ((m == k) ? Kdiag : 0.f);
        vals[j8] = (f16)v;
      }
    } else if (mat == 1){
      int n2 = m >> 1; int im = m & 1;
#pragma unroll
      for (int j8=0;j8<8;j8++){
        int k = g*8 + j8; int p = 63 - k;
        vals[j8] = (f16)(im ? Pim[p][n2] : Pre[p][n2]);
      }
    } else {
#pragma unroll
      for (int j8=0;j8<8;j8++){
        int k = g*8 + j8; int n2 = k >> 1;
        float2 c_ = cp[n2];
        float pr = Pre[m+1][n2], pi = Pim[m+1][n2];
        float re  = c_.x*pr - c_.y*pi;
        float imv = c_.x*pi + c_.y*pr;
        vals[j8] = (f16)((k & 1) ? -imv : re);
      }
    }
    *(f16x8*)(base + mat*4096 + (g*64 + m)*8) = vals;
  }
}

// ---------------- diffusion embedding MLP ----------------
__global__ void emb_kernel(const float* __restrict__ t, const float* __restrict__ gw,
                           const float* __restrict__ w1, const float* __restrict__ b1,
                           const float* __restrict__ w2, const float* __restrict__ b2,
                           float* __restrict__ emb){
  __shared__ float e0[128], e1[128];
  int b = blockIdx.x, tid = threadIdx.x;
  float tb = t[b];
  if (tid < 64){
    float xp = tb * gw[tid] * 6.283185307179586f;
    e0[tid]    = sinf(xp);
    e0[tid+64] = cosf(xp);
  }
  __syncthreads();
  float a = b1[tid];
  for (int i=0;i<128;i++) a = fmaf(e0[i], w1[tid*128+i], a);
  a = a / (1.f + __expf(-a));
  e1[tid] = a;
  __syncthreads();
  float a2 = b2[tid];
  for (int i=0;i<128;i++) a2 = fmaf(e1[i], w2[tid*128+i], a2);
  a2 = a2 / (1.f + __expf(-a2));
  emb[b*ESZ + tid] = a2;
}

// ---------------- per-depth diffusion projection -> f16 ----------------
__global__ void dpe_kernel(const float* __restrict__ emb, const float* __restrict__ dw,
                           const float* __restrict__ db, f16* __restrict__ dpe16){
  int blk = blockIdx.x; int d = blk >> 4; int b = blk & 15; int o = threadIdx.x;
  const float* wp = dw + (size_t)(d*TSZ + o)*ESZ;
  const float* ep = emb + b*ESZ;
  float a = db[d*TSZ + o];
  for (int e=0;e<128;e++) a = fmaf(ep[e], wp[e], a);
  dpe16[(size_t)(d*BB + b)*TSZ + o] = (f16)a;
}

// ---------------- input projection [B,L,14] -> h [B,256,L] fp32 ----------------
__global__ __launch_bounds__(256) void inproj_kernel(const float* __restrict__ x, const float* __restrict__ w,
                                                     const float* __restrict__ bias, float* __restrict__ hb){
  __shared__ float ws[256*14];
  __shared__ float bs[256];
  int tid = threadIdx.x;
#pragma unroll
  for (int c=0;c<14;c++) ws[tid*14+c] = w[tid*14+c];
  bs[tid] = bias[tid];
  __syncthreads();
  int b = blockIdx.x >> 2;
  int l = ((blockIdx.x & 3) << 8) + tid;
  float xv[14];
  const float* xp = x + (size_t)(b*LLEN + l)*CINN;
#pragma unroll
  for (int c=0;c<14;c++) xv[c] = xp[c];
  for (int o=0;o<256;o++){
    float a = bs[o];
#pragma unroll
    for (int c=0;c<14;c++) a = fmaf(ws[o*14+c], xv[c], a);
    hb[(size_t)(b*TSZ + o)*LLEN + l] = a;
  }
}

// ---------------- transpose fp32 [b][256][1024] -> f16 [b][1024][256] ----------------
__global__ __launch_bounds__(256) void h2t_kernel(const float* __restrict__ src, f16* __restrict__ dst){
  __shared__ f16 TT[64*72];
  int tid = threadIdx.x;
  int b = blockIdx.z;
  int l0 = blockIdx.x * 64;
  int t0 = blockIdx.y * 64;
#pragma unroll
  for (int i=0;i<4;i++){
    int job = i*256 + tid;
    int tt = job >> 4, l4 = (job & 15)*4;
    float4 v = *(const float4*)(src + ((size_t)b*TSZ + t0+tt)*LLEN + l0 + l4);
    TT[(l4+0)*72 + tt] = (f16)v.x;
    TT[(l4+1)*72 + tt] = (f16)v.y;
    TT[(l4+2)*72 + tt] = (f16)v.z;
    TT[(l4+3)*72 + tt] = (f16)v.w;
  }
  __syncthreads();
#pragma unroll
  for (int i=0;i<2;i++){
    int job = i*256 + tid;
    int l = job >> 3, g = job & 7;
    f16x8 hv = *(const f16x8*)(TT + l*72 + g*8);
    *(f16x8*)(dst + ((size_t)b*LLEN + l0 + l)*TSZ + t0 + g*8) = hv;
  }
}

// ---------------- MFMA GEMM (validated in R5) ----------------
template<int MODE>
__global__ __launch_bounds__(256) void gemm_k(const float* __restrict__ W, const float* __restrict__ bias,
                                              const f16* __restrict__ XT, const f16* __restrict__ dpeD,
                                              float* __restrict__ Y, float* __restrict__ hbuf,
                                              f16* __restrict__ hT16, float* __restrict__ skipb, int first){
  __shared__ f16 sm[17408];
  f16* As = sm;
  f16* Bs = sm + 8192;
  int tid = threadIdx.x;
  int lane = tid & 63;
  int wv = tid >> 6;
  int n_blk = blockIdx.x * 128;
  int m_blk = blockIdx.y * 128;
  int bz = blockIdx.z;
  const f16* Xb = XT + (size_t)bz * (LLEN*TSZ);
  int wm = (wv & 1) * 64;
  int wn = (wv >> 1) * 64;

  f32x16 acc[2][2];
#pragma unroll
  for (int mi=0;mi<2;mi++)
#pragma unroll
    for (int ni=0;ni<2;ni++)
#pragma unroll
      for (int r=0;r<16;r++) acc[mi][ni][r] = 0.f;

  for (int kt=0; kt<4; kt++){
    int k0 = kt*64;
#pragma unroll
    for (int i=0;i<4;i++){
      int job = i*256 + tid;
      int m = job >> 3, gk = job & 7;
      const float* wp = W + (size_t)(m_blk + m)*TSZ + k0 + gk*8;
      float4 u0 = *(const float4*)wp;
      float4 u1 = *(const float4*)(wp+4);
      f16x8 hv;
      hv[0]=(f16)u0.x; hv[1]=(f16)u0.y; hv[2]=(f16)u0.z; hv[3]=(f16)u0.w;
      hv[4]=(f16)u1.x; hv[5]=(f16)u1.y; hv[6]=(f16)u1.z; hv[7]=(f16)u1.w;
      int P = m*8 + (gk ^ (m & 7));
      *(f16x8*)(As + P*8) = hv;
    }
#pragma unroll
    for (int i=0;i<4;i++){
      int job = i*256 + tid;
      int n = job >> 3, gk = job & 7;
      f16x8 hv = *(const f16x8*)(Xb + (size_t)(n_blk + n)*TSZ + k0 + gk*8);
      if (MODE==0){
        f16x8 dv = *(const f16x8*)(dpeD + bz*TSZ + k0 + gk*8);
#pragma unroll
        for (int e=0;e<8;e++) hv[e] = hv[e] + dv[e];
      }
      if (MODE==2){
#pragma unroll
        for (int e=0;e<8;e++) hv[e] = hv[e] * (f16)IS6;
      }
      int P = n*8 + (gk ^ (n & 7));
      *(f16x8*)(Bs + P*8) = hv;
    }
    __syncthreads();
#pragma unroll
    for (int ks=0; ks<4; ks++){
      int q = lane >> 5;
      int gk = ks*2 + q;
      f16x8 af[2], bf[2];
#pragma unroll
      for (int mi=0; mi<2; mi++){
        int m = wm + mi*32 + (lane & 31);
        af[mi] = *(const f16x8*)(As + (m*8 + (gk ^ (m&7)))*8);
      }
#pragma unroll
      for (int ni=0; ni<2; ni++){
        int n = wn + ni*32 + (lane & 31);
        bf[ni] = *(const f16x8*)(Bs + (n*8 + (gk ^ (n&7)))*8);
      }
#pragma unroll
      for (int mi=0; mi<2; mi++)
#pragma unroll
        for (int ni=0; ni<2; ni++)
          acc[mi][ni] = __builtin_amdgcn_mfma_f32_32x32x16_f16(af[mi], bf[ni], acc[mi][ni], 0, 0, 0);
    }
    __syncthreads();
  }

  int q = lane >> 5;
  if (MODE == 0 || MODE == 2){
    const int MD = (MODE==0) ? HSZ : TSZ;
#pragma unroll
    for (int mi=0;mi<2;mi++)
#pragma unroll
      for (int ni=0;ni<2;ni++){
        int col = n_blk + wn + ni*32 + (lane & 31);
#pragma unroll
        for (int r=0;r<16;r++){
          int row = m_blk + wm + mi*32 + (r&3) + 8*(r>>2) + 4*q;
          float v = acc[mi][ni][r] + bias[row];
          if (MODE==2) v = fmaxf(v, 0.f);
          Y[((size_t)bz*MD + row)*LLEN + col] = v;
        }
      }
  } else {
    if (blockIdx.y < 2){
#pragma unroll
      for (int mi=0;mi<2;mi++)
#pragma unroll
        for (int ni=0;ni<2;ni++){
          int col_l = wn + ni*32 + (lane & 31);
#pragma unroll
          for (int r=0;r<16;r++){
            int row_l = wm + mi*32 + (r&3) + 8*(r>>2) + 4*q;
            int row = m_blk + row_l;
            float v = acc[mi][ni][r] + bias[row];
            float* hp = hbuf + ((size_t)bz*TSZ + row)*LLEN + n_blk + col_l;
            float hn = (*hp + v)*RS2;
            *hp = hn;
            sm[col_l*136 + row_l] = (f16)hn;
          }
        }
      __syncthreads();
#pragma unroll
      for (int i=0;i<8;i++){
        int job = i*256 + tid;
        int n = job >> 4, m8 = job & 15;
        f16x8 hv = *(const f16x8*)(sm + n*136 + m8*8);
        *(f16x8*)(hT16 + ((size_t)bz*LLEN + n_blk + n)*TSZ + m_blk + m8*8) = hv;
      }
    } else {
#pragma unroll
      for (int mi=0;mi<2;mi++)
#pragma unroll
        for (int ni=0;ni<2;ni++){
          int col = n_blk + wn + ni*32 + (lane & 31);
#pragma unroll
          for (int r=0;r<16;r++){
            int row = m_blk + wm + mi*32 + (r&3) + 8*(r>>2) + 4*q;
            float v = acc[mi][ni][r] + bias[row];
            float* sp = skipb + ((size_t)bz*TSZ + (row - TSZ))*LLEN + col;
            if (first) *sp = v; else *sp = *sp + v;
          }
        }
    }
  }
}

// ---------------- S4D via MFMA conv: Z=V*U; prefix; Y = T*U + E*Sprev ----------------
// block = one h, 8 batches (128 cols of 64); wave = 2 batches (32 cols).
// Sync = __syncthreads; Y stored f16 in ZSbuf region (no cross-type overlap).
template<int LN>
__global__ __launch_bounds__(256) void s4_mfma(const f16* __restrict__ matsq,
                                               const float2* __restrict__ lamPq,
                                               const float* u, float* y,
                                               const float* __restrict__ meanp,
                                               const float* __restrict__ rstdp,
                                               const float* __restrict__ gp,
                                               const float* __restrict__ btp){
  __shared__ f16 Ubuf[128*72];
  __shared__ f16 ZSbuf[128*72];     // Z -> Sprev -> Y (all f16)

  int tid  = threadIdx.x;
  int w    = tid >> 6;
  int lane = tid & 63;
  int q    = lane >> 5;
  int colL = lane & 31;
  int h     = blockIdx.x & 511;
  int bhalf = blockIdx.x >> 9;
  int b0    = bhalf*8;

  float gv = 0.f, bv = 0.f;
  if (LN){ gv = gp[h]; bv = btp[h]; }

  const f16* matT = matsq + (size_t)h*12288;
  const f16* matV = matT + 4096;
  const f16* matE = matT + 8192;

  // ---- stage u (wave w covers batches b0+2w, b0+2w+1), optional fused LN
#pragma unroll
  for (int i=0;i<8;i++){
    int fidx = i*64 + lane;
    int row = fidx >> 8;                  // 0/1
    int l   = (fidx & 255)*4;
    int b   = b0 + 2*w + row;
    float4 v = *(const float4*)(u + ((size_t)b*HSZ + h)*LLEN + l);
    if (LN){
      float4 mn = *(const float4*)(meanp + b*LLEN + l);
      float4 rs = *(const float4*)(rstdp + b*LLEN + l);
      v.x = (v.x-mn.x)*rs.x*gv + bv;
      v.y = (v.y-mn.y)*rs.y*gv + bv;
      v.z = (v.z-mn.z)*rs.z*gv + bv;
      v.w = (v.w-mn.w)*rs.w*gv + bv;
    }
    int col = (2*w + row)*16 + (l >> 6);
    int k   = l & 63;
    f16x4 hv; hv[0]=(f16)v.x; hv[1]=(f16)v.y; hv[2]=(f16)v.z; hv[3]=(f16)v.w;
    *(f16x4*)(Ubuf + col*72 + k) = hv;
  }
  __syncthreads();

  int strip = w*32;

  // ---- GEMM1: Z = V @ U  (state-components x cols)
  {
    f32x16 zacc[2];
#pragma unroll
    for (int mt=0;mt<2;mt++)
#pragma unroll
      for (int r=0;r<16;r++) zacc[mt][r] = 0.f;
#pragma unroll
    for (int kt=0; kt<4; kt++){
      int kg = kt*2 + q;
      f16x8 bfrag = *(const f16x8*)(Ubuf + (strip+colL)*72 + kg*8);
#pragma unroll
      for (int mt=0; mt<2; mt++){
        f16x8 afrag = *(const f16x8*)(matV + ((size_t)(kg*64 + mt*32 + colL))*8);
        zacc[mt] = __builtin_amdgcn_mfma_f32_32x32x16_f16(afrag, bfrag, zacc[mt], 0, 0, 0);
      }
    }
#pragma unroll
    for (int mt=0;mt<2;mt++)
#pragma unroll
      for (int rg=0;rg<4;rg++){
        int st0 = mt*32 + rg*8 + q*4;
        f16x4 zp;
        zp[0]=(f16)zacc[mt][rg*4+0]; zp[1]=(f16)zacc[mt][rg*4+1];
        zp[2]=(f16)zacc[mt][rg*4+2]; zp[3]=(f16)zacc[mt][rg*4+3];
        *(f16x4*)(ZSbuf + (strip+colL)*72 + st0) = zp;
      }
  }
  __syncthreads();

  // ---- prefix over 16 chunks (in-place Z -> Sprev), per (batch-row, n) chain
  {
    int n  = lane & 31;
    int colb = (2*w + (lane>>5))*16;
    float2 l64 = lamPq[h*NST + n];
    float Sre = 0.f, Sim = 0.f;
#pragma unroll
    for (int c=0;c<16;c++){
      f16* p = ZSbuf + (colb + c)*72 + 2*n;
      f16x2 z2 = *(f16x2*)p;
      f16x2 sp_; sp_[0] = (f16)Sre; sp_[1] = (f16)Sim;
      *(f16x2*)p = sp_;
      float nr = fmaf(l64.x, Sre, fmaf(-l64.y, Sim, (float)z2[0]));
      float ni = fmaf(l64.x, Sim, fmaf( l64.y, Sre, (float)z2[1]));
      Sre = nr; Sim = ni;
    }
  }
  __syncthreads();

  // ---- GEMM2: Y = T @ U + E @ Sprev
  f32x16 yacc[2];
#pragma unroll
  for (int mt=0;mt<2;mt++)
#pragma unroll
    for (int r=0;r<16;r++) yacc[mt][r] = 0.f;
#pragma unroll
  for (int kt=0; kt<4; kt++){
    int kg = kt*2 + q;
    f16x8 bu = *(const f16x8*)(Ubuf  + (strip+colL)*72 + kg*8);
    f16x8 bs = *(const f16x8*)(ZSbuf + (strip+colL)*72 + kg*8);
#pragma unroll
    for (int mt=0; mt<2; mt++){
      f16x8 aT = *(const f16x8*)(matT + ((size_t)(kg*64 + mt*32 + colL))*8);
      yacc[mt] = __builtin_amdgcn_mfma_f32_32x32x16_f16(aT, bu, yacc[mt], 0, 0, 0);
    }
#pragma unroll
    for (int mt=0; mt<2; mt++){
      f16x8 aE = *(const f16x8*)(matE + ((size_t)(kg*64 + mt*32 + colL))*8);
      yacc[mt] = __builtin_amdgcn_mfma_f32_32x32x16_f16(aE, bs, yacc[mt], 0, 0, 0);
    }
  }
  __syncthreads();   // all ZSbuf reads done before overwrite with Y

  // ---- store Y (f16) into ZSbuf region, then coalesced global write (f32)
#pragma unroll
  for (int mt=0;mt<2;mt++)
#pragma unroll
    for (int rg=0;rg<4;rg++){
      int j0 = mt*32 + rg*8 + q*4;
      f16x4 yv;
      yv[0]=(f16)yacc[mt][rg*4+0]; yv[1]=(f16)yacc[mt][rg*4+1];
      yv[2]=(f16)yacc[mt][rg*4+2]; yv[3]=(f16)yacc[mt][rg*4+3];
      *(f16x4*)(ZSbuf + (strip+colL)*72 + j0) = yv;
    }
  __syncthreads();
#pragma unroll
  for (int i=0;i<8;i++){
    int fidx = i*64 + lane;
    int row = fidx >> 8;
    int l   = (fidx & 255)*4;
    int b   = b0 + 2*w + row;
    int col = (2*w + row)*16 + (l >> 6);
    int j   = l & 63;
    f16x4 hv = *(const f16x4*)(ZSbuf + col*72 + j);
    float4 v = make_float4((float)hv[0], (float)hv[1], (float)hv[2], (float)hv[3]);
    *(float4*)(y + ((size_t)b*HSZ + h)*LLEN + l) = v;
  }
}

// ---------------- LN stats: mean/rstd per (b,l) ----------------
__global__ __launch_bounds__(256) void ln_stats(const float* __restrict__ in,
                                                float* __restrict__ mean, float* __restrict__ rstd){
  __shared__ float rs[4][64];
  __shared__ float rq[4][64];
  int tid = threadIdx.x;
  int hg = tid >> 6;
  int lo = tid & 63;
  int b = blockIdx.x >> 4;
  int l = ((blockIdx.x & 15) << 6) + lo;
  size_t base = (size_t)(b*HSZ)*LLEN + l;
  float s=0.f, ss=0.f;
  for (int hh=0; hh<128; hh++){
    float v = in[base + (size_t)(hg*128+hh)*LLEN];
    s += v; ss = fmaf(v,v,ss);
  }
  rs[hg][lo]=s; rq[hg][lo]=ss;
  __syncthreads();
  if (tid < 64){
    float S = rs[0][tid]+rs[1][tid]+rs[2][tid]+rs[3][tid];
    float Q = rq[0][tid]+rq[1][tid]+rq[2][tid]+rq[3][tid];
    float mn = S * (1.f/HSZ);
    float var  = Q * (1.f/HSZ) - mn*mn;
    int lw = ((blockIdx.x & 15) << 6) + tid;
    mean[b*LLEN + lw] = mn;
    rstd[b*LLEN + lw] = rsqrtf(var + 1e-5f);
  }
}

// ---------------- LN + gate fused, output transposed f16 [b][l][t] ----------------
__global__ __launch_bounds__(256) void ln_gate_kernel(const float* in, f16* __restrict__ gT,
                                                      const float* __restrict__ g, const float* __restrict__ bt){
  __shared__ float rs[4][64];
  __shared__ float rq[4][64];
  __shared__ float mbuf[64], rbuf[64];
  __shared__ f16 gbuf[64*272];
  int tid = threadIdx.x;
  int hg = tid >> 6;
  int lo = tid & 63;
  int b = blockIdx.x >> 4;
  int l0 = (blockIdx.x & 15) << 6;
  int l = l0 + lo;
  size_t base = (size_t)(b*HSZ)*LLEN + l;
  float s=0.f, ss=0.f;
  for (int hh=0; hh<128; hh++){
    float v = in[base + (size_t)(hg*128+hh)*LLEN];
    s += v; ss = fmaf(v,v,ss);
  }
  rs[hg][lo]=s; rq[hg][lo]=ss;
  __syncthreads();
  if (tid < 64){
    float S = rs[0][tid]+rs[1][tid]+rs[2][tid]+rs[3][tid];
    float Q = rq[0][tid]+rq[1][tid]+rq[2][tid]+rq[3][tid];
    float mean = S * (1.f/HSZ);
    float var  = Q * (1.f/HSZ) - mean*mean;
    mbuf[tid]=mean;
    rbuf[tid]=rsqrtf(var + 1e-5f);
  }
  __syncthreads();
  float mean = mbuf[lo], rstd = rbuf[lo];
  for (int tt=0; tt<64; tt++){
    int t = hg*64 + tt;
    float a = (in[base + (size_t)t*LLEN]       - mean)*rstd*g[t]     + bt[t];
    float f = (in[base + (size_t)(t+256)*LLEN] - mean)*rstd*g[t+256] + bt[t+256];
    float sg = 1.f/(1.f+__expf(-a));
    float th = 1.f - 2.f/(__expf(2.f*f)+1.f);
    gbuf[lo*272 + t] = (f16)(sg*th);
  }
  __syncthreads();
#pragma unroll
  for (int i=0;i<8;i++){
    int job = i*256 + tid;
    int ll = job >> 5, g8 = (job & 31)*8;
    f16x8 hv = *(const f16x8*)(gbuf + ll*272 + g8);
    *(f16x8*)(gT + ((size_t)b*LLEN + l0 + ll)*TSZ + g8) = hv;
  }
}

// ---------------- out2 projection + 1/sqrt(beta) + transpose to [B,L,14] --------
__global__ __launch_bounds__(256) void out2_kernel(const float* __restrict__ w2, const float* __restrict__ b2,
                                                   const float* __restrict__ t, const float* __restrict__ z,
                                                   float* __restrict__ outp){
  __shared__ float ws[14*256];
  __shared__ float bs[14];
  int tid = threadIdx.x;
#pragma unroll
  for (int c=0;c<14;c++) ws[c*256+tid] = w2[c*256+tid];
  if (tid < 14) bs[tid] = b2[tid];
  __syncthreads();
  int b = blockIdx.x >> 2;
  int l = ((blockIdx.x & 3) << 8) + tid;
  float tb = t[b];
  float scale = rsqrtf(1e-4f + tb*(2e-2f - 1e-4f));
  float acc[14];
#pragma unroll
  for (int c=0;c<14;c++) acc[c]=0.f;
  const float* zp = z + (size_t)b*TSZ*LLEN + l;
  for (int tt2=0; tt2<256; tt2++){
    float xv = zp[(size_t)tt2*LLEN];
#pragma unroll
    for (int c=0;c<14;c++) acc[c] = fmaf(ws[c*256+tt2], xv, acc[c]);
  }
  float* op = outp + (size_t)(b*LLEN + l)*CINN;
#pragma unroll
  for (int c=0;c<14;c++) op[c] = (acc[c]+bs[c])*scale;
}

// ---------------- host launcher ----------------
extern "C" void kernel_launch(void* const* d_in, const int* in_sizes, int n_in,
                              void* d_out, int out_size, void* d_ws, size_t ws_size,
                              hipStream_t stream) {
  (void)in_sizes; (void)n_in; (void)out_size;
  if (ws_size < (size_t)WS_FLOATS * 4) return;

  const float* x      = (const float*)d_in[0];
  const float* t      = (const float*)d_in[1];
  const float* gfpW   = (const float*)d_in[2];
  const float* ew1    = (const float*)d_in[3];
  const float* eb1    = (const float*)d_in[4];
  const float* ew2    = (const float*)d_in[5];
  const float* eb2    = (const float*)d_in[6];
  const float* in_w   = (const float*)d_in[7];
  const float* in_b   = (const float*)d_in[8];
  const float* out1_w = (const float*)d_in[9];
  const float* out1_b = (const float*)d_in[10];
  const float* out2_w = (const float*)d_in[11];
  const float* out2_b = (const float*)d_in[12];
  const float* dp_w   = (const float*)d_in[13];
  const float* dp_b   = (const float*)d_in[14];
  const float* ip_w   = (const float*)d_in[15];
  const float* ip_b   = (const float*)d_in[16];
  const float* op_w   = (const float*)d_in[17];
  const float* op_b   = (const float*)d_in[18];
  const float* log_dt = (const float*)d_in[19];
  const float* logA   = (const float*)d_in[20];
  const float* Aim    = (const float*)d_in[21];
  const float* Cre    = (const float*)d_in[22];
  const float* Cim    = (const float*)d_in[23];
  const float* s4D    = (const float*)d_in[24];
  const float* ln_g   = (const float*)d_in[25];
  const float* ln_b   = (const float*)d_in[26];
  float* out = (float*)d_out;
  float* ws = (float*)d_ws;

  float2* lam2  = (float2*)(ws + OFF_LAM);
  float2* C2v   = (float2*)(ws + OFF_C);
  float2* lamP  = (float2*)(ws + OFF_LAMP);
  float* embb  = ws + OFF_EMB;
  f16*   dpe16 = (f16*)(ws + OFF_DPE16);
  float* hbuf  = ws + OFF_H;
  float* skipb = ws + OFF_SKIP;
  float* y1    = ws + OFF_Y1;
  f16*   hT16  = (f16*)(ws + OFF_HT);
  f16*   gT16  = (f16*)(ws + OFF_GT);
  f16*   sT16  = (f16*)(ws + OFF_ST);
  float* meanb = ws + OFF_MEAN;
  float* rstdb = ws + OFF_RSTD;
  f16*   mats  = (f16*)(ws + OFF_MATS);

  consts_kernel<<<768,256,0,stream>>>(log_dt, logA, Aim, Cre, Cim, lam2, C2v, lamP);
  emb_kernel<<<BB,128,0,stream>>>(t, gfpW, ew1, eb1, ew2, eb2, embb);
  dpe_kernel<<<NDEPTH*BB,256,0,stream>>>(embb, dp_w, dp_b, dpe16);
  inproj_kernel<<<64,256,0,stream>>>(x, in_w, in_b, hbuf);
  h2t_kernel<<<dim3(16,4,16),256,0,stream>>>(hbuf, hT16);

  for (int d=0; d<NDEPTH; d++){
    int q0 = d*2, q1 = d*2+1;
    // ip: hT16 (+dpe) -> y1 fp32
    gemm_k<0><<<dim3(8,4,16),256,0,stream>>>(ip_w + (size_t)d*HSZ*TSZ, ip_b + d*HSZ,
                                             hT16, dpe16 + (size_t)d*BB*TSZ,
                                             y1, nullptr, nullptr, nullptr, 0);
    // build T/V/E for both layers of this depth
    build_mats<<<1024,256,0,stream>>>(lam2 + (size_t)q0*QHN, C2v + (size_t)q0*QHN,
                                      s4D + (size_t)q0*HSZ, mats);
    // S4 q0
    s4_mfma<0><<<1024,256,0,stream>>>(mats, lamP + (size_t)q0*QHN, y1, y1,
                                      nullptr, nullptr, nullptr, nullptr);
    // mid-LN stats (applied inside next s4's staging)
    ln_stats<<<256,256,0,stream>>>(y1, meanb, rstdb);
    // S4 q1 with fused LN(q0)
    s4_mfma<1><<<1024,256,0,stream>>>(mats + (size_t)512*12288, lamP + (size_t)q1*QHN, y1, y1,
                                      meanb, rstdb, ln_g + q0*HSZ, ln_b + q0*HSZ);
    // LN(q1) + gate -> gT16
    ln_gate_kernel<<<256,256,0,stream>>>(y1, gT16, ln_g + q1*HSZ, ln_b + q1*HSZ);
    // op: gT16 -> res(hbuf,hT16) / skip(skipb)
    gemm_k<1><<<dim3(8,4,16),256,0,stream>>>(op_w + (size_t)d*HSZ*TSZ, op_b + d*HSZ,
                                             gT16, nullptr, nullptr, hbuf, hT16, skipb, (d==0)?1:0);
  }
  h2t_kernel<<<dim3(16,4,16),256,0,stream>>>(skipb, sT16);
  gemm_k<2><<<dim3(8,2,16),256,0,stream>>>(out1_w, out1_b, sT16, nullptr,
                                           y1, nullptr, nullptr, nullptr, 0);
  out2_kernel<<<64,256,0,stream>>>(out2_w, out2_b, t, y1, out);
}

// Round 9
// 821.330 us; speedup vs baseline: 3.1304x; 1.1038x over previous
//
#include <hip/hip_runtime.h>

// ---------------- problem constants ----------------
#define BB     16
#define LLEN   1024
#define CINN   14
#define TSZ    256
#define HSZ    512
#define NST    32
#define ESZ    128
#define NDEPTH 6
#define QHN    (HSZ*NST)

#define RS2 0.70710678118654752f   // 1/sqrt(2)
#define IS6 0.40824829046386302f   // 1/sqrt(6)

typedef unsigned short u16;
typedef unsigned int   u32;
typedef _Float16 f16;
typedef __attribute__((ext_vector_type(2)))  _Float16 f16x2;
typedef __attribute__((ext_vector_type(4)))  _Float16 f16x4;
typedef __attribute__((ext_vector_type(8)))  _Float16 f16x8;
typedef __attribute__((ext_vector_type(16))) float    f32x16;

// workspace layout (float offsets)
#define OFF_LAM   0u          // float2 lambda      x 12*16384
#define OFF_C     393216u     // float2 C'          x 12*16384
#define OFF_LAMP  786432u     // float2 lambda^64   x 12*16384
#define OFF_EMB   1179648u
#define OFF_DPE16 1181696u
#define OFF_H     1193984u    // fp32 [16][256][1024]
#define OFF_SKIP  5388288u    // fp32 [16][256][1024]
#define OFF_Z     9582592u    // fp32 [16][256][1024] (out1 output)
#define OFF_Y16   13776896u   // f16  [16][512][1024]
#define OFF_HT    17971200u   // f16  [16][1024][256]
#define OFF_GT    20068352u
#define OFF_ST    22165504u
#define OFF_MEAN  24262656u
#define OFF_RSTD  24279040u
#define OFF_MATS  24295424u   // f16 [2][512][3][4096] = 6291456 floats
#define WS_FLOATS 30586880u

// ---------------- S4D constants: lambda, C' = 2C(lambda-1)/A, lambda^64 ----------------
__global__ void consts_kernel(const float* __restrict__ log_dt, const float* __restrict__ logA,
                              const float* __restrict__ Aim,   const float* __restrict__ Cre,
                              const float* __restrict__ Cim,
                              float2* __restrict__ lam2, float2* __restrict__ C2,
                              float2* __restrict__ lamP){
  int gid = blockIdx.x*256 + threadIdx.x;            // q*16384 + h*32 + n
  int h = (gid>>5) & 511;
  int q = gid >> 14;
  float dt  = expf(log_dt[q*HSZ + h]);
  float are = -expf(logA[gid]);
  float aim = Aim[gid];
  float dre = are*dt, dim = aim*dt;
  float e   = expf(dre);
  float lre = e*cosf(dim), lim = e*sinf(dim);
  float nre = lre - 1.f, nim = lim;
  float invden = 1.f/(are*are + aim*aim);
  float tre = (nre*are + nim*aim)*invden;
  float tim = (nim*are - nre*aim)*invden;
  float cr = Cre[gid], ci = Cim[gid];
  float Cr = 2.f*(cr*tre - ci*tim);
  float Ci = 2.f*(cr*tim + ci*tre);
  lam2[gid] = make_float2(lre, lim);
  C2[gid]   = make_float2(Cr, Ci);
  float pr = lre, pi = lim;
#pragma unroll
  for (int i=0;i<6;i++){ float nr2 = pr*pr - pi*pi; pi = 2.f*pr*pi; pr = nr2; }
  lamP[gid] = make_float2(pr, pi);
}

// ---------------- build per-(q,h) f16 matrices T,V,E in MFMA A-frag order ----------------
__global__ __launch_bounds__(256) void build_mats(const float2* __restrict__ lam2d,
                                                  const float2* __restrict__ C2d,
                                                  const float* __restrict__ Dd,
                                                  f16* __restrict__ mats){
  __shared__ float Pre[65][33];
  __shared__ float Pim[65][33];
  __shared__ float Kk[64];
  int bid = blockIdx.x;
  int sub = bid >> 9;            // 0/1 (layer within depth)
  int h   = bid & 511;
  const float2* lp = lam2d + sub*QHN + h*NST;
  const float2* cp = C2d  + sub*QHN + h*NST;
  int tid = threadIdx.x;
  int n  = tid & 31;
  int pg = tid >> 5;             // 0..7
  {
    float2 l = lp[n];
    float ar=l.x, ai=l.y;
#pragma unroll
    for (int i=0;i<3;i++){ float t2 = ar*ar - ai*ai; ai = 2.f*ar*ai; ar = t2; }
    float br=1.f, bi=0.f;
    for (int i=0;i<pg;i++){ float t2 = br*ar - bi*ai; bi = br*ai + bi*ar; br = t2; }
    float pr=br, pi=bi;
#pragma unroll
    for (int i=0;i<8;i++){
      Pre[8*pg+i][n] = pr; Pim[8*pg+i][n] = pi;
      float t2 = pr*l.x - pi*l.y; pi = pr*l.y + pi*l.x; pr = t2;
    }
    if (pg == 7){ Pre[64][n] = pr; Pim[64][n] = pi; }
  }
  __syncthreads();
  if (tid < 64){
    float s = 0.f;
    for (int n2=0;n2<32;n2++){
      float2 c_ = cp[n2];
      s += c_.x*Pre[tid][n2] - c_.y*Pim[tid][n2];
    }
    Kk[tid] = s;
  }
  __syncthreads();
  float Kdiag = Kk[0] + Dd[sub*HSZ + h];
  f16* base = mats + (size_t)(sub*512 + h)*12288;
#pragma unroll
  for (int jj=0; jj<6; jj++){
    int job = jj*256 + tid;       // 0..1535
    int mat = job >> 9;           // 0:T 1:V 2:E
    int rem = job & 511;
    int m = rem >> 3;
    int g = rem & 7;
    f16x8 vals;
    if (mat == 0){
#pragma unroll
      for (int j8=0;j8<8;j8++){
        int k = g*8 + j8;
        float v = (m > k) ? Kk[m-k] : ((m == k) ? Kdiag : 0.f);
        vals[j8] = (f16)v;
      }
    } else if (mat == 1){
      int n2 = m >> 1; int im = m & 1;
#pragma unroll
      for (int j8=0;j8<8;j8++){
        int k = g*8 + j8; int p = 63 - k;
        vals[j8] = (f16)(im ? Pim[p][n2] : Pre[p][n2]);
      }
    } else {
#pragma unroll
      for (int j8=0;j8<8;j8++){
        int k = g*8 + j8; int n2 = k >> 1;
        float2 c_ = cp[n2];
        float pr = Pre[m+1][n2], pi = Pim[m+1][n2];
        float re  = c_.x*pr - c_.y*pi;
        float imv = c_.x*pi + c_.y*pr;
        vals[j8] = (f16)((k & 1) ? -imv : re);
      }
    }
    *(f16x8*)(base + mat*4096 + (g*64 + m)*8) = vals;
  }
}

// ---------------- diffusion embedding MLP ----------------
__global__ void emb_kernel(const float* __restrict__ t, const float* __restrict__ gw,
                           const float* __restrict__ w1, const float* __restrict__ b1,
                           const float* __restrict__ w2, const float* __restrict__ b2,
                           float* __restrict__ emb){
  __shared__ float e0[128], e1[128];
  int b = blockIdx.x, tid = threadIdx.x;
  float tb = t[b];
  if (tid < 64){
    float xp = tb * gw[tid] * 6.283185307179586f;
    e0[tid]    = sinf(xp);
    e0[tid+64] = cosf(xp);
  }
  __syncthreads();
  float a = b1[tid];
  for (int i=0;i<128;i++) a = fmaf(e0[i], w1[tid*128+i], a);
  a = a / (1.f + __expf(-a));
  e1[tid] = a;
  __syncthreads();
  float a2 = b2[tid];
  for (int i=0;i<128;i++) a2 = fmaf(e1[i], w2[tid*128+i], a2);
  a2 = a2 / (1.f + __expf(-a2));
  emb[b*ESZ + tid] = a2;
}

// ---------------- per-depth diffusion projection -> f16 ----------------
__global__ void dpe_kernel(const float* __restrict__ emb, const float* __restrict__ dw,
                           const float* __restrict__ db, f16* __restrict__ dpe16){
  int blk = blockIdx.x; int d = blk >> 4; int b = blk & 15; int o = threadIdx.x;
  const float* wp = dw + (size_t)(d*TSZ + o)*ESZ;
  const float* ep = emb + b*ESZ;
  float a = db[d*TSZ + o];
  for (int e=0;e<128;e++) a = fmaf(ep[e], wp[e], a);
  dpe16[(size_t)(d*BB + b)*TSZ + o] = (f16)a;
}

// ---------------- input projection [B,L,14] -> h [B,256,L] fp32 ----------------
__global__ __launch_bounds__(256) void inproj_kernel(const float* __restrict__ x, const float* __restrict__ w,
                                                     const float* __restrict__ bias, float* __restrict__ hb){
  __shared__ float ws[256*14];
  __shared__ float bs[256];
  int tid = threadIdx.x;
#pragma unroll
  for (int c=0;c<14;c++) ws[tid*14+c] = w[tid*14+c];
  bs[tid] = bias[tid];
  __syncthreads();
  int b = blockIdx.x >> 2;
  int l = ((blockIdx.x & 3) << 8) + tid;
  float xv[14];
  const float* xp = x + (size_t)(b*LLEN + l)*CINN;
#pragma unroll
  for (int c=0;c<14;c++) xv[c] = xp[c];
  for (int o=0;o<256;o++){
    float a = bs[o];
#pragma unroll
    for (int c=0;c<14;c++) a = fmaf(ws[o*14+c], xv[c], a);
    hb[(size_t)(b*TSZ + o)*LLEN + l] = a;
  }
}

// ---------------- transpose fp32 [b][256][1024] -> f16 [b][1024][256] ----------------
__global__ __launch_bounds__(256) void h2t_kernel(const float* __restrict__ src, f16* __restrict__ dst){
  __shared__ f16 TT[64*72];
  int tid = threadIdx.x;
  int b = blockIdx.z;
  int l0 = blockIdx.x * 64;
  int t0 = blockIdx.y * 64;
#pragma unroll
  for (int i=0;i<4;i++){
    int job = i*256 + tid;
    int tt = job >> 4, l4 = (job & 15)*4;
    float4 v = *(const float4*)(src + ((size_t)b*TSZ + t0+tt)*LLEN + l0 + l4);
    TT[(l4+0)*72 + tt] = (f16)v.x;
    TT[(l4+1)*72 + tt] = (f16)v.y;
    TT[(l4+2)*72 + tt] = (f16)v.z;
    TT[(l4+3)*72 + tt] = (f16)v.w;
  }
  __syncthreads();
#pragma unroll
  for (int i=0;i<2;i++){
    int job = i*256 + tid;
    int l = job >> 3, g = job & 7;
    f16x8 hv = *(const f16x8*)(TT + l*72 + g*8);
    *(f16x8*)(dst + ((size_t)b*LLEN + l0 + l)*TSZ + t0 + g*8) = hv;
  }
}

// ---------------- MFMA GEMM ----------------
// MODE 0: ip  (B = hT16 + dpe16, Y16o f16 [512][1024])
// MODE 1: op  (B = gT16; y<2: res->hbuf RMW + hT16; y>=2: skip->skipb RMW)
// MODE 2: out1 (B = sT16 * IS6, relu, Yf fp32 [256][1024])
template<int MODE>
__global__ __launch_bounds__(256) void gemm_k(const float* __restrict__ W, const float* __restrict__ bias,
                                              const f16* __restrict__ XT, const f16* __restrict__ dpeD,
                                              float* __restrict__ Yf, f16* __restrict__ Y16o,
                                              float* __restrict__ hbuf, f16* __restrict__ hT16,
                                              float* __restrict__ skipb, int first){
  __shared__ f16 sm[17408];
  f16* As = sm;
  f16* Bs = sm + 8192;
  int tid = threadIdx.x;
  int lane = tid & 63;
  int wv = tid >> 6;
  int n_blk = blockIdx.x * 128;
  int m_blk = blockIdx.y * 128;
  int bz = blockIdx.z;
  const f16* Xb = XT + (size_t)bz * (LLEN*TSZ);
  int wm = (wv & 1) * 64;
  int wn = (wv >> 1) * 64;

  f32x16 acc[2][2];
#pragma unroll
  for (int mi=0;mi<2;mi++)
#pragma unroll
    for (int ni=0;ni<2;ni++)
#pragma unroll
      for (int r=0;r<16;r++) acc[mi][ni][r] = 0.f;

  for (int kt=0; kt<4; kt++){
    int k0 = kt*64;
#pragma unroll
    for (int i=0;i<4;i++){
      int job = i*256 + tid;
      int m = job >> 3, gk = job & 7;
      const float* wp = W + (size_t)(m_blk + m)*TSZ + k0 + gk*8;
      float4 u0 = *(const float4*)wp;
      float4 u1 = *(const float4*)(wp+4);
      f16x8 hv;
      hv[0]=(f16)u0.x; hv[1]=(f16)u0.y; hv[2]=(f16)u0.z; hv[3]=(f16)u0.w;
      hv[4]=(f16)u1.x; hv[5]=(f16)u1.y; hv[6]=(f16)u1.z; hv[7]=(f16)u1.w;
      int P = m*8 + (gk ^ (m & 7));
      *(f16x8*)(As + P*8) = hv;
    }
#pragma unroll
    for (int i=0;i<4;i++){
      int job = i*256 + tid;
      int n = job >> 3, gk = job & 7;
      f16x8 hv = *(const f16x8*)(Xb + (size_t)(n_blk + n)*TSZ + k0 + gk*8);
      if (MODE==0){
        f16x8 dv = *(const f16x8*)(dpeD + bz*TSZ + k0 + gk*8);
#pragma unroll
        for (int e=0;e<8;e++) hv[e] = hv[e] + dv[e];
      }
      if (MODE==2){
#pragma unroll
        for (int e=0;e<8;e++) hv[e] = hv[e] * (f16)IS6;
      }
      int P = n*8 + (gk ^ (n & 7));
      *(f16x8*)(Bs + P*8) = hv;
    }
    __syncthreads();
#pragma unroll
    for (int ks=0; ks<4; ks++){
      int q = lane >> 5;
      int gk = ks*2 + q;
      f16x8 af[2], bf[2];
#pragma unroll
      for (int mi=0; mi<2; mi++){
        int m = wm + mi*32 + (lane & 31);
        af[mi] = *(const f16x8*)(As + (m*8 + (gk ^ (m&7)))*8);
      }
#pragma unroll
      for (int ni=0; ni<2; ni++){
        int n = wn + ni*32 + (lane & 31);
        bf[ni] = *(const f16x8*)(Bs + (n*8 + (gk ^ (n&7)))*8);
      }
#pragma unroll
      for (int mi=0; mi<2; mi++)
#pragma unroll
        for (int ni=0; ni<2; ni++)
          acc[mi][ni] = __builtin_amdgcn_mfma_f32_32x32x16_f16(af[mi], bf[ni], acc[mi][ni], 0, 0, 0);
    }
    __syncthreads();
  }

  int q = lane >> 5;
  if (MODE == 0){
#pragma unroll
    for (int mi=0;mi<2;mi++)
#pragma unroll
      for (int ni=0;ni<2;ni++){
        int col = n_blk + wn + ni*32 + (lane & 31);
#pragma unroll
        for (int r=0;r<16;r++){
          int row = m_blk + wm + mi*32 + (r&3) + 8*(r>>2) + 4*q;
          float v = acc[mi][ni][r] + bias[row];
          Y16o[((size_t)bz*HSZ + row)*LLEN + col] = (f16)v;
        }
      }
  } else if (MODE == 2){
#pragma unroll
    for (int mi=0;mi<2;mi++)
#pragma unroll
      for (int ni=0;ni<2;ni++){
        int col = n_blk + wn + ni*32 + (lane & 31);
#pragma unroll
        for (int r=0;r<16;r++){
          int row = m_blk + wm + mi*32 + (r&3) + 8*(r>>2) + 4*q;
          float v = fmaxf(acc[mi][ni][r] + bias[row], 0.f);
          Yf[((size_t)bz*TSZ + row)*LLEN + col] = v;
        }
      }
  } else {
    if (blockIdx.y < 2){
#pragma unroll
      for (int mi=0;mi<2;mi++)
#pragma unroll
        for (int ni=0;ni<2;ni++){
          int col_l = wn + ni*32 + (lane & 31);
#pragma unroll
          for (int r=0;r<16;r++){
            int row_l = wm + mi*32 + (r&3) + 8*(r>>2) + 4*q;
            int row = m_blk + row_l;
            float v = acc[mi][ni][r] + bias[row];
            float* hp = hbuf + ((size_t)bz*TSZ + row)*LLEN + n_blk + col_l;
            float hn = (*hp + v)*RS2;
            *hp = hn;
            sm[col_l*136 + row_l] = (f16)hn;
          }
        }
      __syncthreads();
#pragma unroll
      for (int i=0;i<8;i++){
        int job = i*256 + tid;
        int n = job >> 4, m8 = job & 15;
        f16x8 hv = *(const f16x8*)(sm + n*136 + m8*8);
        *(f16x8*)(hT16 + ((size_t)bz*LLEN + n_blk + n)*TSZ + m_blk + m8*8) = hv;
      }
    } else {
#pragma unroll
      for (int mi=0;mi<2;mi++)
#pragma unroll
        for (int ni=0;ni<2;ni++){
          int col = n_blk + wn + ni*32 + (lane & 31);
#pragma unroll
          for (int r=0;r<16;r++){
            int row = m_blk + wm + mi*32 + (r&3) + 8*(r>>2) + 4*q;
            float v = acc[mi][ni][r] + bias[row];
            float* sp = skipb + ((size_t)bz*TSZ + (row - TSZ))*LLEN + col;
            if (first) *sp = v; else *sp = *sp + v;
          }
        }
    }
  }
}

// ---------------- S4D via MFMA conv (f16 activations): Z=V*U; prefix; Y=T*U+E*S ----
template<int LN>
__global__ __launch_bounds__(256) void s4_mfma(const f16* __restrict__ matsq,
                                               const float2* __restrict__ lamPq,
                                               const f16* u, f16* y,
                                               const float* __restrict__ meanp,
                                               const float* __restrict__ rstdp,
                                               const float* __restrict__ gp,
                                               const float* __restrict__ btp){
  __shared__ f16 Ubuf[128*72];
  __shared__ f16 ZSbuf[128*72];     // Z -> Sprev -> Y (all f16)

  int tid  = threadIdx.x;
  int w    = tid >> 6;
  int lane = tid & 63;
  int q    = lane >> 5;
  int colL = lane & 31;
  int h     = blockIdx.x & 511;
  int bhalf = blockIdx.x >> 9;
  int b0    = bhalf*8;

  float gv = 0.f, bv = 0.f;
  if (LN){ gv = gp[h]; bv = btp[h]; }

  const f16* matT = matsq + (size_t)h*12288;
  const f16* matV = matT + 4096;
  const f16* matE = matT + 8192;

  // ---- stage u (wave w covers batches b0+2w, b0+2w+1), optional fused LN
#pragma unroll
  for (int i=0;i<4;i++){
    int fidx = i*64 + lane;               // 0..255
    int row = fidx >> 7;                  // 0/1
    int l   = (fidx & 127)*8;
    int b   = b0 + 2*w + row;
    f16x8 hv = *(const f16x8*)(u + ((size_t)b*HSZ + h)*LLEN + l);
    if (LN){
      float4 m0 = *(const float4*)(meanp + b*LLEN + l);
      float4 m1 = *(const float4*)(meanp + b*LLEN + l + 4);
      float4 r0 = *(const float4*)(rstdp + b*LLEN + l);
      float4 r1 = *(const float4*)(rstdp + b*LLEN + l + 4);
      float mm[8] = {m0.x,m0.y,m0.z,m0.w,m1.x,m1.y,m1.z,m1.w};
      float rr[8] = {r0.x,r0.y,r0.z,r0.w,r1.x,r1.y,r1.z,r1.w};
#pragma unroll
      for (int e=0;e<8;e++)
        hv[e] = (f16)(((float)hv[e] - mm[e])*rr[e]*gv + bv);
    }
    int col = (2*w + row)*16 + (l >> 6);
    *(f16x8*)(Ubuf + col*72 + (l & 63)) = hv;
  }
  __syncthreads();

  int strip = w*32;

  // ---- GEMM1: Z = V @ U
  {
    f32x16 zacc[2];
#pragma unroll
    for (int mt=0;mt<2;mt++)
#pragma unroll
      for (int r=0;r<16;r++) zacc[mt][r] = 0.f;
#pragma unroll
    for (int kt=0; kt<4; kt++){
      int kg = kt*2 + q;
      f16x8 bfrag = *(const f16x8*)(Ubuf + (strip+colL)*72 + kg*8);
#pragma unroll
      for (int mt=0; mt<2; mt++){
        f16x8 afrag = *(const f16x8*)(matV + ((size_t)(kg*64 + mt*32 + colL))*8);
        zacc[mt] = __builtin_amdgcn_mfma_f32_32x32x16_f16(afrag, bfrag, zacc[mt], 0, 0, 0);
      }
    }
#pragma unroll
    for (int mt=0;mt<2;mt++)
#pragma unroll
      for (int rg=0;rg<4;rg++){
        int st0 = mt*32 + rg*8 + q*4;
        f16x4 zp;
        zp[0]=(f16)zacc[mt][rg*4+0]; zp[1]=(f16)zacc[mt][rg*4+1];
        zp[2]=(f16)zacc[mt][rg*4+2]; zp[3]=(f16)zacc[mt][rg*4+3];
        *(f16x4*)(ZSbuf + (strip+colL)*72 + st0) = zp;
      }
  }
  __syncthreads();

  // ---- prefix over 16 chunks (in-place Z -> Sprev), per (batch-row, n) chain
  {
    int n  = lane & 31;
    int colb = (2*w + (lane>>5))*16;
    float2 l64 = lamPq[h*NST + n];
    float Sre = 0.f, Sim = 0.f;
#pragma unroll
    for (int c=0;c<16;c++){
      f16* p = ZSbuf + (colb + c)*72 + 2*n;
      f16x2 z2 = *(f16x2*)p;
      f16x2 sp_; sp_[0] = (f16)Sre; sp_[1] = (f16)Sim;
      *(f16x2*)p = sp_;
      float nr = fmaf(l64.x, Sre, fmaf(-l64.y, Sim, (float)z2[0]));
      float ni = fmaf(l64.x, Sim, fmaf( l64.y, Sre, (float)z2[1]));
      Sre = nr; Sim = ni;
    }
  }
  __syncthreads();

  // ---- GEMM2: Y = T @ U + E @ Sprev
  f32x16 yacc[2];
#pragma unroll
  for (int mt=0;mt<2;mt++)
#pragma unroll
    for (int r=0;r<16;r++) yacc[mt][r] = 0.f;
#pragma unroll
  for (int kt=0; kt<4; kt++){
    int kg = kt*2 + q;
    f16x8 bu = *(const f16x8*)(Ubuf  + (strip+colL)*72 + kg*8);
    f16x8 bs = *(const f16x8*)(ZSbuf + (strip+colL)*72 + kg*8);
#pragma unroll
    for (int mt=0; mt<2; mt++){
      f16x8 aT = *(const f16x8*)(matT + ((size_t)(kg*64 + mt*32 + colL))*8);
      yacc[mt] = __builtin_amdgcn_mfma_f32_32x32x16_f16(aT, bu, yacc[mt], 0, 0, 0);
    }
#pragma unroll
    for (int mt=0; mt<2; mt++){
      f16x8 aE = *(const f16x8*)(matE + ((size_t)(kg*64 + mt*32 + colL))*8);
      yacc[mt] = __builtin_amdgcn_mfma_f32_32x32x16_f16(aE, bs, yacc[mt], 0, 0, 0);
    }
  }
  __syncthreads();

  // ---- store Y (f16) into ZSbuf region, then coalesced f16x8 global write
#pragma unroll
  for (int mt=0;mt<2;mt++)
#pragma unroll
    for (int rg=0;rg<4;rg++){
      int j0 = mt*32 + rg*8 + q*4;
      f16x4 yv;
      yv[0]=(f16)yacc[mt][rg*4+0]; yv[1]=(f16)yacc[mt][rg*4+1];
      yv[2]=(f16)yacc[mt][rg*4+2]; yv[3]=(f16)yacc[mt][rg*4+3];
      *(f16x4*)(ZSbuf + (strip+colL)*72 + j0) = yv;
    }
  __syncthreads();
#pragma unroll
  for (int i=0;i<4;i++){
    int fidx = i*64 + lane;
    int row = fidx >> 7;
    int l   = (fidx & 127)*8;
    int b   = b0 + 2*w + row;
    int col = (2*w + row)*16 + (l >> 6);
    f16x8 hv = *(const f16x8*)(ZSbuf + col*72 + (l & 63));
    *(f16x8*)(y + ((size_t)b*HSZ + h)*LLEN + l) = hv;
  }
}

// ---------------- LN stats: mean/rstd per (b,l) over 512 channels (f16 input) ------
__global__ __launch_bounds__(256) void ln_stats(const f16* __restrict__ in,
                                                float* __restrict__ mean, float* __restrict__ rstd){
  __shared__ float rs[4][64];
  __shared__ float rq[4][64];
  int tid = threadIdx.x;
  int hg = tid >> 6;
  int lo = tid & 63;
  int b = blockIdx.x >> 4;
  int l = ((blockIdx.x & 15) << 6) + lo;
  size_t base = (size_t)(b*HSZ)*LLEN + l;
  float s=0.f, ss=0.f;
  for (int hh=0; hh<128; hh++){
    float v = (float)in[base + (size_t)(hg*128+hh)*LLEN];
    s += v; ss = fmaf(v,v,ss);
  }
  rs[hg][lo]=s; rq[hg][lo]=ss;
  __syncthreads();
  if (tid < 64){
    float S = rs[0][tid]+rs[1][tid]+rs[2][tid]+rs[3][tid];
    float Q = rq[0][tid]+rq[1][tid]+rq[2][tid]+rq[3][tid];
    float mn = S * (1.f/HSZ);
    float var  = Q * (1.f/HSZ) - mn*mn;
    int lw = ((blockIdx.x & 15) << 6) + tid;
    mean[b*LLEN + lw] = mn;
    rstd[b*LLEN + lw] = rsqrtf(var + 1e-5f);
  }
}

// ---------------- LN + gate fused (f16 input), output transposed f16 [b][l][t] -----
__global__ __launch_bounds__(256) void ln_gate_kernel(const f16* __restrict__ in, f16* __restrict__ gT,
                                                      const float* __restrict__ g, const float* __restrict__ bt){
  __shared__ float rs[4][64];
  __shared__ float rq[4][64];
  __shared__ float mbuf[64], rbuf[64];
  __shared__ f16 gbuf[64*272];
  int tid = threadIdx.x;
  int hg = tid >> 6;
  int lo = tid & 63;
  int b = blockIdx.x >> 4;
  int l0 = (blockIdx.x & 15) << 6;
  int l = l0 + lo;
  size_t base = (size_t)(b*HSZ)*LLEN + l;
  float s=0.f, ss=0.f;
  for (int hh=0; hh<128; hh++){
    float v = (float)in[base + (size_t)(hg*128+hh)*LLEN];
    s += v; ss = fmaf(v,v,ss);
  }
  rs[hg][lo]=s; rq[hg][lo]=ss;
  __syncthreads();
  if (tid < 64){
    float S = rs[0][tid]+rs[1][tid]+rs[2][tid]+rs[3][tid];
    float Q = rq[0][tid]+rq[1][tid]+rq[2][tid]+rq[3][tid];
    float mean = S * (1.f/HSZ);
    float var  = Q * (1.f/HSZ) - mean*mean;
    mbuf[tid]=mean;
    rbuf[tid]=rsqrtf(var + 1e-5f);
  }
  __syncthreads();
  float mean = mbuf[lo], rstd = rbuf[lo];
  for (int tt=0; tt<64; tt++){
    int t = hg*64 + tt;
    float a = ((float)in[base + (size_t)t*LLEN]       - mean)*rstd*g[t]     + bt[t];
    float f = ((float)in[base + (size_t)(t+256)*LLEN] - mean)*rstd*g[t+256] + bt[t+256];
    float sg = 1.f/(1.f+__expf(-a));
    float th = 1.f - 2.f/(__expf(2.f*f)+1.f);
    gbuf[lo*272 + t] = (f16)(sg*th);
  }
  __syncthreads();
#pragma unroll
  for (int i=0;i<8;i++){
    int job = i*256 + tid;
    int ll = job >> 5, g8 = (job & 31)*8;
    f16x8 hv = *(const f16x8*)(gbuf + ll*272 + g8);
    *(f16x8*)(gT + ((size_t)b*LLEN + l0 + ll)*TSZ + g8) = hv;
  }
}

// ---------------- out2 projection + 1/sqrt(beta) + transpose to [B,L,14] --------
__global__ __launch_bounds__(256) void out2_kernel(const float* __restrict__ w2, const float* __restrict__ b2,
                                                   const float* __restrict__ t, const float* __restrict__ z,
                                                   float* __restrict__ outp){
  __shared__ float ws[14*256];
  __shared__ float bs[14];
  int tid = threadIdx.x;
#pragma unroll
  for (int c=0;c<14;c++) ws[c*256+tid] = w2[c*256+tid];
  if (tid < 14) bs[tid] = b2[tid];
  __syncthreads();
  int b = blockIdx.x >> 2;
  int l = ((blockIdx.x & 3) << 8) + tid;
  float tb = t[b];
  float scale = rsqrtf(1e-4f + tb*(2e-2f - 1e-4f));
  float acc[14];
#pragma unroll
  for (int c=0;c<14;c++) acc[c]=0.f;
  const float* zp = z + (size_t)b*TSZ*LLEN + l;
  for (int tt2=0; tt2<256; tt2++){
    float xv = zp[(size_t)tt2*LLEN];
#pragma unroll
    for (int c=0;c<14;c++) acc[c] = fmaf(ws[c*256+tt2], xv, acc[c]);
  }
  float* op = outp + (size_t)(b*LLEN + l)*CINN;
#pragma unroll
  for (int c=0;c<14;c++) op[c] = (acc[c]+bs[c])*scale;
}

// ---------------- host launcher ----------------
extern "C" void kernel_launch(void* const* d_in, const int* in_sizes, int n_in,
                              void* d_out, int out_size, void* d_ws, size_t ws_size,
                              hipStream_t stream) {
  (void)in_sizes; (void)n_in; (void)out_size;
  if (ws_size < (size_t)WS_FLOATS * 4) return;

  const float* x      = (const float*)d_in[0];
  const float* t      = (const float*)d_in[1];
  const float* gfpW   = (const float*)d_in[2];
  const float* ew1    = (const float*)d_in[3];
  const float* eb1    = (const float*)d_in[4];
  const float* ew2    = (const float*)d_in[5];
  const float* eb2    = (const float*)d_in[6];
  const float* in_w   = (const float*)d_in[7];
  const float* in_b   = (const float*)d_in[8];
  const float* out1_w = (const float*)d_in[9];
  const float* out1_b = (const float*)d_in[10];
  const float* out2_w = (const float*)d_in[11];
  const float* out2_b = (const float*)d_in[12];
  const float* dp_w   = (const float*)d_in[13];
  const float* dp_b   = (const float*)d_in[14];
  const float* ip_w   = (const float*)d_in[15];
  const float* ip_b   = (const float*)d_in[16];
  const float* op_w   = (const float*)d_in[17];
  const float* op_b   = (const float*)d_in[18];
  const float* log_dt = (const float*)d_in[19];
  const float* logA   = (const float*)d_in[20];
  const float* Aim    = (const float*)d_in[21];
  const float* Cre    = (const float*)d_in[22];
  const float* Cim    = (const float*)d_in[23];
  const float* s4D    = (const float*)d_in[24];
  const float* ln_g   = (const float*)d_in[25];
  const float* ln_b   = (const float*)d_in[26];
  float* out = (float*)d_out;
  float* ws = (float*)d_ws;

  float2* lam2  = (float2*)(ws + OFF_LAM);
  float2* C2v   = (float2*)(ws + OFF_C);
  float2* lamP  = (float2*)(ws + OFF_LAMP);
  float* embb  = ws + OFF_EMB;
  f16*   dpe16 = (f16*)(ws + OFF_DPE16);
  float* hbuf  = ws + OFF_H;
  float* skipb = ws + OFF_SKIP;
  float* zbuf  = ws + OFF_Z;
  f16*   y16   = (f16*)(ws + OFF_Y16);
  f16*   hT16  = (f16*)(ws + OFF_HT);
  f16*   gT16  = (f16*)(ws + OFF_GT);
  f16*   sT16  = (f16*)(ws + OFF_ST);
  float* meanb = ws + OFF_MEAN;
  float* rstdb = ws + OFF_RSTD;
  f16*   mats  = (f16*)(ws + OFF_MATS);

  consts_kernel<<<768,256,0,stream>>>(log_dt, logA, Aim, Cre, Cim, lam2, C2v, lamP);
  emb_kernel<<<BB,128,0,stream>>>(t, gfpW, ew1, eb1, ew2, eb2, embb);
  dpe_kernel<<<NDEPTH*BB,256,0,stream>>>(embb, dp_w, dp_b, dpe16);
  inproj_kernel<<<64,256,0,stream>>>(x, in_w, in_b, hbuf);
  h2t_kernel<<<dim3(16,4,16),256,0,stream>>>(hbuf, hT16);

  for (int d=0; d<NDEPTH; d++){
    int q0 = d*2, q1 = d*2+1;
    // ip: hT16 (+dpe) -> y16 f16
    gemm_k<0><<<dim3(8,4,16),256,0,stream>>>(ip_w + (size_t)d*HSZ*TSZ, ip_b + d*HSZ,
                                             hT16, dpe16 + (size_t)d*BB*TSZ,
                                             nullptr, y16, nullptr, nullptr, nullptr, 0);
    // build T/V/E for both layers of this depth
    build_mats<<<1024,256,0,stream>>>(lam2 + (size_t)q0*QHN, C2v + (size_t)q0*QHN,
                                      s4D + (size_t)q0*HSZ, mats);
    // S4 q0 (in place on y16)
    s4_mfma<0><<<1024,256,0,stream>>>(mats, lamP + (size_t)q0*QHN, y16, y16,
                                      nullptr, nullptr, nullptr, nullptr);
    // mid-LN stats (applied inside next s4's staging)
    ln_stats<<<256,256,0,stream>>>(y16, meanb, rstdb);
    // S4 q1 with fused LN(q0)
    s4_mfma<1><<<1024,256,0,stream>>>(mats + (size_t)512*12288, lamP + (size_t)q1*QHN, y16, y16,
                                      meanb, rstdb, ln_g + q0*HSZ, ln_b + q0*HSZ);
    // LN(q1) + gate -> gT16
    ln_gate_kernel<<<256,256,0,stream>>>(y16, gT16, ln_g + q1*HSZ, ln_b + q1*HSZ);
    // op: gT16 -> res(hbuf,hT16) / skip(skipb)
    gemm_k<1><<<dim3(8,4,16),256,0,stream>>>(op_w + (size_t)d*HSZ*TSZ, op_b + d*HSZ,
                                             gT16, nullptr, nullptr, nullptr, hbuf, hT16, skipb, (d==0)?1:0);
  }
  h2t_kernel<<<dim3(16,4,16),256,0,stream>>>(skipb, sT16);
  gemm_k<2><<<dim3(8,2,16),256,0,stream>>>(out1_w, out1_b, sT16, nullptr,
                                           zbuf, nullptr, nullptr, nullptr, nullptr, 0);
  out2_kernel<<<64,256,0,stream>>>(out2_w, out2_b, t, zbuf, out);
}

// Round 10
// 778.633 us; speedup vs baseline: 3.3021x; 1.0548x over previous
//
#include <hip/hip_runtime.h>

// ---------------- problem constants ----------------
#define BB     16
#define LLEN   1024
#define CINN   14
#define TSZ    256
#define HSZ    512
#define NST    32
#define ESZ    128
#define NDEPTH 6
#define QHN    (HSZ*NST)

#define RS2 0.70710678118654752f   // 1/sqrt(2)
#define IS6 0.40824829046386302f   // 1/sqrt(6)

typedef unsigned short u16;
typedef unsigned int   u32;
typedef _Float16 f16;
typedef __attribute__((ext_vector_type(2)))  _Float16 f16x2;
typedef __attribute__((ext_vector_type(4)))  _Float16 f16x4;
typedef __attribute__((ext_vector_type(8)))  _Float16 f16x8;
typedef __attribute__((ext_vector_type(16))) float    f32x16;

// workspace layout (float offsets)
#define OFF_LAM   0u          // float2 lambda      x 12*16384
#define OFF_C     393216u     // float2 C'          x 12*16384
#define OFF_LAMP  786432u     // float2 lambda^64   x 12*16384
#define OFF_EMB   1179648u
#define OFF_DPE16 1181696u
#define OFF_H     1193984u    // fp32 [16][256][1024] (initial h only)
#define OFF_Z     5388288u    // fp32 [16][256][1024] (out1 output)
#define OFF_Y16   9582592u    // f16  [16][512][1024]
#define OFF_HT    13776896u   // f16  [16][1024][256]
#define OFF_GT    15874048u
#define OFF_ST    17971200u
#define OFF_MEAN  20068352u
#define OFF_RSTD  20084736u
#define OFF_MATS  20101120u   // f16 [2][512][3][4096] = 6291456 floats
#define WS_FLOATS 26392576u

// ---------------- S4D constants: lambda, C' = 2C(lambda-1)/A, lambda^64 ----------------
__global__ void consts_kernel(const float* __restrict__ log_dt, const float* __restrict__ logA,
                              const float* __restrict__ Aim,   const float* __restrict__ Cre,
                              const float* __restrict__ Cim,
                              float2* __restrict__ lam2, float2* __restrict__ C2,
                              float2* __restrict__ lamP){
  int gid = blockIdx.x*256 + threadIdx.x;            // q*16384 + h*32 + n
  int h = (gid>>5) & 511;
  int q = gid >> 14;
  float dt  = expf(log_dt[q*HSZ + h]);
  float are = -expf(logA[gid]);
  float aim = Aim[gid];
  float dre = are*dt, dim = aim*dt;
  float e   = expf(dre);
  float lre = e*cosf(dim), lim = e*sinf(dim);
  float nre = lre - 1.f, nim = lim;
  float invden = 1.f/(are*are + aim*aim);
  float tre = (nre*are + nim*aim)*invden;
  float tim = (nim*are - nre*aim)*invden;
  float cr = Cre[gid], ci = Cim[gid];
  float Cr = 2.f*(cr*tre - ci*tim);
  float Ci = 2.f*(cr*tim + ci*tre);
  lam2[gid] = make_float2(lre, lim);
  C2[gid]   = make_float2(Cr, Ci);
  float pr = lre, pi = lim;
#pragma unroll
  for (int i=0;i<6;i++){ float nr2 = pr*pr - pi*pi; pi = 2.f*pr*pi; pr = nr2; }
  lamP[gid] = make_float2(pr, pi);
}

// ---------------- build per-(q,h) f16 matrices T,V,E in MFMA A-frag order ----------------
__global__ __launch_bounds__(256) void build_mats(const float2* __restrict__ lam2d,
                                                  const float2* __restrict__ C2d,
                                                  const float* __restrict__ Dd,
                                                  f16* __restrict__ mats){
  __shared__ float Pre[65][33];
  __shared__ float Pim[65][33];
  __shared__ float Kk[64];
  int bid = blockIdx.x;
  int sub = bid >> 9;            // 0/1 (layer within depth)
  int h   = bid & 511;
  const float2* lp = lam2d + sub*QHN + h*NST;
  const float2* cp = C2d  + sub*QHN + h*NST;
  int tid = threadIdx.x;
  int n  = tid & 31;
  int pg = tid >> 5;             // 0..7
  {
    float2 l = lp[n];
    float ar=l.x, ai=l.y;
#pragma unroll
    for (int i=0;i<3;i++){ float t2 = ar*ar - ai*ai; ai = 2.f*ar*ai; ar = t2; }
    float br=1.f, bi=0.f;
    for (int i=0;i<pg;i++){ float t2 = br*ar - bi*ai; bi = br*ai + bi*ar; br = t2; }
    float pr=br, pi=bi;
#pragma unroll
    for (int i=0;i<8;i++){
      Pre[8*pg+i][n] = pr; Pim[8*pg+i][n] = pi;
      float t2 = pr*l.x - pi*l.y; pi = pr*l.y + pi*l.x; pr = t2;
    }
    if (pg == 7){ Pre[64][n] = pr; Pim[64][n] = pi; }
  }
  __syncthreads();
  if (tid < 64){
    float s = 0.f;
    for (int n2=0;n2<32;n2++){
      float2 c_ = cp[n2];
      s += c_.x*Pre[tid][n2] - c_.y*Pim[tid][n2];
    }
    Kk[tid] = s;
  }
  __syncthreads();
  float Kdiag = Kk[0] + Dd[sub*HSZ + h];
  f16* base = mats + (size_t)(sub*512 + h)*12288;
#pragma unroll
  for (int jj=0; jj<6; jj++){
    int job = jj*256 + tid;       // 0..1535
    int mat = job >> 9;           // 0:T 1:V 2:E
    int rem = job & 511;
    int m = rem >> 3;
    int g = rem & 7;
    f16x8 vals;
    if (mat == 0){
#pragma unroll
      for (int j8=0;j8<8;j8++){
        int k = g*8 + j8;
        float v = (m > k) ? Kk[m-k] : ((m == k) ? Kdiag : 0.f);
        vals[j8] = (f16)v;
      }
    } else if (mat == 1){
      int n2 = m >> 1; int im = m & 1;
#pragma unroll
      for (int j8=0;j8<8;j8++){
        int k = g*8 + j8; int p = 63 - k;
        vals[j8] = (f16)(im ? Pim[p][n2] : Pre[p][n2]);
      }
    } else {
#pragma unroll
      for (int j8=0;j8<8;j8++){
        int k = g*8 + j8; int n2 = k >> 1;
        float2 c_ = cp[n2];
        float pr = Pre[m+1][n2], pi = Pim[m+1][n2];
        float re  = c_.x*pr - c_.y*pi;
        float imv = c_.x*pi + c_.y*pr;
        vals[j8] = (f16)((k & 1) ? -imv : re);
      }
    }
    *(f16x8*)(base + mat*4096 + (g*64 + m)*8) = vals;
  }
}

// ---------------- diffusion embedding MLP ----------------
__global__ void emb_kernel(const float* __restrict__ t, const float* __restrict__ gw,
                           const float* __restrict__ w1, const float* __restrict__ b1,
                           const float* __restrict__ w2, const float* __restrict__ b2,
                           float* __restrict__ emb){
  __shared__ float e0[128], e1[128];
  int b = blockIdx.x, tid = threadIdx.x;
  float tb = t[b];
  if (tid < 64){
    float xp = tb * gw[tid] * 6.283185307179586f;
    e0[tid]    = sinf(xp);
    e0[tid+64] = cosf(xp);
  }
  __syncthreads();
  float a = b1[tid];
  for (int i=0;i<128;i++) a = fmaf(e0[i], w1[tid*128+i], a);
  a = a / (1.f + __expf(-a));
  e1[tid] = a;
  __syncthreads();
  float a2 = b2[tid];
  for (int i=0;i<128;i++) a2 = fmaf(e1[i], w2[tid*128+i], a2);
  a2 = a2 / (1.f + __expf(-a2));
  emb[b*ESZ + tid] = a2;
}

// ---------------- per-depth diffusion projection -> f16 ----------------
__global__ void dpe_kernel(const float* __restrict__ emb, const float* __restrict__ dw,
                           const float* __restrict__ db, f16* __restrict__ dpe16){
  int blk = blockIdx.x; int d = blk >> 4; int b = blk & 15; int o = threadIdx.x;
  const float* wp = dw + (size_t)(d*TSZ + o)*ESZ;
  const float* ep = emb + b*ESZ;
  float a = db[d*TSZ + o];
  for (int e=0;e<128;e++) a = fmaf(ep[e], wp[e], a);
  dpe16[(size_t)(d*BB + b)*TSZ + o] = (f16)a;
}

// ---------------- input projection [B,L,14] -> h [B,256,L] fp32 ----------------
__global__ __launch_bounds__(256) void inproj_kernel(const float* __restrict__ x, const float* __restrict__ w,
                                                     const float* __restrict__ bias, float* __restrict__ hb){
  __shared__ float ws[256*14];
  __shared__ float bs[256];
  int tid = threadIdx.x;
#pragma unroll
  for (int c=0;c<14;c++) ws[tid*14+c] = w[tid*14+c];
  bs[tid] = bias[tid];
  __syncthreads();
  int b = blockIdx.x >> 2;
  int l = ((blockIdx.x & 3) << 8) + tid;
  float xv[14];
  const float* xp = x + (size_t)(b*LLEN + l)*CINN;
#pragma unroll
  for (int c=0;c<14;c++) xv[c] = xp[c];
  for (int o=0;o<256;o++){
    float a = bs[o];
#pragma unroll
    for (int c=0;c<14;c++) a = fmaf(ws[o*14+c], xv[c], a);
    hb[(size_t)(b*TSZ + o)*LLEN + l] = a;
  }
}

// ---------------- transpose fp32 [b][256][1024] -> f16 [b][1024][256] ----------------
__global__ __launch_bounds__(256) void h2t_kernel(const float* __restrict__ src, f16* __restrict__ dst){
  __shared__ f16 TT[64*72];
  int tid = threadIdx.x;
  int b = blockIdx.z;
  int l0 = blockIdx.x * 64;
  int t0 = blockIdx.y * 64;
#pragma unroll
  for (int i=0;i<4;i++){
    int job = i*256 + tid;
    int tt = job >> 4, l4 = (job & 15)*4;
    float4 v = *(const float4*)(src + ((size_t)b*TSZ + t0+tt)*LLEN + l0 + l4);
    TT[(l4+0)*72 + tt] = (f16)v.x;
    TT[(l4+1)*72 + tt] = (f16)v.y;
    TT[(l4+2)*72 + tt] = (f16)v.z;
    TT[(l4+3)*72 + tt] = (f16)v.w;
  }
  __syncthreads();
#pragma unroll
  for (int i=0;i<2;i++){
    int job = i*256 + tid;
    int l = job >> 3, g = job & 7;
    f16x8 hv = *(const f16x8*)(TT + l*72 + g*8);
    *(f16x8*)(dst + ((size_t)b*LLEN + l0 + l)*TSZ + t0 + g*8) = hv;
  }
}

// ---------------- MFMA GEMM ----------------
// MODE 0: ip  (B = hT16 + dpe16, Y16o f16 [512][1024])
// MODE 1: op  (B = gT16; y<2: res RMW in hT16; y>=2: skip RMW in sT16)
// MODE 2: out1 (B = sT16 * IS6, relu, Yf fp32 [256][1024])
template<int MODE>
__global__ __launch_bounds__(256) void gemm_k(const float* __restrict__ W, const float* __restrict__ bias,
                                              const f16* __restrict__ XT, const f16* __restrict__ dpeD,
                                              float* __restrict__ Yf, f16* __restrict__ Y16o,
                                              f16* __restrict__ hT16, f16* __restrict__ sT16, int first){
  __shared__ f16 sm[17408];
  f16* As = sm;
  f16* Bs = sm + 8192;
  int tid = threadIdx.x;
  int lane = tid & 63;
  int wv = tid >> 6;
  int n_blk = blockIdx.x * 128;
  int m_blk = blockIdx.y * 128;
  int bz = blockIdx.z;
  const f16* Xb = XT + (size_t)bz * (LLEN*TSZ);
  int wm = (wv & 1) * 64;
  int wn = (wv >> 1) * 64;

  f32x16 acc[2][2];
#pragma unroll
  for (int mi=0;mi<2;mi++)
#pragma unroll
    for (int ni=0;ni<2;ni++)
#pragma unroll
      for (int r=0;r<16;r++) acc[mi][ni][r] = 0.f;

  for (int kt=0; kt<4; kt++){
    int k0 = kt*64;
#pragma unroll
    for (int i=0;i<4;i++){
      int job = i*256 + tid;
      int m = job >> 3, gk = job & 7;
      const float* wp = W + (size_t)(m_blk + m)*TSZ + k0 + gk*8;
      float4 u0 = *(const float4*)wp;
      float4 u1 = *(const float4*)(wp+4);
      f16x8 hv;
      hv[0]=(f16)u0.x; hv[1]=(f16)u0.y; hv[2]=(f16)u0.z; hv[3]=(f16)u0.w;
      hv[4]=(f16)u1.x; hv[5]=(f16)u1.y; hv[6]=(f16)u1.z; hv[7]=(f16)u1.w;
      int P = m*8 + (gk ^ (m & 7));
      *(f16x8*)(As + P*8) = hv;
    }
#pragma unroll
    for (int i=0;i<4;i++){
      int job = i*256 + tid;
      int n = job >> 3, gk = job & 7;
      f16x8 hv = *(const f16x8*)(Xb + (size_t)(n_blk + n)*TSZ + k0 + gk*8);
      if (MODE==0){
        f16x8 dv = *(const f16x8*)(dpeD + bz*TSZ + k0 + gk*8);
#pragma unroll
        for (int e=0;e<8;e++) hv[e] = hv[e] + dv[e];
      }
      if (MODE==2){
#pragma unroll
        for (int e=0;e<8;e++) hv[e] = hv[e] * (f16)IS6;
      }
      int P = n*8 + (gk ^ (n & 7));
      *(f16x8*)(Bs + P*8) = hv;
    }
    __syncthreads();
#pragma unroll
    for (int ks=0; ks<4; ks++){
      int q = lane >> 5;
      int gk = ks*2 + q;
      f16x8 af[2], bf[2];
#pragma unroll
      for (int mi=0; mi<2; mi++){
        int m = wm + mi*32 + (lane & 31);
        af[mi] = *(const f16x8*)(As + (m*8 + (gk ^ (m&7)))*8);
      }
#pragma unroll
      for (int ni=0; ni<2; ni++){
        int n = wn + ni*32 + (lane & 31);
        bf[ni] = *(const f16x8*)(Bs + (n*8 + (gk ^ (n&7)))*8);
      }
#pragma unroll
      for (int mi=0; mi<2; mi++)
#pragma unroll
        for (int ni=0; ni<2; ni++)
          acc[mi][ni] = __builtin_amdgcn_mfma_f32_32x32x16_f16(af[mi], bf[ni], acc[mi][ni], 0, 0, 0);
    }
    __syncthreads();
  }

  int q = lane >> 5;
  if (MODE == 0){
#pragma unroll
    for (int mi=0;mi<2;mi++)
#pragma unroll
      for (int ni=0;ni<2;ni++){
        int col = n_blk + wn + ni*32 + (lane & 31);
#pragma unroll
        for (int r=0;r<16;r++){
          int row = m_blk + wm + mi*32 + (r&3) + 8*(r>>2) + 4*q;
          float v = acc[mi][ni][r] + bias[row];
          Y16o[((size_t)bz*HSZ + row)*LLEN + col] = (f16)v;
        }
      }
  } else if (MODE == 2){
#pragma unroll
    for (int mi=0;mi<2;mi++)
#pragma unroll
      for (int ni=0;ni<2;ni++){
        int col = n_blk + wn + ni*32 + (lane & 31);
#pragma unroll
        for (int r=0;r<16;r++){
          int row = m_blk + wm + mi*32 + (r&3) + 8*(r>>2) + 4*q;
          float v = fmaxf(acc[mi][ni][r] + bias[row], 0.f);
          Yf[((size_t)bz*TSZ + row)*LLEN + col] = v;
        }
      }
  } else {
    // tile RMW in transposed f16 buffers, via LDS (coalesced)
    int isRes = (blockIdx.y < 2);
    f16* dst = isRes ? hT16 : sT16;
    int mOff  = isRes ? m_blk : (m_blk - TSZ);
    int doLoad = isRes || !first;
    if (doLoad){
#pragma unroll
      for (int i=0;i<8;i++){
        int job = i*256 + tid;          // 128 n x 16 m-granules
        int n = job >> 4, m8 = job & 15;
        f16x8 hv = *(const f16x8*)(dst + ((size_t)bz*LLEN + n_blk + n)*TSZ + mOff + m8*8);
        *(f16x8*)(sm + n*136 + m8*8) = hv;
      }
      __syncthreads();
    }
#pragma unroll
    for (int mi=0;mi<2;mi++)
#pragma unroll
      for (int ni=0;ni<2;ni++){
        int col_l = wn + ni*32 + (lane & 31);
#pragma unroll
        for (int r=0;r<16;r++){
          int row_l = wm + mi*32 + (r&3) + 8*(r>>2) + 4*q;
          float v = acc[mi][ni][r] + bias[m_blk + row_l];
          if (isRes){
            float old = (float)sm[col_l*136 + row_l];
            sm[col_l*136 + row_l] = (f16)((old + v)*RS2);
          } else if (first){
            sm[col_l*136 + row_l] = (f16)v;
          } else {
            float old = (float)sm[col_l*136 + row_l];
            sm[col_l*136 + row_l] = (f16)(old + v);
          }
        }
      }
    __syncthreads();
#pragma unroll
    for (int i=0;i<8;i++){
      int job = i*256 + tid;
      int n = job >> 4, m8 = job & 15;
      f16x8 hv = *(const f16x8*)(sm + n*136 + m8*8);
      *(f16x8*)(dst + ((size_t)bz*LLEN + n_blk + n)*TSZ + mOff + m8*8) = hv;
    }
  }
}

// ---------------- S4D via MFMA conv (f16): 128-thread blocks, 4 batches each -------
template<int LN>
__global__ __launch_bounds__(128) void s4_mfma(const f16* __restrict__ matsq,
                                               const float2* __restrict__ lamPq,
                                               const f16* u, f16* y,
                                               const float* __restrict__ meanp,
                                               const float* __restrict__ rstdp,
                                               const float* __restrict__ gp,
                                               const float* __restrict__ btp){
  __shared__ f16 Ubuf[64*72];
  __shared__ f16 ZSbuf[64*72];     // Z -> Sprev -> Y (all f16)

  int tid  = threadIdx.x;
  int w    = tid >> 6;              // 0/1
  int lane = tid & 63;
  int q    = lane >> 5;
  int colL = lane & 31;
  int h  = blockIdx.x & 511;
  int bq = blockIdx.x >> 9;         // 0..3
  int b0 = bq*4;

  float gv = 0.f, bv = 0.f;
  if (LN){ gv = gp[h]; bv = btp[h]; }

  const f16* matT = matsq + (size_t)h*12288;
  const f16* matV = matT + 4096;
  const f16* matE = matT + 8192;

  // ---- stage u (wave w covers batches b0+2w, b0+2w+1), optional fused LN
#pragma unroll
  for (int i=0;i<4;i++){
    int fidx = i*64 + lane;               // 0..255
    int row = fidx >> 7;                  // 0/1
    int l   = (fidx & 127)*8;
    int b   = b0 + 2*w + row;
    f16x8 hv = *(const f16x8*)(u + ((size_t)b*HSZ + h)*LLEN + l);
    if (LN){
      float4 m0 = *(const float4*)(meanp + b*LLEN + l);
      float4 m1 = *(const float4*)(meanp + b*LLEN + l + 4);
      float4 r0 = *(const float4*)(rstdp + b*LLEN + l);
      float4 r1 = *(const float4*)(rstdp + b*LLEN + l + 4);
      float mm[8] = {m0.x,m0.y,m0.z,m0.w,m1.x,m1.y,m1.z,m1.w};
      float rr[8] = {r0.x,r0.y,r0.z,r0.w,r1.x,r1.y,r1.z,r1.w};
#pragma unroll
      for (int e=0;e<8;e++)
        hv[e] = (f16)(((float)hv[e] - mm[e])*rr[e]*gv + bv);
    }
    int col = (2*w + row)*16 + (l >> 6);
    *(f16x8*)(Ubuf + col*72 + (l & 63)) = hv;
  }
  __syncthreads();

  int strip = w*32;

  // ---- GEMM1: Z = V @ U
  {
    f32x16 zacc[2];
#pragma unroll
    for (int mt=0;mt<2;mt++)
#pragma unroll
      for (int r=0;r<16;r++) zacc[mt][r] = 0.f;
#pragma unroll
    for (int kt=0; kt<4; kt++){
      int kg = kt*2 + q;
      f16x8 bfrag = *(const f16x8*)(Ubuf + (strip+colL)*72 + kg*8);
#pragma unroll
      for (int mt=0; mt<2; mt++){
        f16x8 afrag = *(const f16x8*)(matV + ((size_t)(kg*64 + mt*32 + colL))*8);
        zacc[mt] = __builtin_amdgcn_mfma_f32_32x32x16_f16(afrag, bfrag, zacc[mt], 0, 0, 0);
      }
    }
#pragma unroll
    for (int mt=0;mt<2;mt++)
#pragma unroll
      for (int rg=0;rg<4;rg++){
        int st0 = mt*32 + rg*8 + q*4;
        f16x4 zp;
        zp[0]=(f16)zacc[mt][rg*4+0]; zp[1]=(f16)zacc[mt][rg*4+1];
        zp[2]=(f16)zacc[mt][rg*4+2]; zp[3]=(f16)zacc[mt][rg*4+3];
        *(f16x4*)(ZSbuf + (strip+colL)*72 + st0) = zp;
      }
  }
  __syncthreads();

  // ---- prefix over 16 chunks (in-place Z -> Sprev), per (batch-row, n) chain
  {
    int n  = lane & 31;
    int colb = (2*w + (lane>>5))*16;
    float2 l64 = lamPq[h*NST + n];
    float Sre = 0.f, Sim = 0.f;
#pragma unroll
    for (int c=0;c<16;c++){
      f16* p = ZSbuf + (colb + c)*72 + 2*n;
      f16x2 z2 = *(f16x2*)p;
      f16x2 sp_; sp_[0] = (f16)Sre; sp_[1] = (f16)Sim;
      *(f16x2*)p = sp_;
      float nr = fmaf(l64.x, Sre, fmaf(-l64.y, Sim, (float)z2[0]));
      float ni = fmaf(l64.x, Sim, fmaf( l64.y, Sre, (float)z2[1]));
      Sre = nr; Sim = ni;
    }
  }
  __syncthreads();

  // ---- GEMM2: Y = T @ U + E @ Sprev
  f32x16 yacc[2];
#pragma unroll
  for (int mt=0;mt<2;mt++)
#pragma unroll
    for (int r=0;r<16;r++) yacc[mt][r] = 0.f;
#pragma unroll
  for (int kt=0; kt<4; kt++){
    int kg = kt*2 + q;
    f16x8 bu = *(const f16x8*)(Ubuf  + (strip+colL)*72 + kg*8);
    f16x8 bs = *(const f16x8*)(ZSbuf + (strip+colL)*72 + kg*8);
#pragma unroll
    for (int mt=0; mt<2; mt++){
      f16x8 aT = *(const f16x8*)(matT + ((size_t)(kg*64 + mt*32 + colL))*8);
      yacc[mt] = __builtin_amdgcn_mfma_f32_32x32x16_f16(aT, bu, yacc[mt], 0, 0, 0);
    }
#pragma unroll
    for (int mt=0; mt<2; mt++){
      f16x8 aE = *(const f16x8*)(matE + ((size_t)(kg*64 + mt*32 + colL))*8);
      yacc[mt] = __builtin_amdgcn_mfma_f32_32x32x16_f16(aE, bs, yacc[mt], 0, 0, 0);
    }
  }
  __syncthreads();

  // ---- store Y (f16) into ZSbuf region, then coalesced f16x8 global write
#pragma unroll
  for (int mt=0;mt<2;mt++)
#pragma unroll
    for (int rg=0;rg<4;rg++){
      int j0 = mt*32 + rg*8 + q*4;
      f16x4 yv;
      yv[0]=(f16)yacc[mt][rg*4+0]; yv[1]=(f16)yacc[mt][rg*4+1];
      yv[2]=(f16)yacc[mt][rg*4+2]; yv[3]=(f16)yacc[mt][rg*4+3];
      *(f16x4*)(ZSbuf + (strip+colL)*72 + j0) = yv;
    }
  __syncthreads();
#pragma unroll
  for (int i=0;i<4;i++){
    int fidx = i*64 + lane;
    int row = fidx >> 7;
    int l   = (fidx & 127)*8;
    int b   = b0 + 2*w + row;
    int col = (2*w + row)*16 + (l >> 6);
    f16x8 hv = *(const f16x8*)(ZSbuf + col*72 + (l & 63));
    *(f16x8*)(y + ((size_t)b*HSZ + h)*LLEN + l) = hv;
  }
}

// ---------------- LN stats: mean/rstd per (b,l) over 512 channels (f16 input) ------
__global__ __launch_bounds__(256) void ln_stats(const f16* __restrict__ in,
                                                float* __restrict__ mean, float* __restrict__ rstd){
  __shared__ float rs[4][64];
  __shared__ float rq[4][64];
  int tid = threadIdx.x;
  int hg = tid >> 6;
  int lo = tid & 63;
  int b = blockIdx.x >> 4;
  int l = ((blockIdx.x & 15) << 6) + lo;
  size_t base = (size_t)(b*HSZ)*LLEN + l;
  float s=0.f, ss=0.f;
  for (int hh=0; hh<128; hh++){
    float v = (float)in[base + (size_t)(hg*128+hh)*LLEN];
    s += v; ss = fmaf(v,v,ss);
  }
  rs[hg][lo]=s; rq[hg][lo]=ss;
  __syncthreads();
  if (tid < 64){
    float S = rs[0][tid]+rs[1][tid]+rs[2][tid]+rs[3][tid];
    float Q = rq[0][tid]+rq[1][tid]+rq[2][tid]+rq[3][tid];
    float mn = S * (1.f/HSZ);
    float var  = Q * (1.f/HSZ) - mn*mn;
    int lw = ((blockIdx.x & 15) << 6) + tid;
    mean[b*LLEN + lw] = mn;
    rstd[b*LLEN + lw] = rsqrtf(var + 1e-5f);
  }
}

// ---------------- LN + gate fused (f16 input), output transposed f16 [b][l][t] -----
__global__ __launch_bounds__(256) void ln_gate_kernel(const f16* __restrict__ in, f16* __restrict__ gT,
                                                      const float* __restrict__ g, const float* __restrict__ bt){
  __shared__ float rs[4][64];
  __shared__ float rq[4][64];
  __shared__ float mbuf[64], rbuf[64];
  __shared__ f16 gbuf[64*272];
  int tid = threadIdx.x;
  int hg = tid >> 6;
  int lo = tid & 63;
  int b = blockIdx.x >> 4;
  int l0 = (blockIdx.x & 15) << 6;
  int l = l0 + lo;
  size_t base = (size_t)(b*HSZ)*LLEN + l;
  float s=0.f, ss=0.f;
  for (int hh=0; hh<128; hh++){
    float v = (float)in[base + (size_t)(hg*128+hh)*LLEN];
    s += v; ss = fmaf(v,v,ss);
  }
  rs[hg][lo]=s; rq[hg][lo]=ss;
  __syncthreads();
  if (tid < 64){
    float S = rs[0][tid]+rs[1][tid]+rs[2][tid]+rs[3][tid];
    float Q = rq[0][tid]+rq[1][tid]+rq[2][tid]+rq[3][tid];
    float mean = S * (1.f/HSZ);
    float var  = Q * (1.f/HSZ) - mean*mean;
    mbuf[tid]=mean;
    rbuf[tid]=rsqrtf(var + 1e-5f);
  }
  __syncthreads();
  float mean = mbuf[lo], rstd = rbuf[lo];
  for (int tt=0; tt<64; tt++){
    int t = hg*64 + tt;
    float a = ((float)in[base + (size_t)t*LLEN]       - mean)*rstd*g[t]     + bt[t];
    float f = ((float)in[base + (size_t)(t+256)*LLEN] - mean)*rstd*g[t+256] + bt[t+256];
    float sg = 1.f/(1.f+__expf(-a));
    float th = 1.f - 2.f/(__expf(2.f*f)+1.f);
    gbuf[lo*272 + t] = (f16)(sg*th);
  }
  __syncthreads();
#pragma unroll
  for (int i=0;i<8;i++){
    int job = i*256 + tid;
    int ll = job >> 5, g8 = (job & 31)*8;
    f16x8 hv = *(const f16x8*)(gbuf + ll*272 + g8);
    *(f16x8*)(gT + ((size_t)b*LLEN + l0 + ll)*TSZ + g8) = hv;
  }
}

// ---------------- out2 projection + 1/sqrt(beta) + transpose to [B,L,14] --------
__global__ __launch_bounds__(256) void out2_kernel(const float* __restrict__ w2, const float* __restrict__ b2,
                                                   const float* __restrict__ t, const float* __restrict__ z,
                                                   float* __restrict__ outp){
  __shared__ float ws[14*256];
  __shared__ float bs[14];
  int tid = threadIdx.x;
#pragma unroll
  for (int c=0;c<14;c++) ws[c*256+tid] = w2[c*256+tid];
  if (tid < 14) bs[tid] = b2[tid];
  __syncthreads();
  int b = blockIdx.x >> 2;
  int l = ((blockIdx.x & 3) << 8) + tid;
  float tb = t[b];
  float scale = rsqrtf(1e-4f + tb*(2e-2f - 1e-4f));
  float acc[14];
#pragma unroll
  for (int c=0;c<14;c++) acc[c]=0.f;
  const float* zp = z + (size_t)b*TSZ*LLEN + l;
  for (int tt2=0; tt2<256; tt2++){
    float xv = zp[(size_t)tt2*LLEN];
#pragma unroll
    for (int c=0;c<14;c++) acc[c] = fmaf(ws[c*256+tt2], xv, acc[c]);
  }
  float* op = outp + (size_t)(b*LLEN + l)*CINN;
#pragma unroll
  for (int c=0;c<14;c++) op[c] = (acc[c]+bs[c])*scale;
}

// ---------------- host launcher ----------------
extern "C" void kernel_launch(void* const* d_in, const int* in_sizes, int n_in,
                              void* d_out, int out_size, void* d_ws, size_t ws_size,
                              hipStream_t stream) {
  (void)in_sizes; (void)n_in; (void)out_size;
  if (ws_size < (size_t)WS_FLOATS * 4) return;

  const float* x      = (const float*)d_in[0];
  const float* t      = (const float*)d_in[1];
  const float* gfpW   = (const float*)d_in[2];
  const float* ew1    = (const float*)d_in[3];
  const float* eb1    = (const float*)d_in[4];
  const float* ew2    = (const float*)d_in[5];
  const float* eb2    = (const float*)d_in[6];
  const float* in_w   = (const float*)d_in[7];
  const float* in_b   = (const float*)d_in[8];
  const float* out1_w = (const float*)d_in[9];
  const float* out1_b = (const float*)d_in[10];
  const float* out2_w = (const float*)d_in[11];
  const float* out2_b = (const float*)d_in[12];
  const float* dp_w   = (const float*)d_in[13];
  const float* dp_b   = (const float*)d_in[14];
  const float* ip_w   = (const float*)d_in[15];
  const float* ip_b   = (const float*)d_in[16];
  const float* op_w   = (const float*)d_in[17];
  const float* op_b   = (const float*)d_in[18];
  const float* log_dt = (const float*)d_in[19];
  const float* logA   = (const float*)d_in[20];
  const float* Aim    = (const float*)d_in[21];
  const float* Cre    = (const float*)d_in[22];
  const float* Cim    = (const float*)d_in[23];
  const float* s4D    = (const float*)d_in[24];
  const float* ln_g   = (const float*)d_in[25];
  const float* ln_b   = (const float*)d_in[26];
  float* out = (float*)d_out;
  float* ws = (float*)d_ws;

  float2* lam2  = (float2*)(ws + OFF_LAM);
  float2* C2v   = (float2*)(ws + OFF_C);
  float2* lamP  = (float2*)(ws + OFF_LAMP);
  float* embb  = ws + OFF_EMB;
  f16*   dpe16 = (f16*)(ws + OFF_DPE16);
  float* hbuf  = ws + OFF_H;
  float* zbuf  = ws + OFF_Z;
  f16*   y16   = (f16*)(ws + OFF_Y16);
  f16*   hT16  = (f16*)(ws + OFF_HT);
  f16*   gT16  = (f16*)(ws + OFF_GT);
  f16*   sT16  = (f16*)(ws + OFF_ST);
  float* meanb = ws + OFF_MEAN;
  float* rstdb = ws + OFF_RSTD;
  f16*   mats  = (f16*)(ws + OFF_MATS);

  consts_kernel<<<768,256,0,stream>>>(log_dt, logA, Aim, Cre, Cim, lam2, C2v, lamP);
  emb_kernel<<<BB,128,0,stream>>>(t, gfpW, ew1, eb1, ew2, eb2, embb);
  dpe_kernel<<<NDEPTH*BB,256,0,stream>>>(embb, dp_w, dp_b, dpe16);
  inproj_kernel<<<64,256,0,stream>>>(x, in_w, in_b, hbuf);
  h2t_kernel<<<dim3(16,4,16),256,0,stream>>>(hbuf, hT16);

  for (int d=0; d<NDEPTH; d++){
    int q0 = d*2, q1 = d*2+1;
    // ip: hT16 (+dpe) -> y16 f16
    gemm_k<0><<<dim3(8,4,16),256,0,stream>>>(ip_w + (size_t)d*HSZ*TSZ, ip_b + d*HSZ,
                                             hT16, dpe16 + (size_t)d*BB*TSZ,
                                             nullptr, y16, nullptr, nullptr, 0);
    // build T/V/E for both layers of this depth
    build_mats<<<1024,256,0,stream>>>(lam2 + (size_t)q0*QHN, C2v + (size_t)q0*QHN,
                                      s4D + (size_t)q0*HSZ, mats);
    // S4 q0 (in place on y16)
    s4_mfma<0><<<2048,128,0,stream>>>(mats, lamP + (size_t)q0*QHN, y16, y16,
                                      nullptr, nullptr, nullptr, nullptr);
    // mid-LN stats (applied inside next s4's staging)
    ln_stats<<<256,256,0,stream>>>(y16, meanb, rstdb);
    // S4 q1 with fused LN(q0)
    s4_mfma<1><<<2048,128,0,stream>>>(mats + (size_t)512*12288, lamP + (size_t)q1*QHN, y16, y16,
                                      meanb, rstdb, ln_g + q0*HSZ, ln_b + q0*HSZ);
    // LN(q1) + gate -> gT16
    ln_gate_kernel<<<256,256,0,stream>>>(y16, gT16, ln_g + q1*HSZ, ln_b + q1*HSZ);
    // op: gT16 -> res RMW(hT16) / skip RMW(sT16)
    gemm_k<1><<<dim3(8,4,16),256,0,stream>>>(op_w + (size_t)d*HSZ*TSZ, op_b + d*HSZ,
                                             gT16, nullptr, nullptr, nullptr, hT16, sT16, (d==0)?1:0);
  }
  // out1 reads sT16 directly (skip sum, transposed f16)
  gemm_k<2><<<dim3(8,2,16),256,0,stream>>>(out1_w, out1_b, sT16, nullptr,
                                           zbuf, nullptr, nullptr, nullptr, 0);
  out2_kernel<<<64,256,0,stream>>>(out2_w, out2_b, t, zbuf, out);
}

// Round 11
// 731.569 us; speedup vs baseline: 3.5145x; 1.0643x over previous
//
#include <hip/hip_runtime.h>

// ---------------- problem constants ----------------
#define BB     16
#define LLEN   1024
#define CINN   14
#define TSZ    256
#define HSZ    512
#define NST    32
#define ESZ    128
#define NDEPTH 6
#define QHN    (HSZ*NST)

#define RS2 0.70710678118654752f   // 1/sqrt(2)
#define IS6 0.40824829046386302f   // 1/sqrt(6)

typedef unsigned short u16;
typedef unsigned int   u32;
typedef _Float16 f16;
typedef __attribute__((ext_vector_type(2)))  _Float16 f16x2;
typedef __attribute__((ext_vector_type(4)))  _Float16 f16x4;
typedef __attribute__((ext_vector_type(8)))  _Float16 f16x8;
typedef __attribute__((ext_vector_type(16))) float    f32x16;

// workspace layout (float offsets)
#define OFF_LAM   0u          // float2 lambda      x 12*16384
#define OFF_C     393216u     // float2 C'          x 12*16384
#define OFF_LAMP  786432u     // float2 lambda^64   x 12*16384
#define OFF_EMB   1179648u
#define OFF_DPE16 1181696u
#define OFF_H     1193984u    // fp32 [16][256][1024] (initial h only)
#define OFF_Y16   5388288u    // f16  [16][512][1024]
#define OFF_HT    9582592u    // f16  [16][1024][256]
#define OFF_GT    11679744u
#define OFF_ST    13776896u
#define OFF_ZT    15874048u   // f16  [16][1024][256] (out1 output, transposed)
#define OFF_MEAN  17971200u
#define OFF_RSTD  17987584u
#define OFF_MATS  18003968u   // f16 [12][512][3][4096] = 37748736 floats
#define WS_FLOATS 55752704u

#define MATS_PER_LAYER ((size_t)512*12288)

// ---------------- S4D constants: lambda, C' = 2C(lambda-1)/A, lambda^64 ----------------
__global__ void consts_kernel(const float* __restrict__ log_dt, const float* __restrict__ logA,
                              const float* __restrict__ Aim,   const float* __restrict__ Cre,
                              const float* __restrict__ Cim,
                              float2* __restrict__ lam2, float2* __restrict__ C2,
                              float2* __restrict__ lamP){
  int gid = blockIdx.x*256 + threadIdx.x;            // q*16384 + h*32 + n
  int h = (gid>>5) & 511;
  int q = gid >> 14;
  float dt  = expf(log_dt[q*HSZ + h]);
  float are = -expf(logA[gid]);
  float aim = Aim[gid];
  float dre = are*dt, dim = aim*dt;
  float e   = expf(dre);
  float lre = e*cosf(dim), lim = e*sinf(dim);
  float nre = lre - 1.f, nim = lim;
  float invden = 1.f/(are*are + aim*aim);
  float tre = (nre*are + nim*aim)*invden;
  float tim = (nim*are - nre*aim)*invden;
  float cr = Cre[gid], ci = Cim[gid];
  float Cr = 2.f*(cr*tre - ci*tim);
  float Ci = 2.f*(cr*tim + ci*tre);
  lam2[gid] = make_float2(lre, lim);
  C2[gid]   = make_float2(Cr, Ci);
  float pr = lre, pi = lim;
#pragma unroll
  for (int i=0;i<6;i++){ float nr2 = pr*pr - pi*pi; pi = 2.f*pr*pi; pr = nr2; }
  lamP[gid] = make_float2(pr, pi);
}

// ---------------- build ALL per-(q,h) f16 matrices T,V,E (MFMA A-frag order) ----------
// grid 6144: bid = q*512 + h
__global__ __launch_bounds__(256) void build_mats(const float2* __restrict__ lam2d,
                                                  const float2* __restrict__ C2d,
                                                  const float* __restrict__ Dd,
                                                  f16* __restrict__ mats){
  __shared__ float Pre[65][33];
  __shared__ float Pim[65][33];
  __shared__ float Kk[64];
  int bid = blockIdx.x;
  int q   = bid >> 9;            // 0..11
  int h   = bid & 511;
  const float2* lp = lam2d + (size_t)q*QHN + h*NST;
  const float2* cp = C2d  + (size_t)q*QHN + h*NST;
  int tid = threadIdx.x;
  int n  = tid & 31;
  int pg = tid >> 5;             // 0..7
  {
    float2 l = lp[n];
    float ar=l.x, ai=l.y;
#pragma unroll
    for (int i=0;i<3;i++){ float t2 = ar*ar - ai*ai; ai = 2.f*ar*ai; ar = t2; }
    float br=1.f, bi=0.f;
    for (int i=0;i<pg;i++){ float t2 = br*ar - bi*ai; bi = br*ai + bi*ar; br = t2; }
    float pr=br, pi=bi;
#pragma unroll
    for (int i=0;i<8;i++){
      Pre[8*pg+i][n] = pr; Pim[8*pg+i][n] = pi;
      float t2 = pr*l.x - pi*l.y; pi = pr*l.y + pi*l.x; pr = t2;
    }
    if (pg == 7){ Pre[64][n] = pr; Pim[64][n] = pi; }
  }
  __syncthreads();
  if (tid < 64){
    float s = 0.f;
    for (int n2=0;n2<32;n2++){
      float2 c_ = cp[n2];
      s += c_.x*Pre[tid][n2] - c_.y*Pim[tid][n2];
    }
    Kk[tid] = s;
  }
  __syncthreads();
  float Kdiag = Kk[0] + Dd[q*HSZ + h];
  f16* base = mats + (size_t)bid*12288;
#pragma unroll
  for (int jj=0; jj<6; jj++){
    int job = jj*256 + tid;       // 0..1535
    int mat = job >> 9;           // 0:T 1:V 2:E
    int rem = job & 511;
    int m = rem >> 3;
    int g = rem & 7;
    f16x8 vals;
    if (mat == 0){
#pragma unroll
      for (int j8=0;j8<8;j8++){
        int k = g*8 + j8;
        float v = (m > k) ? Kk[m-k] : ((m == k) ? Kdiag : 0.f);
        vals[j8] = (f16)v;
      }
    } else if (mat == 1){
      int n2 = m >> 1; int im = m & 1;
#pragma unroll
      for (int j8=0;j8<8;j8++){
        int k = g*8 + j8; int p = 63 - k;
        vals[j8] = (f16)(im ? Pim[p][n2] : Pre[p][n2]);
      }
    } else {
#pragma unroll
      for (int j8=0;j8<8;j8++){
        int k = g*8 + j8; int n2 = k >> 1;
        float2 c_ = cp[n2];
        float pr = Pre[m+1][n2], pi = Pim[m+1][n2];
        float re  = c_.x*pr - c_.y*pi;
        float imv = c_.x*pi + c_.y*pr;
        vals[j8] = (f16)((k & 1) ? -imv : re);
      }
    }
    *(f16x8*)(base + mat*4096 + (g*64 + m)*8) = vals;
  }
}

// ---------------- diffusion embedding MLP ----------------
__global__ void emb_kernel(const float* __restrict__ t, const float* __restrict__ gw,
                           const float* __restrict__ w1, const float* __restrict__ b1,
                           const float* __restrict__ w2, const float* __restrict__ b2,
                           float* __restrict__ emb){
  __shared__ float e0[128], e1[128];
  int b = blockIdx.x, tid = threadIdx.x;
  float tb = t[b];
  if (tid < 64){
    float xp = tb * gw[tid] * 6.283185307179586f;
    e0[tid]    = sinf(xp);
    e0[tid+64] = cosf(xp);
  }
  __syncthreads();
  float a = b1[tid];
  for (int i=0;i<128;i++) a = fmaf(e0[i], w1[tid*128+i], a);
  a = a / (1.f + __expf(-a));
  e1[tid] = a;
  __syncthreads();
  float a2 = b2[tid];
  for (int i=0;i<128;i++) a2 = fmaf(e1[i], w2[tid*128+i], a2);
  a2 = a2 / (1.f + __expf(-a2));
  emb[b*ESZ + tid] = a2;
}

// ---------------- per-depth diffusion projection -> f16 ----------------
__global__ void dpe_kernel(const float* __restrict__ emb, const float* __restrict__ dw,
                           const float* __restrict__ db, f16* __restrict__ dpe16){
  int blk = blockIdx.x; int d = blk >> 4; int b = blk & 15; int o = threadIdx.x;
  const float* wp = dw + (size_t)(d*TSZ + o)*ESZ;
  const float* ep = emb + b*ESZ;
  float a = db[d*TSZ + o];
  for (int e=0;e<128;e++) a = fmaf(ep[e], wp[e], a);
  dpe16[(size_t)(d*BB + b)*TSZ + o] = (f16)a;
}

// ---------------- input projection [B,L,14] -> h [B,256,L] fp32 ----------------
__global__ __launch_bounds__(256) void inproj_kernel(const float* __restrict__ x, const float* __restrict__ w,
                                                     const float* __restrict__ bias, float* __restrict__ hb){
  __shared__ float ws[256*14];
  __shared__ float bs[256];
  int tid = threadIdx.x;
#pragma unroll
  for (int c=0;c<14;c++) ws[tid*14+c] = w[tid*14+c];
  bs[tid] = bias[tid];
  __syncthreads();
  int b = blockIdx.x >> 2;
  int l = ((blockIdx.x & 3) << 8) + tid;
  float xv[14];
  const float* xp = x + (size_t)(b*LLEN + l)*CINN;
#pragma unroll
  for (int c=0;c<14;c++) xv[c] = xp[c];
  for (int o=0;o<256;o++){
    float a = bs[o];
#pragma unroll
    for (int c=0;c<14;c++) a = fmaf(ws[o*14+c], xv[c], a);
    hb[(size_t)(b*TSZ + o)*LLEN + l] = a;
  }
}

// ---------------- transpose fp32 [b][256][1024] -> f16 [b][1024][256] ----------------
__global__ __launch_bounds__(256) void h2t_kernel(const float* __restrict__ src, f16* __restrict__ dst){
  __shared__ f16 TT[64*72];
  int tid = threadIdx.x;
  int b = blockIdx.z;
  int l0 = blockIdx.x * 64;
  int t0 = blockIdx.y * 64;
#pragma unroll
  for (int i=0;i<4;i++){
    int job = i*256 + tid;
    int tt = job >> 4, l4 = (job & 15)*4;
    float4 v = *(const float4*)(src + ((size_t)b*TSZ + t0+tt)*LLEN + l0 + l4);
    TT[(l4+0)*72 + tt] = (f16)v.x;
    TT[(l4+1)*72 + tt] = (f16)v.y;
    TT[(l4+2)*72 + tt] = (f16)v.z;
    TT[(l4+3)*72 + tt] = (f16)v.w;
  }
  __syncthreads();
#pragma unroll
  for (int i=0;i<2;i++){
    int job = i*256 + tid;
    int l = job >> 3, g = job & 7;
    f16x8 hv = *(const f16x8*)(TT + l*72 + g*8);
    *(f16x8*)(dst + ((size_t)b*LLEN + l0 + l)*TSZ + t0 + g*8) = hv;
  }
}

// ---------------- MFMA GEMM ----------------
// MODE 0: ip  (B = hT16 + dpe16, Y16o f16 [512][1024])
// MODE 1: op  (B = gT16; y<2: res RMW in hT16; y>=2: skip RMW in sT16)
// MODE 2: out1 (B = sT16 * IS6, relu, Y16o = zT16 transposed f16 [1024][256])
template<int MODE>
__global__ __launch_bounds__(256) void gemm_k(const float* __restrict__ W, const float* __restrict__ bias,
                                              const f16* __restrict__ XT, const f16* __restrict__ dpeD,
                                              f16* __restrict__ Y16o,
                                              f16* __restrict__ hT16, f16* __restrict__ sT16, int first){
  __shared__ f16 sm[17408];
  f16* As = sm;
  f16* Bs = sm + 8192;
  int tid = threadIdx.x;
  int lane = tid & 63;
  int wv = tid >> 6;
  int n_blk = blockIdx.x * 128;
  int m_blk = blockIdx.y * 128;
  int bz = blockIdx.z;
  const f16* Xb = XT + (size_t)bz * (LLEN*TSZ);
  int wm = (wv & 1) * 64;
  int wn = (wv >> 1) * 64;

  f32x16 acc[2][2];
#pragma unroll
  for (int mi=0;mi<2;mi++)
#pragma unroll
    for (int ni=0;ni<2;ni++)
#pragma unroll
      for (int r=0;r<16;r++) acc[mi][ni][r] = 0.f;

  for (int kt=0; kt<4; kt++){
    int k0 = kt*64;
#pragma unroll
    for (int i=0;i<4;i++){
      int job = i*256 + tid;
      int m = job >> 3, gk = job & 7;
      const float* wp = W + (size_t)(m_blk + m)*TSZ + k0 + gk*8;
      float4 u0 = *(const float4*)wp;
      float4 u1 = *(const float4*)(wp+4);
      f16x8 hv;
      hv[0]=(f16)u0.x; hv[1]=(f16)u0.y; hv[2]=(f16)u0.z; hv[3]=(f16)u0.w;
      hv[4]=(f16)u1.x; hv[5]=(f16)u1.y; hv[6]=(f16)u1.z; hv[7]=(f16)u1.w;
      int P = m*8 + (gk ^ (m & 7));
      *(f16x8*)(As + P*8) = hv;
    }
#pragma unroll
    for (int i=0;i<4;i++){
      int job = i*256 + tid;
      int n = job >> 3, gk = job & 7;
      f16x8 hv = *(const f16x8*)(Xb + (size_t)(n_blk + n)*TSZ + k0 + gk*8);
      if (MODE==0){
        f16x8 dv = *(const f16x8*)(dpeD + bz*TSZ + k0 + gk*8);
#pragma unroll
        for (int e=0;e<8;e++) hv[e] = hv[e] + dv[e];
      }
      if (MODE==2){
#pragma unroll
        for (int e=0;e<8;e++) hv[e] = hv[e] * (f16)IS6;
      }
      int P = n*8 + (gk ^ (n & 7));
      *(f16x8*)(Bs + P*8) = hv;
    }
    __syncthreads();
#pragma unroll
    for (int ks=0; ks<4; ks++){
      int q = lane >> 5;
      int gk = ks*2 + q;
      f16x8 af[2], bf[2];
#pragma unroll
      for (int mi=0; mi<2; mi++){
        int m = wm + mi*32 + (lane & 31);
        af[mi] = *(const f16x8*)(As + (m*8 + (gk ^ (m&7)))*8);
      }
#pragma unroll
      for (int ni=0; ni<2; ni++){
        int n = wn + ni*32 + (lane & 31);
        bf[ni] = *(const f16x8*)(Bs + (n*8 + (gk ^ (n&7)))*8);
      }
#pragma unroll
      for (int mi=0; mi<2; mi++)
#pragma unroll
        for (int ni=0; ni<2; ni++)
          acc[mi][ni] = __builtin_amdgcn_mfma_f32_32x32x16_f16(af[mi], bf[ni], acc[mi][ni], 0, 0, 0);
    }
    __syncthreads();
  }

  int q = lane >> 5;
  if (MODE == 0){
#pragma unroll
    for (int mi=0;mi<2;mi++)
#pragma unroll
      for (int ni=0;ni<2;ni++){
        int col = n_blk + wn + ni*32 + (lane & 31);
#pragma unroll
        for (int r=0;r<16;r++){
          int row = m_blk + wm + mi*32 + (r&3) + 8*(r>>2) + 4*q;
          float v = acc[mi][ni][r] + bias[row];
          Y16o[((size_t)bz*HSZ + row)*LLEN + col] = (f16)v;
        }
      }
  } else if (MODE == 2){
    // relu + transpose-store to zT16 [b][l][256]
#pragma unroll
    for (int mi=0;mi<2;mi++)
#pragma unroll
      for (int ni=0;ni<2;ni++){
        int col_l = wn + ni*32 + (lane & 31);
#pragma unroll
        for (int r=0;r<16;r++){
          int row_l = wm + mi*32 + (r&3) + 8*(r>>2) + 4*q;
          float v = fmaxf(acc[mi][ni][r] + bias[m_blk + row_l], 0.f);
          sm[col_l*136 + row_l] = (f16)v;
        }
      }
    __syncthreads();
#pragma unroll
    for (int i=0;i<8;i++){
      int job = i*256 + tid;
      int n = job >> 4, m8 = job & 15;
      f16x8 hv = *(const f16x8*)(sm + n*136 + m8*8);
      *(f16x8*)(Y16o + ((size_t)bz*LLEN + n_blk + n)*TSZ + m_blk + m8*8) = hv;
    }
  } else {
    // tile RMW in transposed f16 buffers, via LDS (coalesced)
    int isRes = (blockIdx.y < 2);
    f16* dst = isRes ? hT16 : sT16;
    int mOff  = isRes ? m_blk : (m_blk - TSZ);
    int doLoad = isRes || !first;
    if (doLoad){
#pragma unroll
      for (int i=0;i<8;i++){
        int job = i*256 + tid;          // 128 n x 16 m-granules
        int n = job >> 4, m8 = job & 15;
        f16x8 hv = *(const f16x8*)(dst + ((size_t)bz*LLEN + n_blk + n)*TSZ + mOff + m8*8);
        *(f16x8*)(sm + n*136 + m8*8) = hv;
      }
      __syncthreads();
    }
#pragma unroll
    for (int mi=0;mi<2;mi++)
#pragma unroll
      for (int ni=0;ni<2;ni++){
        int col_l = wn + ni*32 + (lane & 31);
#pragma unroll
        for (int r=0;r<16;r++){
          int row_l = wm + mi*32 + (r&3) + 8*(r>>2) + 4*q;
          float v = acc[mi][ni][r] + bias[m_blk + row_l];
          if (isRes){
            float old = (float)sm[col_l*136 + row_l];
            sm[col_l*136 + row_l] = (f16)((old + v)*RS2);
          } else if (first){
            sm[col_l*136 + row_l] = (f16)v;
          } else {
            float old = (float)sm[col_l*136 + row_l];
            sm[col_l*136 + row_l] = (f16)(old + v);
          }
        }
      }
    __syncthreads();
#pragma unroll
    for (int i=0;i<8;i++){
      int job = i*256 + tid;
      int n = job >> 4, m8 = job & 15;
      f16x8 hv = *(const f16x8*)(sm + n*136 + m8*8);
      *(f16x8*)(dst + ((size_t)bz*LLEN + n_blk + n)*TSZ + mOff + m8*8) = hv;
    }
  }
}

// ---------------- S4D via MFMA conv (f16): 128-thread blocks, 4 batches each -------
template<int LN>
__global__ __launch_bounds__(128) void s4_mfma(const f16* __restrict__ matsq,
                                               const float2* __restrict__ lamPq,
                                               const f16* u, f16* y,
                                               const float* __restrict__ meanp,
                                               const float* __restrict__ rstdp,
                                               const float* __restrict__ gp,
                                               const float* __restrict__ btp){
  __shared__ f16 Ubuf[64*72];
  __shared__ f16 ZSbuf[64*72];     // Z -> Sprev -> Y (all f16)

  int tid  = threadIdx.x;
  int w    = tid >> 6;              // 0/1
  int lane = tid & 63;
  int q    = lane >> 5;
  int colL = lane & 31;
  int h  = blockIdx.x & 511;
  int bq = blockIdx.x >> 9;         // 0..3
  int b0 = bq*4;

  float gv = 0.f, bv = 0.f;
  if (LN){ gv = gp[h]; bv = btp[h]; }

  const f16* matT = matsq + (size_t)h*12288;
  const f16* matV = matT + 4096;
  const f16* matE = matT + 8192;

  // ---- stage u (wave w covers batches b0+2w, b0+2w+1), optional fused LN
#pragma unroll
  for (int i=0;i<4;i++){
    int fidx = i*64 + lane;               // 0..255
    int row = fidx >> 7;                  // 0/1
    int l   = (fidx & 127)*8;
    int b   = b0 + 2*w + row;
    f16x8 hv = *(const f16x8*)(u + ((size_t)b*HSZ + h)*LLEN + l);
    if (LN){
      float4 m0 = *(const float4*)(meanp + b*LLEN + l);
      float4 m1 = *(const float4*)(meanp + b*LLEN + l + 4);
      float4 r0 = *(const float4*)(rstdp + b*LLEN + l);
      float4 r1 = *(const float4*)(rstdp + b*LLEN + l + 4);
      float mm[8] = {m0.x,m0.y,m0.z,m0.w,m1.x,m1.y,m1.z,m1.w};
      float rr[8] = {r0.x,r0.y,r0.z,r0.w,r1.x,r1.y,r1.z,r1.w};
#pragma unroll
      for (int e=0;e<8;e++)
        hv[e] = (f16)(((float)hv[e] - mm[e])*rr[e]*gv + bv);
    }
    int col = (2*w + row)*16 + (l >> 6);
    *(f16x8*)(Ubuf + col*72 + (l & 63)) = hv;
  }
  __syncthreads();

  int strip = w*32;

  // ---- GEMM1: Z = V @ U
  {
    f32x16 zacc[2];
#pragma unroll
    for (int mt=0;mt<2;mt++)
#pragma unroll
      for (int r=0;r<16;r++) zacc[mt][r] = 0.f;
#pragma unroll
    for (int kt=0; kt<4; kt++){
      int kg = kt*2 + q;
      f16x8 bfrag = *(const f16x8*)(Ubuf + (strip+colL)*72 + kg*8);
#pragma unroll
      for (int mt=0; mt<2; mt++){
        f16x8 afrag = *(const f16x8*)(matV + ((size_t)(kg*64 + mt*32 + colL))*8);
        zacc[mt] = __builtin_amdgcn_mfma_f32_32x32x16_f16(afrag, bfrag, zacc[mt], 0, 0, 0);
      }
    }
#pragma unroll
    for (int mt=0;mt<2;mt++)
#pragma unroll
      for (int rg=0;rg<4;rg++){
        int st0 = mt*32 + rg*8 + q*4;
        f16x4 zp;
        zp[0]=(f16)zacc[mt][rg*4+0]; zp[1]=(f16)zacc[mt][rg*4+1];
        zp[2]=(f16)zacc[mt][rg*4+2]; zp[3]=(f16)zacc[mt][rg*4+3];
        *(f16x4*)(ZSbuf + (strip+colL)*72 + st0) = zp;
      }
  }
  __syncthreads();

  // ---- prefix over 16 chunks (in-place Z -> Sprev), per (batch-row, n) chain
  {
    int n  = lane & 31;
    int colb = (2*w + (lane>>5))*16;
    float2 l64 = lamPq[h*NST + n];
    float Sre = 0.f, Sim = 0.f;
#pragma unroll
    for (int c=0;c<16;c++){
      f16* p = ZSbuf + (colb + c)*72 + 2*n;
      f16x2 z2 = *(f16x2*)p;
      f16x2 sp_; sp_[0] = (f16)Sre; sp_[1] = (f16)Sim;
      *(f16x2*)p = sp_;
      float nr = fmaf(l64.x, Sre, fmaf(-l64.y, Sim, (float)z2[0]));
      float ni = fmaf(l64.x, Sim, fmaf( l64.y, Sre, (float)z2[1]));
      Sre = nr; Sim = ni;
    }
  }
  __syncthreads();

  // ---- GEMM2: Y = T @ U + E @ Sprev
  f32x16 yacc[2];
#pragma unroll
  for (int mt=0;mt<2;mt++)
#pragma unroll
    for (int r=0;r<16;r++) yacc[mt][r] = 0.f;
#pragma unroll
  for (int kt=0; kt<4; kt++){
    int kg = kt*2 + q;
    f16x8 bu = *(const f16x8*)(Ubuf  + (strip+colL)*72 + kg*8);
    f16x8 bs = *(const f16x8*)(ZSbuf + (strip+colL)*72 + kg*8);
#pragma unroll
    for (int mt=0; mt<2; mt++){
      f16x8 aT = *(const f16x8*)(matT + ((size_t)(kg*64 + mt*32 + colL))*8);
      yacc[mt] = __builtin_amdgcn_mfma_f32_32x32x16_f16(aT, bu, yacc[mt], 0, 0, 0);
    }
#pragma unroll
    for (int mt=0; mt<2; mt++){
      f16x8 aE = *(const f16x8*)(matE + ((size_t)(kg*64 + mt*32 + colL))*8);
      yacc[mt] = __builtin_amdgcn_mfma_f32_32x32x16_f16(aE, bs, yacc[mt], 0, 0, 0);
    }
  }
  __syncthreads();

  // ---- store Y (f16) into ZSbuf region, then coalesced f16x8 global write
#pragma unroll
  for (int mt=0;mt<2;mt++)
#pragma unroll
    for (int rg=0;rg<4;rg++){
      int j0 = mt*32 + rg*8 + q*4;
      f16x4 yv;
      yv[0]=(f16)yacc[mt][rg*4+0]; yv[1]=(f16)yacc[mt][rg*4+1];
      yv[2]=(f16)yacc[mt][rg*4+2]; yv[3]=(f16)yacc[mt][rg*4+3];
      *(f16x4*)(ZSbuf + (strip+colL)*72 + j0) = yv;
    }
  __syncthreads();
#pragma unroll
  for (int i=0;i<4;i++){
    int fidx = i*64 + lane;
    int row = fidx >> 7;
    int l   = (fidx & 127)*8;
    int b   = b0 + 2*w + row;
    int col = (2*w + row)*16 + (l >> 6);
    f16x8 hv = *(const f16x8*)(ZSbuf + col*72 + (l & 63));
    *(f16x8*)(y + ((size_t)b*HSZ + h)*LLEN + l) = hv;
  }
}

// ---------------- LN stats: mean/rstd per (b,l), 512 blocks of 32 l ----------------
__global__ __launch_bounds__(256) void ln_stats(const f16* __restrict__ in,
                                                float* __restrict__ mean, float* __restrict__ rstd){
  __shared__ float rs[8][32];
  __shared__ float rq[8][32];
  int tid = threadIdx.x;
  int hg = tid >> 5;          // 0..7
  int lo = tid & 31;
  int b = blockIdx.x >> 5;
  int l = ((blockIdx.x & 31) << 5) + lo;
  size_t base = (size_t)(b*HSZ)*LLEN + l;
  float s=0.f, ss=0.f;
  for (int hh=0; hh<64; hh++){
    float v = (float)in[base + (size_t)(hg*64+hh)*LLEN];
    s += v; ss = fmaf(v,v,ss);
  }
  rs[hg][lo]=s; rq[hg][lo]=ss;
  __syncthreads();
  if (tid < 32){
    float S=0.f, Q=0.f;
#pragma unroll
    for (int g=0; g<8; g++){ S += rs[g][tid]; Q += rq[g][tid]; }
    float mn = S * (1.f/HSZ);
    float var  = Q * (1.f/HSZ) - mn*mn;
    int lw = ((blockIdx.x & 31) << 5) + tid;
    mean[b*LLEN + lw] = mn;
    rstd[b*LLEN + lw] = rsqrtf(var + 1e-5f);
  }
}

// ---------------- LN + gate fused, 512 blocks of 32 l, out transposed f16 ----------
__global__ __launch_bounds__(256) void ln_gate_kernel(const f16* __restrict__ in, f16* __restrict__ gT,
                                                      const float* __restrict__ g, const float* __restrict__ bt){
  __shared__ float rs[8][32];
  __shared__ float rq[8][32];
  __shared__ float mbuf[32], rbuf[32];
  __shared__ f16 gbuf[32*272];
  int tid = threadIdx.x;
  int hg = tid >> 5;
  int lo = tid & 31;
  int b = blockIdx.x >> 5;
  int l0 = (blockIdx.x & 31) << 5;
  int l = l0 + lo;
  size_t base = (size_t)(b*HSZ)*LLEN + l;
  float s=0.f, ss=0.f;
  for (int hh=0; hh<64; hh++){
    float v = (float)in[base + (size_t)(hg*64+hh)*LLEN];
    s += v; ss = fmaf(v,v,ss);
  }
  rs[hg][lo]=s; rq[hg][lo]=ss;
  __syncthreads();
  if (tid < 32){
    float S=0.f, Q=0.f;
#pragma unroll
    for (int gg=0; gg<8; gg++){ S += rs[gg][tid]; Q += rq[gg][tid]; }
    float mean = S * (1.f/HSZ);
    float var  = Q * (1.f/HSZ) - mean*mean;
    mbuf[tid]=mean;
    rbuf[tid]=rsqrtf(var + 1e-5f);
  }
  __syncthreads();
  float mean = mbuf[lo], rstd = rbuf[lo];
  for (int tt=0; tt<32; tt++){
    int t = hg*32 + tt;           // 8*32 = 256
    float a = ((float)in[base + (size_t)t*LLEN]       - mean)*rstd*g[t]     + bt[t];
    float f = ((float)in[base + (size_t)(t+256)*LLEN] - mean)*rstd*g[t+256] + bt[t+256];
    float sg = 1.f/(1.f+__expf(-a));
    float th = 1.f - 2.f/(__expf(2.f*f)+1.f);
    gbuf[lo*272 + t] = (f16)(sg*th);
  }
  __syncthreads();
#pragma unroll
  for (int i=0;i<4;i++){
    int job = i*256 + tid;           // 32 l x 32 granules
    int ll = job >> 5, g8 = (job & 31)*8;
    f16x8 hv = *(const f16x8*)(gbuf + ll*272 + g8);
    *(f16x8*)(gT + ((size_t)b*LLEN + l0 + ll)*TSZ + g8) = hv;
  }
}

// ---------------- out2: zT16 [b][l][256] -> out [b][l][14], coalesced -----------
__global__ __launch_bounds__(256) void out2_kernel(const float* __restrict__ w2, const float* __restrict__ b2,
                                                   const float* __restrict__ t, const f16* __restrict__ zT,
                                                   float* __restrict__ outp){
  __shared__ f16 zt[64*264];
  __shared__ float wsm[14*256];
  __shared__ float part[64][4][16];
  __shared__ float bs[14];
  int tid = threadIdx.x;
#pragma unroll
  for (int c=0;c<14;c++) wsm[c*256+tid] = w2[c*256+tid];
  if (tid < 14) bs[tid] = b2[tid];
  int b = blockIdx.x >> 4;
  int l0 = (blockIdx.x & 15) * 64;
#pragma unroll
  for (int i=0;i<8;i++){
    int job = i*256 + tid;           // 64 l x 32 granules
    int ll = job >> 5, g8 = (job & 31)*8;
    f16x8 hv = *(const f16x8*)(zT + ((size_t)b*LLEN + l0 + ll)*TSZ + g8);
    *(f16x8*)(zt + ll*264 + g8) = hv;
  }
  __syncthreads();
  int l = tid >> 2;
  int g = tid & 3;
  float acc[14];
#pragma unroll
  for (int c=0;c<14;c++) acc[c]=0.f;
  for (int k=0;k<64;k++){
    float zv = (float)zt[l*264 + g*64 + k];
#pragma unroll
    for (int c=0;c<14;c++) acc[c] = fmaf(wsm[c*256 + g*64 + k], zv, acc[c]);
  }
#pragma unroll
  for (int c=0;c<14;c++) part[l][g][c] = acc[c];
  __syncthreads();
  if (g == 0){
    float tb = t[b];
    float scale = rsqrtf(1e-4f + tb*(2e-2f - 1e-4f));
    float* op = outp + (size_t)(b*LLEN + l0 + l)*CINN;
#pragma unroll
    for (int c=0;c<14;c++)
      op[c] = (part[l][0][c]+part[l][1][c]+part[l][2][c]+part[l][3][c] + bs[c])*scale;
  }
}

// ---------------- host launcher ----------------
extern "C" void kernel_launch(void* const* d_in, const int* in_sizes, int n_in,
                              void* d_out, int out_size, void* d_ws, size_t ws_size,
                              hipStream_t stream) {
  (void)in_sizes; (void)n_in; (void)out_size;
  if (ws_size < (size_t)WS_FLOATS * 4) return;

  const float* x      = (const float*)d_in[0];
  const float* t      = (const float*)d_in[1];
  const float* gfpW   = (const float*)d_in[2];
  const float* ew1    = (const float*)d_in[3];
  const float* eb1    = (const float*)d_in[4];
  const float* ew2    = (const float*)d_in[5];
  const float* eb2    = (const float*)d_in[6];
  const float* in_w   = (const float*)d_in[7];
  const float* in_b   = (const float*)d_in[8];
  const float* out1_w = (const float*)d_in[9];
  const float* out1_b = (const float*)d_in[10];
  const float* out2_w = (const float*)d_in[11];
  const float* out2_b = (const float*)d_in[12];
  const float* dp_w   = (const float*)d_in[13];
  const float* dp_b   = (const float*)d_in[14];
  const float* ip_w   = (const float*)d_in[15];
  const float* ip_b   = (const float*)d_in[16];
  const float* op_w   = (const float*)d_in[17];
  const float* op_b   = (const float*)d_in[18];
  const float* log_dt = (const float*)d_in[19];
  const float* logA   = (const float*)d_in[20];
  const float* Aim    = (const float*)d_in[21];
  const float* Cre    = (const float*)d_in[22];
  const float* Cim    = (const float*)d_in[23];
  const float* s4D    = (const float*)d_in[24];
  const float* ln_g   = (const float*)d_in[25];
  const float* ln_b   = (const float*)d_in[26];
  float* out = (float*)d_out;
  float* ws = (float*)d_ws;

  float2* lam2  = (float2*)(ws + OFF_LAM);
  float2* C2v   = (float2*)(ws + OFF_C);
  float2* lamP  = (float2*)(ws + OFF_LAMP);
  float* embb  = ws + OFF_EMB;
  f16*   dpe16 = (f16*)(ws + OFF_DPE16);
  float* hbuf  = ws + OFF_H;
  f16*   y16   = (f16*)(ws + OFF_Y16);
  f16*   hT16  = (f16*)(ws + OFF_HT);
  f16*   gT16  = (f16*)(ws + OFF_GT);
  f16*   sT16  = (f16*)(ws + OFF_ST);
  f16*   zT16  = (f16*)(ws + OFF_ZT);
  float* meanb = ws + OFF_MEAN;
  float* rstdb = ws + OFF_RSTD;
  f16*   mats  = (f16*)(ws + OFF_MATS);

  consts_kernel<<<768,256,0,stream>>>(log_dt, logA, Aim, Cre, Cim, lam2, C2v, lamP);
  build_mats<<<6144,256,0,stream>>>(lam2, C2v, s4D, mats);
  emb_kernel<<<BB,128,0,stream>>>(t, gfpW, ew1, eb1, ew2, eb2, embb);
  dpe_kernel<<<NDEPTH*BB,256,0,stream>>>(embb, dp_w, dp_b, dpe16);
  inproj_kernel<<<64,256,0,stream>>>(x, in_w, in_b, hbuf);
  h2t_kernel<<<dim3(16,4,16),256,0,stream>>>(hbuf, hT16);

  for (int d=0; d<NDEPTH; d++){
    int q0 = d*2, q1 = d*2+1;
    // ip: hT16 (+dpe) -> y16 f16
    gemm_k<0><<<dim3(8,4,16),256,0,stream>>>(ip_w + (size_t)d*HSZ*TSZ, ip_b + d*HSZ,
                                             hT16, dpe16 + (size_t)d*BB*TSZ,
                                             y16, nullptr, nullptr, 0);
    // S4 q0 (in place on y16)
    s4_mfma<0><<<2048,128,0,stream>>>(mats + (size_t)q0*MATS_PER_LAYER, lamP + (size_t)q0*QHN,
                                      y16, y16, nullptr, nullptr, nullptr, nullptr);
    // mid-LN stats (applied inside next s4's staging)
    ln_stats<<<512,256,0,stream>>>(y16, meanb, rstdb);
    // S4 q1 with fused LN(q0)
    s4_mfma<1><<<2048,128,0,stream>>>(mats + (size_t)q1*MATS_PER_LAYER, lamP + (size_t)q1*QHN,
                                      y16, y16, meanb, rstdb, ln_g + q0*HSZ, ln_b + q0*HSZ);
    // LN(q1) + gate -> gT16
    ln_gate_kernel<<<512,256,0,stream>>>(y16, gT16, ln_g + q1*HSZ, ln_b + q1*HSZ);
    // op: gT16 -> res RMW(hT16) / skip RMW(sT16)
    gemm_k<1><<<dim3(8,4,16),256,0,stream>>>(op_w + (size_t)d*HSZ*TSZ, op_b + d*HSZ,
                                             gT16, nullptr, nullptr, hT16, sT16, (d==0)?1:0);
  }
  // out1: sT16 -> zT16 (relu, transposed f16)
  gemm_k<2><<<dim3(8,2,16),256,0,stream>>>(out1_w, out1_b, sT16, nullptr,
                                           zT16, nullptr, nullptr, 0);
  // out2: zT16 -> out (coalesced)
  out2_kernel<<<256,256,0,stream>>>(out2_w, out2_b, t, zT16, out);
}

// Round 12
// 709.742 us; speedup vs baseline: 3.6226x; 1.0308x over previous
//
#include <hip/hip_runtime.h>

// ---------------- problem constants ----------------
#define BB     16
#define LLEN   1024
#define CINN   14
#define TSZ    256
#define HSZ    512
#define NST    32
#define ESZ    128
#define NDEPTH 6
#define QHN    (HSZ*NST)

#define RS2 0.70710678118654752f   // 1/sqrt(2)
#define IS6 0.40824829046386302f   // 1/sqrt(6)

typedef unsigned short u16;
typedef unsigned int   u32;
typedef _Float16 f16;
typedef __attribute__((ext_vector_type(2)))  _Float16 f16x2;
typedef __attribute__((ext_vector_type(4)))  _Float16 f16x4;
typedef __attribute__((ext_vector_type(8)))  _Float16 f16x8;
typedef __attribute__((ext_vector_type(16))) float    f32x16;

// workspace layout (float offsets)
#define OFF_LAM   0u          // float2 lambda      x 12*16384
#define OFF_C     393216u     // float2 C'          x 12*16384
#define OFF_LAMP  786432u     // float2 lambda^64   x 12*16384
#define OFF_DPE16 1181696u
#define OFF_Y16   5388288u    // f16  [16][512][1024]
#define OFF_HT    9582592u    // f16  [16][1024][256]
#define OFF_GT    11679744u
#define OFF_ST    13776896u
#define OFF_ZT    15874048u   // f16  [16][1024][256] (out1 output, transposed)
#define OFF_MEAN  17971200u
#define OFF_RSTD  17987584u
#define OFF_MATS  18003968u   // f16 [12][512][3][4096] = 37748736 floats
#define WS_FLOATS 55752704u

#define MATS_PER_LAYER ((size_t)512*12288)

// ---------------- S4D constants: lambda, C' = 2C(lambda-1)/A, lambda^64 ----------------
__global__ void consts_kernel(const float* __restrict__ log_dt, const float* __restrict__ logA,
                              const float* __restrict__ Aim,   const float* __restrict__ Cre,
                              const float* __restrict__ Cim,
                              float2* __restrict__ lam2, float2* __restrict__ C2,
                              float2* __restrict__ lamP){
  int gid = blockIdx.x*256 + threadIdx.x;            // q*16384 + h*32 + n
  int h = (gid>>5) & 511;
  int q = gid >> 14;
  float dt  = expf(log_dt[q*HSZ + h]);
  float are = -expf(logA[gid]);
  float aim = Aim[gid];
  float dre = are*dt, dim = aim*dt;
  float e   = expf(dre);
  float lre = e*cosf(dim), lim = e*sinf(dim);
  float nre = lre - 1.f, nim = lim;
  float invden = 1.f/(are*are + aim*aim);
  float tre = (nre*are + nim*aim)*invden;
  float tim = (nim*are - nre*aim)*invden;
  float cr = Cre[gid], ci = Cim[gid];
  float Cr = 2.f*(cr*tre - ci*tim);
  float Ci = 2.f*(cr*tim + ci*tre);
  lam2[gid] = make_float2(lre, lim);
  C2[gid]   = make_float2(Cr, Ci);
  float pr = lre, pi = lim;
#pragma unroll
  for (int i=0;i<6;i++){ float nr2 = pr*pr - pi*pi; pi = 2.f*pr*pi; pr = nr2; }
  lamP[gid] = make_float2(pr, pi);
}

// ---------------- build ALL per-(q,h) f16 matrices T,V,E (MFMA A-frag order) ----------
__global__ __launch_bounds__(256) void build_mats(const float2* __restrict__ lam2d,
                                                  const float2* __restrict__ C2d,
                                                  const float* __restrict__ Dd,
                                                  f16* __restrict__ mats){
  __shared__ float Pre[65][33];
  __shared__ float Pim[65][33];
  __shared__ float Kk[64];
  int bid = blockIdx.x;
  int q   = bid >> 9;            // 0..11
  int h   = bid & 511;
  const float2* lp = lam2d + (size_t)q*QHN + h*NST;
  const float2* cp = C2d  + (size_t)q*QHN + h*NST;
  int tid = threadIdx.x;
  int n  = tid & 31;
  int pg = tid >> 5;             // 0..7
  {
    float2 l = lp[n];
    float ar=l.x, ai=l.y;
#pragma unroll
    for (int i=0;i<3;i++){ float t2 = ar*ar - ai*ai; ai = 2.f*ar*ai; ar = t2; }
    float br=1.f, bi=0.f;
    for (int i=0;i<pg;i++){ float t2 = br*ar - bi*ai; bi = br*ai + bi*ar; br = t2; }
    float pr=br, pi=bi;
#pragma unroll
    for (int i=0;i<8;i++){
      Pre[8*pg+i][n] = pr; Pim[8*pg+i][n] = pi;
      float t2 = pr*l.x - pi*l.y; pi = pr*l.y + pi*l.x; pr = t2;
    }
    if (pg == 7){ Pre[64][n] = pr; Pim[64][n] = pi; }
  }
  __syncthreads();
  if (tid < 64){
    float s = 0.f;
    for (int n2=0;n2<32;n2++){
      float2 c_ = cp[n2];
      s += c_.x*Pre[tid][n2] - c_.y*Pim[tid][n2];
    }
    Kk[tid] = s;
  }
  __syncthreads();
  float Kdiag = Kk[0] + Dd[q*HSZ + h];
  f16* base = mats + (size_t)bid*12288;
#pragma unroll
  for (int jj=0; jj<6; jj++){
    int job = jj*256 + tid;       // 0..1535
    int mat = job >> 9;           // 0:T 1:V 2:E
    int rem = job & 511;
    int m = rem >> 3;
    int g = rem & 7;
    f16x8 vals;
    if (mat == 0){
#pragma unroll
      for (int j8=0;j8<8;j8++){
        int k = g*8 + j8;
        float v = (m > k) ? Kk[m-k] : ((m == k) ? Kdiag : 0.f);
        vals[j8] = (f16)v;
      }
    } else if (mat == 1){
      int n2 = m >> 1; int im = m & 1;
#pragma unroll
      for (int j8=0;j8<8;j8++){
        int k = g*8 + j8; int p = 63 - k;
        vals[j8] = (f16)(im ? Pim[p][n2] : Pre[p][n2]);
      }
    } else {
#pragma unroll
      for (int j8=0;j8<8;j8++){
        int k = g*8 + j8; int n2 = k >> 1;
        float2 c_ = cp[n2];
        float pr = Pre[m+1][n2], pi = Pim[m+1][n2];
        float re  = c_.x*pr - c_.y*pi;
        float imv = c_.x*pi + c_.y*pr;
        vals[j8] = (f16)((k & 1) ? -imv : re);
      }
    }
    *(f16x8*)(base + mat*4096 + (g*64 + m)*8) = vals;
  }
}

// ---------------- fused diffusion embedding MLP + per-depth projection -> f16 ------
// grid 96: bid = d*16 + b. Each block recomputes emb(b) inline (tiny), then dpe row.
__global__ __launch_bounds__(256) void embdpe_kernel(const float* __restrict__ t, const float* __restrict__ gw,
                                                     const float* __restrict__ w1, const float* __restrict__ b1,
                                                     const float* __restrict__ w2, const float* __restrict__ b2,
                                                     const float* __restrict__ dw, const float* __restrict__ db,
                                                     f16* __restrict__ dpe16){
  __shared__ float e0[128], e1[128], e2[128];
  int bid = blockIdx.x;
  int d = bid >> 4, b = bid & 15;
  int tid = threadIdx.x;
  float tb = t[b];
  if (tid < 64){
    float xp = tb * gw[tid] * 6.283185307179586f;
    e0[tid]    = sinf(xp);
    e0[tid+64] = cosf(xp);
  }
  __syncthreads();
  if (tid < 128){
    float a = b1[tid];
    for (int i=0;i<128;i++) a = fmaf(e0[i], w1[tid*128+i], a);
    e1[tid] = a / (1.f + __expf(-a));
  }
  __syncthreads();
  if (tid < 128){
    float a2 = b2[tid];
    for (int i=0;i<128;i++) a2 = fmaf(e1[i], w2[tid*128+i], a2);
    e2[tid] = a2 / (1.f + __expf(-a2));
  }
  __syncthreads();
  int o = tid;
  const float* wp = dw + (size_t)(d*TSZ + o)*ESZ;
  float a = db[d*TSZ + o];
  for (int e=0;e<128;e++) a = fmaf(e2[e], wp[e], a);
  dpe16[(size_t)(d*BB + b)*TSZ + o] = (f16)a;
}

// ---------------- input projection [B,L,14] -> hT16 [b][l][256] (f16, transposed) ---
// grid 256: bid = b*16 + ltile (64 l per block)
__global__ __launch_bounds__(256) void inproj_t_kernel(const float* __restrict__ x, const float* __restrict__ w,
                                                       const float* __restrict__ bias, f16* __restrict__ hT){
  __shared__ float ws[256*14];
  __shared__ float bs[256];
  __shared__ f16 TT[64*264];
  int tid = threadIdx.x;
#pragma unroll
  for (int c=0;c<14;c++) ws[tid*14+c] = w[tid*14+c];
  bs[tid] = bias[tid];
  __syncthreads();
  int b  = blockIdx.x >> 4;
  int l0 = (blockIdx.x & 15) * 64;
  int ll = tid & 63;
  int tq = tid >> 6;            // t-quarter 0..3
  float xv[14];
  const float* xp = x + (size_t)(b*LLEN + l0 + ll)*CINN;
#pragma unroll
  for (int c=0;c<14;c++) xv[c] = xp[c];
  for (int tt=tq*64; tt<tq*64+64; tt++){
    float a = bs[tt];
#pragma unroll
    for (int c=0;c<14;c++) a = fmaf(ws[tt*14+c], xv[c], a);
    TT[ll*264 + tt] = (f16)a;
  }
  __syncthreads();
#pragma unroll
  for (int i=0;i<8;i++){
    int job = i*256 + tid;        // 64 l x 32 granules
    int l2 = job >> 5, g8 = (job & 31)*8;
    f16x8 hv = *(const f16x8*)(TT + l2*264 + g8);
    *(f16x8*)(hT + ((size_t)b*LLEN + l0 + l2)*TSZ + g8) = hv;
  }
}

// ---------------- MFMA GEMM ----------------
// MODE 0: ip  (B = hT16 + dpe16, Y16o f16 [512][1024])
// MODE 1: op  (B = gT16; y<2: res RMW in hT16; y>=2: skip RMW in sT16)
// MODE 2: out1 (B = sT16 * IS6, relu, Y16o = zT16 transposed f16 [1024][256])
template<int MODE>
__global__ __launch_bounds__(256) void gemm_k(const float* __restrict__ W, const float* __restrict__ bias,
                                              const f16* __restrict__ XT, const f16* __restrict__ dpeD,
                                              f16* __restrict__ Y16o,
                                              f16* __restrict__ hT16, f16* __restrict__ sT16, int first){
  __shared__ f16 sm[17408];
  f16* As = sm;
  f16* Bs = sm + 8192;
  int tid = threadIdx.x;
  int lane = tid & 63;
  int wv = tid >> 6;
  int n_blk = blockIdx.x * 128;
  int m_blk = blockIdx.y * 128;
  int bz = blockIdx.z;
  const f16* Xb = XT + (size_t)bz * (LLEN*TSZ);
  int wm = (wv & 1) * 64;
  int wn = (wv >> 1) * 64;

  f32x16 acc[2][2];
#pragma unroll
  for (int mi=0;mi<2;mi++)
#pragma unroll
    for (int ni=0;ni<2;ni++)
#pragma unroll
      for (int r=0;r<16;r++) acc[mi][ni][r] = 0.f;

  for (int kt=0; kt<4; kt++){
    int k0 = kt*64;
#pragma unroll
    for (int i=0;i<4;i++){
      int job = i*256 + tid;
      int m = job >> 3, gk = job & 7;
      const float* wp = W + (size_t)(m_blk + m)*TSZ + k0 + gk*8;
      float4 u0 = *(const float4*)wp;
      float4 u1 = *(const float4*)(wp+4);
      f16x8 hv;
      hv[0]=(f16)u0.x; hv[1]=(f16)u0.y; hv[2]=(f16)u0.z; hv[3]=(f16)u0.w;
      hv[4]=(f16)u1.x; hv[5]=(f16)u1.y; hv[6]=(f16)u1.z; hv[7]=(f16)u1.w;
      int P = m*8 + (gk ^ (m & 7));
      *(f16x8*)(As + P*8) = hv;
    }
#pragma unroll
    for (int i=0;i<4;i++){
      int job = i*256 + tid;
      int n = job >> 3, gk = job & 7;
      f16x8 hv = *(const f16x8*)(Xb + (size_t)(n_blk + n)*TSZ + k0 + gk*8);
      if (MODE==0){
        f16x8 dv = *(const f16x8*)(dpeD + bz*TSZ + k0 + gk*8);
#pragma unroll
        for (int e=0;e<8;e++) hv[e] = hv[e] + dv[e];
      }
      if (MODE==2){
#pragma unroll
        for (int e=0;e<8;e++) hv[e] = hv[e] * (f16)IS6;
      }
      int P = n*8 + (gk ^ (n & 7));
      *(f16x8*)(Bs + P*8) = hv;
    }
    __syncthreads();
#pragma unroll
    for (int ks=0; ks<4; ks++){
      int q = lane >> 5;
      int gk = ks*2 + q;
      f16x8 af[2], bf[2];
#pragma unroll
      for (int mi=0; mi<2; mi++){
        int m = wm + mi*32 + (lane & 31);
        af[mi] = *(const f16x8*)(As + (m*8 + (gk ^ (m&7)))*8);
      }
#pragma unroll
      for (int ni=0; ni<2; ni++){
        int n = wn + ni*32 + (lane & 31);
        bf[ni] = *(const f16x8*)(Bs + (n*8 + (gk ^ (n&7)))*8);
      }
#pragma unroll
      for (int mi=0; mi<2; mi++)
#pragma unroll
        for (int ni=0; ni<2; ni++)
          acc[mi][ni] = __builtin_amdgcn_mfma_f32_32x32x16_f16(af[mi], bf[ni], acc[mi][ni], 0, 0, 0);
    }
    __syncthreads();
  }

  int q = lane >> 5;
  if (MODE == 0){
#pragma unroll
    for (int mi=0;mi<2;mi++)
#pragma unroll
      for (int ni=0;ni<2;ni++){
        int col = n_blk + wn + ni*32 + (lane & 31);
#pragma unroll
        for (int r=0;r<16;r++){
          int row = m_blk + wm + mi*32 + (r&3) + 8*(r>>2) + 4*q;
          float v = acc[mi][ni][r] + bias[row];
          Y16o[((size_t)bz*HSZ + row)*LLEN + col] = (f16)v;
        }
      }
  } else if (MODE == 2){
    // relu + transpose-store to zT16 [b][l][256]
#pragma unroll
    for (int mi=0;mi<2;mi++)
#pragma unroll
      for (int ni=0;ni<2;ni++){
        int col_l = wn + ni*32 + (lane & 31);
#pragma unroll
        for (int r=0;r<16;r++){
          int row_l = wm + mi*32 + (r&3) + 8*(r>>2) + 4*q;
          float v = fmaxf(acc[mi][ni][r] + bias[m_blk + row_l], 0.f);
          sm[col_l*136 + row_l] = (f16)v;
        }
      }
    __syncthreads();
#pragma unroll
    for (int i=0;i<8;i++){
      int job = i*256 + tid;
      int n = job >> 4, m8 = job & 15;
      f16x8 hv = *(const f16x8*)(sm + n*136 + m8*8);
      *(f16x8*)(Y16o + ((size_t)bz*LLEN + n_blk + n)*TSZ + m_blk + m8*8) = hv;
    }
  } else {
    // tile RMW in transposed f16 buffers, via LDS (coalesced)
    int isRes = (blockIdx.y < 2);
    f16* dst = isRes ? hT16 : sT16;
    int mOff  = isRes ? m_blk : (m_blk - TSZ);
    int doLoad = isRes || !first;
    if (doLoad){
#pragma unroll
      for (int i=0;i<8;i++){
        int job = i*256 + tid;          // 128 n x 16 m-granules
        int n = job >> 4, m8 = job & 15;
        f16x8 hv = *(const f16x8*)(dst + ((size_t)bz*LLEN + n_blk + n)*TSZ + mOff + m8*8);
        *(f16x8*)(sm + n*136 + m8*8) = hv;
      }
      __syncthreads();
    }
#pragma unroll
    for (int mi=0;mi<2;mi++)
#pragma unroll
      for (int ni=0;ni<2;ni++){
        int col_l = wn + ni*32 + (lane & 31);
#pragma unroll
        for (int r=0;r<16;r++){
          int row_l = wm + mi*32 + (r&3) + 8*(r>>2) + 4*q;
          float v = acc[mi][ni][r] + bias[m_blk + row_l];
          if (isRes){
            float old = (float)sm[col_l*136 + row_l];
            sm[col_l*136 + row_l] = (f16)((old + v)*RS2);
          } else if (first){
            sm[col_l*136 + row_l] = (f16)v;
          } else {
            float old = (float)sm[col_l*136 + row_l];
            sm[col_l*136 + row_l] = (f16)(old + v);
          }
        }
      }
    __syncthreads();
#pragma unroll
    for (int i=0;i<8;i++){
      int job = i*256 + tid;
      int n = job >> 4, m8 = job & 15;
      f16x8 hv = *(const f16x8*)(sm + n*136 + m8*8);
      *(f16x8*)(dst + ((size_t)bz*LLEN + n_blk + n)*TSZ + mOff + m8*8) = hv;
    }
  }
}

// ---------------- S4D via MFMA conv (f16): 128-thread blocks, 4 batches each -------
template<int LN>
__global__ __launch_bounds__(128) void s4_mfma(const f16* __restrict__ matsq,
                                               const float2* __restrict__ lamPq,
                                               const f16* u, f16* y,
                                               const float* __restrict__ meanp,
                                               const float* __restrict__ rstdp,
                                               const float* __restrict__ gp,
                                               const float* __restrict__ btp){
  __shared__ f16 Ubuf[64*72];
  __shared__ f16 ZSbuf[64*72];     // Z -> Sprev -> Y (all f16)

  int tid  = threadIdx.x;
  int w    = tid >> 6;              // 0/1
  int lane = tid & 63;
  int q    = lane >> 5;
  int colL = lane & 31;
  int h  = blockIdx.x & 511;
  int bq = blockIdx.x >> 9;         // 0..3
  int b0 = bq*4;

  float gv = 0.f, bv = 0.f;
  if (LN){ gv = gp[h]; bv = btp[h]; }

  const f16* matT = matsq + (size_t)h*12288;
  const f16* matV = matT + 4096;
  const f16* matE = matT + 8192;

  // ---- stage u (wave w covers batches b0+2w, b0+2w+1), optional fused LN
#pragma unroll
  for (int i=0;i<4;i++){
    int fidx = i*64 + lane;               // 0..255
    int row = fidx >> 7;                  // 0/1
    int l   = (fidx & 127)*8;
    int b   = b0 + 2*w + row;
    f16x8 hv = *(const f16x8*)(u + ((size_t)b*HSZ + h)*LLEN + l);
    if (LN){
      float4 m0 = *(const float4*)(meanp + b*LLEN + l);
      float4 m1 = *(const float4*)(meanp + b*LLEN + l + 4);
      float4 r0 = *(const float4*)(rstdp + b*LLEN + l);
      float4 r1 = *(const float4*)(rstdp + b*LLEN + l + 4);
      float mm[8] = {m0.x,m0.y,m0.z,m0.w,m1.x,m1.y,m1.z,m1.w};
      float rr[8] = {r0.x,r0.y,r0.z,r0.w,r1.x,r1.y,r1.z,r1.w};
#pragma unroll
      for (int e=0;e<8;e++)
        hv[e] = (f16)(((float)hv[e] - mm[e])*rr[e]*gv + bv);
    }
    int col = (2*w + row)*16 + (l >> 6);
    *(f16x8*)(Ubuf + col*72 + (l & 63)) = hv;
  }
  __syncthreads();

  int strip = w*32;

  // ---- GEMM1: Z = V @ U
  {
    f32x16 zacc[2];
#pragma unroll
    for (int mt=0;mt<2;mt++)
#pragma unroll
      for (int r=0;r<16;r++) zacc[mt][r] = 0.f;
#pragma unroll
    for (int kt=0; kt<4; kt++){
      int kg = kt*2 + q;
      f16x8 bfrag = *(const f16x8*)(Ubuf + (strip+colL)*72 + kg*8);
#pragma unroll
      for (int mt=0; mt<2; mt++){
        f16x8 afrag = *(const f16x8*)(matV + ((size_t)(kg*64 + mt*32 + colL))*8);
        zacc[mt] = __builtin_amdgcn_mfma_f32_32x32x16_f16(afrag, bfrag, zacc[mt], 0, 0, 0);
      }
    }
#pragma unroll
    for (int mt=0;mt<2;mt++)
#pragma unroll
      for (int rg=0;rg<4;rg++){
        int st0 = mt*32 + rg*8 + q*4;
        f16x4 zp;
        zp[0]=(f16)zacc[mt][rg*4+0]; zp[1]=(f16)zacc[mt][rg*4+1];
        zp[2]=(f16)zacc[mt][rg*4+2]; zp[3]=(f16)zacc[mt][rg*4+3];
        *(f16x4*)(ZSbuf + (strip+colL)*72 + st0) = zp;
      }
  }
  __syncthreads();

  // ---- prefix over 16 chunks (in-place Z -> Sprev), per (batch-row, n) chain
  {
    int n  = lane & 31;
    int colb = (2*w + (lane>>5))*16;
    float2 l64 = lamPq[h*NST + n];
    float Sre = 0.f, Sim = 0.f;
#pragma unroll
    for (int c=0;c<16;c++){
      f16* p = ZSbuf + (colb + c)*72 + 2*n;
      f16x2 z2 = *(f16x2*)p;
      f16x2 sp_; sp_[0] = (f16)Sre; sp_[1] = (f16)Sim;
      *(f16x2*)p = sp_;
      float nr = fmaf(l64.x, Sre, fmaf(-l64.y, Sim, (float)z2[0]));
      float ni = fmaf(l64.x, Sim, fmaf( l64.y, Sre, (float)z2[1]));
      Sre = nr; Sim = ni;
    }
  }
  __syncthreads();

  // ---- GEMM2: Y = T @ U + E @ Sprev
  f32x16 yacc[2];
#pragma unroll
  for (int mt=0;mt<2;mt++)
#pragma unroll
    for (int r=0;r<16;r++) yacc[mt][r] = 0.f;
#pragma unroll
  for (int kt=0; kt<4; kt++){
    int kg = kt*2 + q;
    f16x8 bu = *(const f16x8*)(Ubuf  + (strip+colL)*72 + kg*8);
    f16x8 bs = *(const f16x8*)(ZSbuf + (strip+colL)*72 + kg*8);
#pragma unroll
    for (int mt=0; mt<2; mt++){
      f16x8 aT = *(const f16x8*)(matT + ((size_t)(kg*64 + mt*32 + colL))*8);
      yacc[mt] = __builtin_amdgcn_mfma_f32_32x32x16_f16(aT, bu, yacc[mt], 0, 0, 0);
    }
#pragma unroll
    for (int mt=0; mt<2; mt++){
      f16x8 aE = *(const f16x8*)(matE + ((size_t)(kg*64 + mt*32 + colL))*8);
      yacc[mt] = __builtin_amdgcn_mfma_f32_32x32x16_f16(aE, bs, yacc[mt], 0, 0, 0);
    }
  }
  __syncthreads();

  // ---- store Y (f16) into ZSbuf region, then coalesced f16x8 global write
#pragma unroll
  for (int mt=0;mt<2;mt++)
#pragma unroll
    for (int rg=0;rg<4;rg++){
      int j0 = mt*32 + rg*8 + q*4;
      f16x4 yv;
      yv[0]=(f16)yacc[mt][rg*4+0]; yv[1]=(f16)yacc[mt][rg*4+1];
      yv[2]=(f16)yacc[mt][rg*4+2]; yv[3]=(f16)yacc[mt][rg*4+3];
      *(f16x4*)(ZSbuf + (strip+colL)*72 + j0) = yv;
    }
  __syncthreads();
#pragma unroll
  for (int i=0;i<4;i++){
    int fidx = i*64 + lane;
    int row = fidx >> 7;
    int l   = (fidx & 127)*8;
    int b   = b0 + 2*w + row;
    int col = (2*w + row)*16 + (l >> 6);
    f16x8 hv = *(const f16x8*)(ZSbuf + col*72 + (l & 63));
    *(f16x8*)(y + ((size_t)b*HSZ + h)*LLEN + l) = hv;
  }
}

// ---------------- LN stats v2: coalesced f16x8 reads + wave shfl reduce -------------
// grid 512: bid = b*32 + ltile (32 l). thread: lg = tid&3 (l-granule), hb = tid>>2.
__global__ __launch_bounds__(256) void ln_stats(const f16* __restrict__ in,
                                                float* __restrict__ mean, float* __restrict__ rstd){
  __shared__ float rs[4][32];
  __shared__ float rq[4][32];
  int tid = threadIdx.x;
  int lg = tid & 3;
  int hb = tid >> 2;            // 0..63
  int w  = tid >> 6;
  int b  = blockIdx.x >> 5;
  int l0 = (blockIdx.x & 31) << 5;
  float s8[8], q8[8];
#pragma unroll
  for (int j=0;j<8;j++){ s8[j]=0.f; q8[j]=0.f; }
  const f16* basep = in + (size_t)(b*HSZ)*LLEN + l0 + lg*8;
#pragma unroll
  for (int i=0;i<8;i++){
    int h = hb + 64*i;
    f16x8 hv = *(const f16x8*)(basep + (size_t)h*LLEN);
#pragma unroll
    for (int j=0;j<8;j++){
      float v = (float)hv[j];
      s8[j] += v; q8[j] = fmaf(v,v,q8[j]);
    }
  }
  // reduce across the 16 hb-lanes sharing lg within each wave
#pragma unroll
  for (int d=4; d<64; d<<=1){
#pragma unroll
    for (int j=0;j<8;j++){
      s8[j] += __shfl_xor(s8[j], (unsigned)d);
      q8[j] += __shfl_xor(q8[j], (unsigned)d);
    }
  }
  if (((tid>>2) & 15) == 0){
#pragma unroll
    for (int j=0;j<8;j++){
      rs[w][lg*8+j] = s8[j];
      rq[w][lg*8+j] = q8[j];
    }
  }
  __syncthreads();
  if (tid < 32){
    float S = rs[0][tid]+rs[1][tid]+rs[2][tid]+rs[3][tid];
    float Q = rq[0][tid]+rq[1][tid]+rq[2][tid]+rq[3][tid];
    float mn = S * (1.f/HSZ);
    float var = Q * (1.f/HSZ) - mn*mn;
    mean[b*LLEN + l0 + tid] = mn;
    rstd[b*LLEN + l0 + tid] = rsqrtf(var + 1e-5f);
  }
}

// ---------------- LN + gate v2: coalesced, two-pass, out transposed f16 -------------
// grid 512: bid = b*32 + ltile (32 l).
__global__ __launch_bounds__(256) void ln_gate_kernel(const f16* __restrict__ in, f16* __restrict__ gT,
                                                      const float* __restrict__ g, const float* __restrict__ bt){
  __shared__ float rs[4][32];
  __shared__ float rq[4][32];
  __shared__ float mbuf[32], rbuf[32];
  __shared__ f16 gbuf[32*264];
  int tid = threadIdx.x;
  int lg = tid & 3;
  int w  = tid >> 6;
  int b  = blockIdx.x >> 5;
  int l0 = (blockIdx.x & 31) << 5;
  // ---- pass 1: stats
  {
    int hb = tid >> 2;
    float s8[8], q8[8];
#pragma unroll
    for (int j=0;j<8;j++){ s8[j]=0.f; q8[j]=0.f; }
    const f16* basep = in + (size_t)(b*HSZ)*LLEN + l0 + lg*8;
#pragma unroll
    for (int i=0;i<8;i++){
      int h = hb + 64*i;
      f16x8 hv = *(const f16x8*)(basep + (size_t)h*LLEN);
#pragma unroll
      for (int j=0;j<8;j++){
        float v = (float)hv[j];
        s8[j] += v; q8[j] = fmaf(v,v,q8[j]);
      }
    }
#pragma unroll
    for (int d=4; d<64; d<<=1){
#pragma unroll
      for (int j=0;j<8;j++){
        s8[j] += __shfl_xor(s8[j], (unsigned)d);
        q8[j] += __shfl_xor(q8[j], (unsigned)d);
      }
    }
    if (((tid>>2) & 15) == 0){
#pragma unroll
      for (int j=0;j<8;j++){
        rs[w][lg*8+j] = s8[j];
        rq[w][lg*8+j] = q8[j];
      }
    }
  }
  __syncthreads();
  if (tid < 32){
    float S = rs[0][tid]+rs[1][tid]+rs[2][tid]+rs[3][tid];
    float Q = rq[0][tid]+rq[1][tid]+rq[2][tid]+rq[3][tid];
    float mn = S * (1.f/HSZ);
    float var = Q * (1.f/HSZ) - mn*mn;
    mbuf[tid] = mn;
    rbuf[tid] = rsqrtf(var + 1e-5f);
  }
  __syncthreads();
  // ---- pass 2: gate + transpose
  {
    int tq = tid >> 2;            // 0..63
    float mloc[8], rloc[8];
#pragma unroll
    for (int j=0;j<8;j++){ mloc[j]=mbuf[lg*8+j]; rloc[j]=rbuf[lg*8+j]; }
    const f16* basep = in + (size_t)(b*HSZ)*LLEN + l0 + lg*8;
#pragma unroll
    for (int i=0;i<4;i++){
      int t = tq + 64*i;          // 0..255
      f16x8 av = *(const f16x8*)(basep + (size_t)t*LLEN);
      f16x8 fv = *(const f16x8*)(basep + (size_t)(t+256)*LLEN);
      float ga = g[t], ba = bt[t], gf = g[t+256], bf2 = bt[t+256];
#pragma unroll
      for (int j=0;j<8;j++){
        float a = ((float)av[j] - mloc[j])*rloc[j]*ga + ba;
        float f = ((float)fv[j] - mloc[j])*rloc[j]*gf + bf2;
        float sg = 1.f/(1.f+__expf(-a));
        float th = 1.f - 2.f/(__expf(2.f*f)+1.f);
        gbuf[(lg*8+j)*264 + t] = (f16)(sg*th);
      }
    }
  }
  __syncthreads();
#pragma unroll
  for (int i=0;i<4;i++){
    int job = i*256 + tid;        // 32 l x 32 granules
    int ll = job >> 5, g8 = (job & 31)*8;
    f16x8 hv = *(const f16x8*)(gbuf + ll*264 + g8);
    *(f16x8*)(gT + ((size_t)b*LLEN + l0 + ll)*TSZ + g8) = hv;
  }
}

// ---------------- out2: zT16 [b][l][256] -> out [b][l][14], coalesced -----------
__global__ __launch_bounds__(256) void out2_kernel(const float* __restrict__ w2, const float* __restrict__ b2,
                                                   const float* __restrict__ t, const f16* __restrict__ zT,
                                                   float* __restrict__ outp){
  __shared__ f16 zt[64*264];
  __shared__ float wsm[14*256];
  __shared__ float part[64][4][16];
  __shared__ float bs[14];
  int tid = threadIdx.x;
#pragma unroll
  for (int c=0;c<14;c++) wsm[c*256+tid] = w2[c*256+tid];
  if (tid < 14) bs[tid] = b2[tid];
  int b = blockIdx.x >> 4;
  int l0 = (blockIdx.x & 15) * 64;
#pragma unroll
  for (int i=0;i<8;i++){
    int job = i*256 + tid;           // 64 l x 32 granules
    int ll = job >> 5, g8 = (job & 31)*8;
    f16x8 hv = *(const f16x8*)(zT + ((size_t)b*LLEN + l0 + ll)*TSZ + g8);
    *(f16x8*)(zt + ll*264 + g8) = hv;
  }
  __syncthreads();
  int l = tid >> 2;
  int g = tid & 3;
  float acc[14];
#pragma unroll
  for (int c=0;c<14;c++) acc[c]=0.f;
  for (int k=0;k<64;k++){
    float zv = (float)zt[l*264 + g*64 + k];
#pragma unroll
    for (int c=0;c<14;c++) acc[c] = fmaf(wsm[c*256 + g*64 + k], zv, acc[c]);
  }
#pragma unroll
  for (int c=0;c<14;c++) part[l][g][c] = acc[c];
  __syncthreads();
  if (g == 0){
    float tb = t[b];
    float scale = rsqrtf(1e-4f + tb*(2e-2f - 1e-4f));
    float* op = outp + (size_t)(b*LLEN + l0 + l)*CINN;
#pragma unroll
    for (int c=0;c<14;c++)
      op[c] = (part[l][0][c]+part[l][1][c]+part[l][2][c]+part[l][3][c] + bs[c])*scale;
  }
}

// ---------------- host launcher ----------------
extern "C" void kernel_launch(void* const* d_in, const int* in_sizes, int n_in,
                              void* d_out, int out_size, void* d_ws, size_t ws_size,
                              hipStream_t stream) {
  (void)in_sizes; (void)n_in; (void)out_size;
  if (ws_size < (size_t)WS_FLOATS * 4) return;

  const float* x      = (const float*)d_in[0];
  const float* t      = (const float*)d_in[1];
  const float* gfpW   = (const float*)d_in[2];
  const float* ew1    = (const float*)d_in[3];
  const float* eb1    = (const float*)d_in[4];
  const float* ew2    = (const float*)d_in[5];
  const float* eb2    = (const float*)d_in[6];
  const float* in_w   = (const float*)d_in[7];
  const float* in_b   = (const float*)d_in[8];
  const float* out1_w = (const float*)d_in[9];
  const float* out1_b = (const float*)d_in[10];
  const float* out2_w = (const float*)d_in[11];
  const float* out2_b = (const float*)d_in[12];
  const float* dp_w   = (const float*)d_in[13];
  const float* dp_b   = (const float*)d_in[14];
  const float* ip_w   = (const float*)d_in[15];
  const float* ip_b   = (const float*)d_in[16];
  const float* op_w   = (const float*)d_in[17];
  const float* op_b   = (const float*)d_in[18];
  const float* log_dt = (const float*)d_in[19];
  const float* logA   = (const float*)d_in[20];
  const float* Aim    = (const float*)d_in[21];
  const float* Cre    = (const float*)d_in[22];
  const float* Cim    = (const float*)d_in[23];
  const float* s4D    = (const float*)d_in[24];
  const float* ln_g   = (const float*)d_in[25];
  const float* ln_b   = (const float*)d_in[26];
  float* out = (float*)d_out;
  float* ws = (float*)d_ws;

  float2* lam2  = (float2*)(ws + OFF_LAM);
  float2* C2v   = (float2*)(ws + OFF_C);
  float2* lamP  = (float2*)(ws + OFF_LAMP);
  f16*   dpe16 = (f16*)(ws + OFF_DPE16);
  f16*   y16   = (f16*)(ws + OFF_Y16);
  f16*   hT16  = (f16*)(ws + OFF_HT);
  f16*   gT16  = (f16*)(ws + OFF_GT);
  f16*   sT16  = (f16*)(ws + OFF_ST);
  f16*   zT16  = (f16*)(ws + OFF_ZT);
  float* meanb = ws + OFF_MEAN;
  float* rstdb = ws + OFF_RSTD;
  f16*   mats  = (f16*)(ws + OFF_MATS);

  consts_kernel<<<768,256,0,stream>>>(log_dt, logA, Aim, Cre, Cim, lam2, C2v, lamP);
  build_mats<<<6144,256,0,stream>>>(lam2, C2v, s4D, mats);
  embdpe_kernel<<<NDEPTH*BB,256,0,stream>>>(t, gfpW, ew1, eb1, ew2, eb2, dp_w, dp_b, dpe16);
  inproj_t_kernel<<<256,256,0,stream>>>(x, in_w, in_b, hT16);

  for (int d=0; d<NDEPTH; d++){
    int q0 = d*2, q1 = d*2+1;
    // ip: hT16 (+dpe) -> y16 f16
    gemm_k<0><<<dim3(8,4,16),256,0,stream>>>(ip_w + (size_t)d*HSZ*TSZ, ip_b + d*HSZ,
                                             hT16, dpe16 + (size_t)d*BB*TSZ,
                                             y16, nullptr, nullptr, 0);
    // S4 q0 (in place on y16)
    s4_mfma<0><<<2048,128,0,stream>>>(mats + (size_t)q0*MATS_PER_LAYER, lamP + (size_t)q0*QHN,
                                      y16, y16, nullptr, nullptr, nullptr, nullptr);
    // mid-LN stats (applied inside next s4's staging)
    ln_stats<<<512,256,0,stream>>>(y16, meanb, rstdb);
    // S4 q1 with fused LN(q0)
    s4_mfma<1><<<2048,128,0,stream>>>(mats + (size_t)q1*MATS_PER_LAYER, lamP + (size_t)q1*QHN,
                                      y16, y16, meanb, rstdb, ln_g + q0*HSZ, ln_b + q0*HSZ);
    // LN(q1) + gate -> gT16
    ln_gate_kernel<<<512,256,0,stream>>>(y16, gT16, ln_g + q1*HSZ, ln_b + q1*HSZ);
    // op: gT16 -> res RMW(hT16) / skip RMW(sT16)
    gemm_k<1><<<dim3(8,4,16),256,0,stream>>>(op_w + (size_t)d*HSZ*TSZ, op_b + d*HSZ,
                                             gT16, nullptr, nullptr, hT16, sT16, (d==0)?1:0);
  }
  // out1: sT16 -> zT16 (relu, transposed f16)
  gemm_k<2><<<dim3(8,2,16),256,0,stream>>>(out1_w, out1_b, sT16, nullptr,
                                           zT16, nullptr, nullptr, 0);
  // out2: zT16 -> out (coalesced)
  out2_kernel<<<256,256,0,stream>>>(out2_w, out2_b, t, zT16, out);
}